// Round 2
// baseline (1651.690 us; speedup 1.0000x reference)
//
#include <hip/hip_runtime.h>
#include <hip/hip_bf16.h>

#define N_NODES 16384
#define K_NBR 16
#define HOPS 4
#define IN_DIM 256
#define RAW_DIM 128
#define OUT_DIM 64
#define PHI_DIM 16
#define N_KERN 4
#define E_EDGES (N_NODES * K_NBR)

typedef __hip_bfloat16 bf16;

__device__ __forceinline__ float toF(float x) { return x; }
__device__ __forceinline__ float toF(bf16 x) { return __bfloat162float(x); }

// --------------------------- workspace layout (floats) ---------------------
#define CV_WPHI 0
#define CV_W1   (CV_WPHI + HOPS * RAW_DIM * (PHI_DIM - 1))
#define CV_B1   (CV_W1 + HOPS * RAW_DIM * IN_DIM)
#define CV_W2   (CV_B1 + HOPS * IN_DIM)
#define CV_B2   (CV_W2 + HOPS * IN_DIM * PHI_DIM * N_KERN)
#define CV_TPHI (CV_B2 + HOPS * PHI_DIM * N_KERN)
#define CV_W    (CV_TPHI + HOPS * N_KERN * PHI_DIM)
#define CV_BIAS (CV_W + HOPS * IN_DIM * OUT_DIM * N_KERN)
#define CV_Z    (CV_BIAS + HOPS * OUT_DIM)
#define CV_END  (CV_Z + OUT_DIM)

// ---------------------------------------------------------------------------
// dtype detection: read h as bf16. Real bf16 -> max|v| ~ 4. f32 read as bf16
// halves -> garbage exponents, max >> 1e4.  *flag = 1 means inputs are bf16.
// ---------------------------------------------------------------------------
__global__ void detect_kernel(const void* __restrict__ h, int* __restrict__ flag)
{
    __shared__ float red[256];
    int t = threadIdx.x;
    const unsigned short* p = (const unsigned short*)h;
    float mx = 0.f;
    for (int i = t; i < 2048; i += 256) {
        unsigned int bits = ((unsigned int)p[i]) << 16;
        float v;
        __builtin_memcpy(&v, &bits, 4);
        v = fabsf(v);
        if (!(v == v) || v > 1e30f) v = 1e30f;
        mx = fmaxf(mx, v);
    }
    red[t] = mx;
    __syncthreads();
    for (int s = 128; s > 0; s >>= 1) {
        if (t < s) red[t] = fmaxf(red[t], red[t + s]);
        __syncthreads();
    }
    if (t == 0) *flag = (red[0] < 1e4f) ? 1 : 0;
}

__device__ __forceinline__ float loadDyn(const void* p, int i, bool isbf)
{
    return isbf ? toF(((const bf16*)p)[i]) : ((const float*)p)[i];
}

// Convert the 9 small weight tensors into one contiguous f32 region.
__global__ __launch_bounds__(256) void cvt_small_kernel(
    const void* wphi, const void* w1, const void* b1, const void* w2,
    const void* b2, const void* tphi, const void* W, const void* bias,
    const void* z, float* __restrict__ dst, const int* __restrict__ flag)
{
    int idx = blockIdx.x * 256 + threadIdx.x;
    if (idx >= CV_END) return;
    bool isbf = (*flag != 0);
    float v;
    if      (idx < CV_W1)   v = loadDyn(wphi, idx - CV_WPHI, isbf);
    else if (idx < CV_B1)   v = loadDyn(w1,   idx - CV_W1,   isbf);
    else if (idx < CV_W2)   v = loadDyn(b1,   idx - CV_B1,   isbf);
    else if (idx < CV_B2)   v = loadDyn(w2,   idx - CV_W2,   isbf);
    else if (idx < CV_TPHI) v = loadDyn(b2,   idx - CV_B2,   isbf);
    else if (idx < CV_W)    v = loadDyn(tphi, idx - CV_TPHI, isbf);
    else if (idx < CV_BIAS) v = loadDyn(W,    idx - CV_W,    isbf);
    else if (idx < CV_Z)    v = loadDyn(bias, idx - CV_BIAS, isbf);
    else                    v = loadDyn(z,    idx - CV_Z,    isbf);
    dst[idx] = v;
}

// ---------------------------------------------------------------------------
// Tiled GEMM body: C(f32, M x ldc) = [relu]( A(M x K) @ B(K x N) + bias )
// 64x64 tile, BK=16, 256 threads, 4x4 micro-tile per thread. B/bias are f32.
// ---------------------------------------------------------------------------
template <typename TA>
__device__ void gemm_body(const TA* __restrict__ A, const float* __restrict__ B,
                          const float* __restrict__ bias, float* __restrict__ C,
                          int M, int N, int K, int ldc, int relu)
{
    __shared__ float As[16][65];
    __shared__ float Bs[16][65];
    int tid = threadIdx.x;
    int rowBase = blockIdx.y * 64;
    int colBase = blockIdx.x * 64;
    int tx = tid & 15, ty = tid >> 4;
    float acc[4][4] = {};

    int la_r = tid >> 2;
    int la_c = (tid & 3) << 2;
    int lb_r = tid >> 4;
    int lb_c = (tid & 15) << 2;

    for (int k0 = 0; k0 < K; k0 += 16) {
        const TA* ap = A + (size_t)(rowBase + la_r) * K + (k0 + la_c);
        As[la_c + 0][la_r] = toF(ap[0]);
        As[la_c + 1][la_r] = toF(ap[1]);
        As[la_c + 2][la_r] = toF(ap[2]);
        As[la_c + 3][la_r] = toF(ap[3]);
        const float* bp = B + (size_t)(k0 + lb_r) * N + (colBase + lb_c);
#pragma unroll
        for (int j = 0; j < 4; j++) {
            int c = colBase + lb_c + j;
            Bs[lb_r][lb_c + j] = (c < N) ? bp[j] : 0.f;
        }
        __syncthreads();
#pragma unroll
        for (int kk = 0; kk < 16; kk++) {
            float a[4], b[4];
#pragma unroll
            for (int i = 0; i < 4; i++) a[i] = As[kk][(ty << 2) + i];
#pragma unroll
            for (int j = 0; j < 4; j++) b[j] = Bs[kk][(tx << 2) + j];
#pragma unroll
            for (int i = 0; i < 4; i++)
#pragma unroll
                for (int j = 0; j < 4; j++) acc[i][j] += a[i] * b[j];
        }
        __syncthreads();
    }
#pragma unroll
    for (int i = 0; i < 4; i++) {
        int r = rowBase + (ty << 2) + i;
#pragma unroll
        for (int j = 0; j < 4; j++) {
            int c = colBase + (tx << 2) + j;
            if (c < N) {
                float v = acc[i][j];
                if (bias) v += bias[c];
                if (relu) v = fmaxf(v, 0.f);
                C[(size_t)r * ldc + c] = v;
            }
        }
    }
}

// Dual-pointer GEMM: selects bf16 or f32 A pointer by *flag (block-uniform).
__global__ __launch_bounds__(256) void gemm_dyn2(
    const void* __restrict__ A_bf, const void* __restrict__ A_f32,
    const float* __restrict__ B, const float* __restrict__ bias,
    float* __restrict__ C, int M, int N, int K, int ldc, int relu,
    const int* __restrict__ flag)
{
    if (*flag != 0) gemm_body<bf16>((const bf16*)A_bf, B, bias, C, M, N, K, ldc, relu);
    else            gemm_body<float>((const float*)A_f32, B, bias, C, M, N, K, ldc, relu);
}

// f32-A GEMM (workspace input)
__global__ __launch_bounds__(256) void gemm_f32(
    const float* __restrict__ A, const float* __restrict__ B,
    const float* __restrict__ bias, float* __restrict__ C,
    int M, int N, int K, int ldc, int relu)
{
    gemm_body<float>(A, B, bias, C, M, N, K, ldc, relu);
}

// ---------------------------------------------------------------------------
// tn = row-normalized tilde_phi (no epsilon), accumulate l_sep. 64 threads.
// ---------------------------------------------------------------------------
__global__ void tn_lsep_kernel(const float* __restrict__ tphi_l,
                               float* __restrict__ tn_out, float* __restrict__ acc)
{
    __shared__ float s_v[64], s_tn[64], s_red[64];
    int t = threadIdx.x;
    int row = t >> 4, p = t & 15;
    float v = tphi_l[t];
    s_v[t] = v;
    __syncthreads();
    float ss = 0.f;
    for (int q = 0; q < 16; q++) { float x = s_v[row * 16 + q]; ss += x * x; }
    float tnv = v / sqrtf(ss);
    tn_out[t] = tnv;
    s_tn[t] = tnv;
    __syncthreads();
    float s = 0.f;
    for (int j = 0; j < 4; j++) { float d = tnv - s_tn[j * 16 + p]; s += d * d; }
    s_red[t] = s;
    __syncthreads();
    if (t == 0) {
        float tot = 0.f;
        for (int i = 0; i < 64; i++) tot += s_red[i];
        atomicAdd(acc, tot * 0.25f);
    }
}

// delta_ik = tn + delta (in place), accumulate sum(delta^2) for l_focus.
__global__ __launch_bounds__(256) void deltaik_kernel(
    float* __restrict__ delta, const float* __restrict__ tn, float* __restrict__ acc)
{
    int idx = blockIdx.x * 256 + threadIdx.x;
    int j = idx & 63;
    float v = delta[idx];
    float sq = v * v;
    delta[idx] = v + tn[j];
#pragma unroll
    for (int off = 32; off > 0; off >>= 1) sq += __shfl_xor(sq, off);
    if ((threadIdx.x & 63) == 0) atomicAdd(acc, sq);
}

// ---------------------------------------------------------------------------
// Per-dst-node: dist -> logits -> edge softmax -> aggregation -> bias ->
// row-normalize. One 64-thread block per node (edges contiguous in memory).
// ---------------------------------------------------------------------------
__global__ __launch_bounds__(64) void edge_agg_kernel(
    const float* __restrict__ hk, const float* __restrict__ phi,
    const float* __restrict__ dik, const int* __restrict__ src_l,
    const float* __restrict__ bias_l, float* __restrict__ outs_l)
{
    int node = blockIdx.x;
    int tid = threadIdx.x;
    __shared__ float s_phi[15];
    __shared__ float s_dik[64];
    __shared__ int s_src[16];
    __shared__ float s_att[16][4];

    s_dik[tid] = dik[(size_t)node * 64 + tid];
    if (tid < 16) s_src[tid] = src_l[(size_t)node * 16 + tid];
    if (tid < 15) s_phi[tid] = phi[(size_t)node * 16 + tid];
    __syncthreads();

    // stage 1: per-(edge e, kernel k) logit
    int e = tid >> 2, k = tid & 3;
    int s = s_src[e];
    float dist[16];
    float ss = 0.f;
    bool allz = true;
    for (int p = 0; p < 15; p++) {
        float d = phi[(size_t)s * 16 + p] - s_phi[p];
        dist[p] = d;
        ss += d * d;
        if (d != 0.f) allz = false;
    }
    float last = allz ? 1.f : 0.f;
    dist[15] = last;
    ss += last * last;
    float inv = 1.f / fmaxf(sqrtf(ss), 1e-8f);
    float lg = 0.f;
    for (int p = 0; p < 16; p++) lg += dist[p] * inv * s_dik[k * 16 + p];
    s_att[e][k] = lg;
    __syncthreads();

    // stage 2: softmax over 16 edges for this k
    float mx = -1e30f;
    for (int ee = 0; ee < 16; ee++) mx = fmaxf(mx, s_att[ee][k]);
    float den = 0.f;
    for (int ee = 0; ee < 16; ee++) den += expf(s_att[ee][k] - mx);
    float att = expf(lg - mx) / den;
    __syncthreads();
    s_att[e][k] = att;
    __syncthreads();

    // stage 3: aggregation; thread = output dim
    float accv[4] = {0.f, 0.f, 0.f, 0.f};
    for (int ee = 0; ee < 16; ee++) {
        const float* hr = hk + (size_t)s_src[ee] * 256 + tid;
#pragma unroll
        for (int kk = 0; kk < 4; kk++) accv[kk] += s_att[ee][kk] * hr[kk * 64];
    }
    float o = accv[0] + accv[1] + accv[2] + accv[3] + bias_l[tid];

    // stage 4: row-normalize (full-wave shuffles)
    float s2 = o * o;
#pragma unroll
    for (int off = 32; off > 0; off >>= 1) s2 += __shfl_xor(s2, off);
    o /= fmaxf(sqrtf(s2), 1e-8f);
    outs_l[(size_t)node * 64 + tid] = o;
}

// Hop fusion + output store (dtype by flag).
__global__ __launch_bounds__(256) void fuse_kernel(
    const float* __restrict__ outs, const float* __restrict__ z,
    void* __restrict__ out, const int* __restrict__ flag)
{
    int tid = threadIdx.x;
    int node = blockIdx.x * 4 + (tid >> 6);
    int dd = tid & 63;
    float zv = z[dd];
    float o[4], sc[4];
#pragma unroll
    for (int h = 0; h < 4; h++) {
        o[h] = outs[((size_t)h * N_NODES + node) * 64 + dd];
        float v = o[h] * zv;
#pragma unroll
        for (int off = 32; off > 0; off >>= 1) v += __shfl_xor(v, off);
        sc[h] = v;
    }
    float mx = fmaxf(fmaxf(sc[0], sc[1]), fmaxf(sc[2], sc[3]));
    float e0 = expf(sc[0] - mx), e1 = expf(sc[1] - mx);
    float e2 = expf(sc[2] - mx), e3 = expf(sc[3] - mx);
    float den = e0 + e1 + e2 + e3;
    float t = (e0 * o[0] + e1 * o[1] + e2 * o[2] + e3 * o[3]) / den;
    size_t oi = (size_t)node * 64 + dd;
    if (*flag != 0) ((bf16*)out)[oi] = __float2bfloat16(t);
    else            ((float*)out)[oi] = t;
}

__global__ void init_kernel(float* acc)
{
    if (threadIdx.x < 2) acc[threadIdx.x] = 0.f;
}

__global__ void final_kernel(const float* __restrict__ acc, void* __restrict__ out,
                             const int* __restrict__ flag)
{
    if (threadIdx.x == 0) {
        float a = acc[0] * 0.25f;
        float b = acc[1] / ((float)N_NODES * 4.f * 4.f);
        size_t base = (size_t)N_NODES * 64;
        if (*flag != 0) {
            ((bf16*)out)[base]     = __float2bfloat16(a);
            ((bf16*)out)[base + 1] = __float2bfloat16(b);
        } else {
            ((float*)out)[base]     = a;
            ((float*)out)[base + 1] = b;
        }
    }
}

extern "C" void kernel_launch(void* const* d_in, const int* in_sizes, int n_in,
                              void* d_out, int out_size, void* d_ws, size_t ws_size,
                              hipStream_t stream)
{
    const void* h    = d_in[0];
    const void* e    = d_in[1];
    const int*  src  = (const int*)d_in[2];
    const void* Wphi = d_in[4];
    const void* w1   = d_in[5];
    const void* b1   = d_in[6];
    const void* w2   = d_in[7];
    const void* b2   = d_in[8];
    const void* tphi = d_in[9];
    const void* W    = d_in[10];
    const void* bias = d_in[11];
    const void* z    = d_in[12];

    float* ws    = (float*)d_ws;
    float* CV    = ws;
    float* OUTS  = CV + CV_END;
    float* HK    = OUTS + (size_t)4 * N_NODES * 64;
    float* HID   = HK + (size_t)N_NODES * 256;
    float* PHI   = HID + (size_t)N_NODES * 256;
    float* DELTA = PHI + (size_t)N_NODES * 16;
    float* TN    = DELTA + (size_t)N_NODES * 64;
    float* ACC   = TN + 64;
    int*   FLAG  = (int*)(ACC + 2);

    detect_kernel<<<1, 256, 0, stream>>>(h, FLAG);
    init_kernel<<<1, 64, 0, stream>>>(ACC);
    cvt_small_kernel<<<(CV_END + 255) / 256, 256, 0, stream>>>(
        Wphi, w1, b1, w2, b2, tphi, W, bias, z, CV, FLAG);

    for (int l = 0; l < HOPS; l++) {
        const int* src_l = src + (size_t)l * E_EDGES;
        size_t eoff = (size_t)l * N_NODES * RAW_DIM;
        const void* e_bf  = (const void*)((const bf16*)e + eoff);
        const void* e_f32 = (const void*)((const float*)e + eoff);

        // hk = h @ W_l                       (16384x256 @ 256x256)
        gemm_dyn2<<<dim3(4, 256), 256, 0, stream>>>(
            h, h, CV + CV_W + (size_t)l * 256 * 256, nullptr, HK,
            N_NODES, 256, 256, 256, 0, FLAG);
        // phi = e_l @ Wphi_l                 (16384x128 @ 128x15, ldc 16)
        gemm_dyn2<<<dim3(1, 256), 256, 0, stream>>>(
            e_bf, e_f32, CV + CV_WPHI + (size_t)l * 128 * 15, nullptr, PHI,
            N_NODES, 15, 128, 16, 0, FLAG);
        // hid = relu(e_l @ w1 + b1)          (16384x128 @ 128x256)
        gemm_dyn2<<<dim3(4, 256), 256, 0, stream>>>(
            e_bf, e_f32, CV + CV_W1 + (size_t)l * 128 * 256,
            CV + CV_B1 + (size_t)l * 256, HID,
            N_NODES, 256, 128, 256, 1, FLAG);
        // delta = hid @ w2 + b2              (16384x256 @ 256x64)
        gemm_f32<<<dim3(1, 256), 256, 0, stream>>>(
            HID, CV + CV_W2 + (size_t)l * 256 * 64,
            CV + CV_B2 + (size_t)l * 64, DELTA,
            N_NODES, 64, 256, 64, 0);
        tn_lsep_kernel<<<1, 64, 0, stream>>>(CV + CV_TPHI + (size_t)l * 64, TN, ACC);
        deltaik_kernel<<<dim3(N_NODES * 64 / 256), 256, 0, stream>>>(DELTA, TN, ACC + 1);
        edge_agg_kernel<<<dim3(N_NODES), 64, 0, stream>>>(
            HK, PHI, DELTA, src_l, CV + CV_BIAS + (size_t)l * 64,
            OUTS + (size_t)l * N_NODES * 64);
    }

    fuse_kernel<<<dim3(N_NODES / 4), 256, 0, stream>>>(OUTS, CV + CV_Z, d_out, FLAG);
    final_kernel<<<1, 64, 0, stream>>>(ACC, d_out, FLAG);
}

// Round 3
// 771.662 us; speedup vs baseline: 2.1404x; 2.1404x over previous
//
#include <hip/hip_runtime.h>
#include <hip/hip_bf16.h>

#define N_NODES 16384
#define K_NBR 16
#define HOPS 4
#define IN_DIM 256
#define RAW_DIM 128
#define OUT_DIM 64
#define PHI_DIM 16
#define N_KERN 4
#define E_EDGES (N_NODES * K_NBR)

typedef __hip_bfloat16 bf16;

__device__ __forceinline__ float toF(float x) { return x; }
__device__ __forceinline__ float toF(bf16 x) { return __bfloat162float(x); }

// --------------------------- workspace layout (floats) ---------------------
#define CV_WPHI 0
#define CV_W1   (CV_WPHI + HOPS * RAW_DIM * (PHI_DIM - 1))
#define CV_B1   (CV_W1 + HOPS * RAW_DIM * IN_DIM)
#define CV_W2   (CV_B1 + HOPS * IN_DIM)
#define CV_B2   (CV_W2 + HOPS * IN_DIM * PHI_DIM * N_KERN)
#define CV_TPHI (CV_B2 + HOPS * PHI_DIM * N_KERN)
#define CV_W    (CV_TPHI + HOPS * N_KERN * PHI_DIM)
#define CV_BIAS (CV_W + HOPS * IN_DIM * OUT_DIM * N_KERN)
#define CV_Z    (CV_BIAS + HOPS * OUT_DIM)
#define CV_END  (CV_Z + OUT_DIM)

// ---------------------------------------------------------------------------
// dtype detection: read h as bf16. Real bf16 -> max|v| ~ 4. f32 read as bf16
// halves -> garbage exponents, max >> 1e4.  *flag = 1 means inputs are bf16.
// ---------------------------------------------------------------------------
__global__ void detect_kernel(const void* __restrict__ h, int* __restrict__ flag)
{
    __shared__ float red[256];
    int t = threadIdx.x;
    const unsigned short* p = (const unsigned short*)h;
    float mx = 0.f;
    for (int i = t; i < 2048; i += 256) {
        unsigned int bits = ((unsigned int)p[i]) << 16;
        float v;
        __builtin_memcpy(&v, &bits, 4);
        v = fabsf(v);
        if (!(v == v) || v > 1e30f) v = 1e30f;
        mx = fmaxf(mx, v);
    }
    red[t] = mx;
    __syncthreads();
    for (int s = 128; s > 0; s >>= 1) {
        if (t < s) red[t] = fmaxf(red[t], red[t + s]);
        __syncthreads();
    }
    if (t == 0) *flag = (red[0] < 1e4f) ? 1 : 0;
}

__device__ __forceinline__ float loadDyn(const void* p, int i, bool isbf)
{
    return isbf ? toF(((const bf16*)p)[i]) : ((const float*)p)[i];
}

// Convert the 9 small weight tensors into one contiguous f32 region.
__global__ __launch_bounds__(256) void cvt_small_kernel(
    const void* wphi, const void* w1, const void* b1, const void* w2,
    const void* b2, const void* tphi, const void* W, const void* bias,
    const void* z, float* __restrict__ dst, const int* __restrict__ flag)
{
    int idx = blockIdx.x * 256 + threadIdx.x;
    if (idx >= CV_END) return;
    bool isbf = (*flag != 0);
    float v;
    if      (idx < CV_W1)   v = loadDyn(wphi, idx - CV_WPHI, isbf);
    else if (idx < CV_B1)   v = loadDyn(w1,   idx - CV_W1,   isbf);
    else if (idx < CV_W2)   v = loadDyn(b1,   idx - CV_B1,   isbf);
    else if (idx < CV_B2)   v = loadDyn(w2,   idx - CV_W2,   isbf);
    else if (idx < CV_TPHI) v = loadDyn(b2,   idx - CV_B2,   isbf);
    else if (idx < CV_W)    v = loadDyn(tphi, idx - CV_TPHI, isbf);
    else if (idx < CV_BIAS) v = loadDyn(W,    idx - CV_W,    isbf);
    else if (idx < CV_Z)    v = loadDyn(bias, idx - CV_BIAS, isbf);
    else                    v = loadDyn(z,    idx - CV_Z,    isbf);
    dst[idx] = v;
}

// ---------------------------------------------------------------------------
// Tiled GEMM body: C(f32, M x ldc) = [relu]( A(M x K) @ B(K x N) + bias )
// 64x64 tile, BK=16, 256 threads, 4x4 micro-tile per thread. B/bias are f32.
// ---------------------------------------------------------------------------
template <typename TA>
__device__ void gemm_body(const TA* __restrict__ A, const float* __restrict__ B,
                          const float* __restrict__ bias, float* __restrict__ C,
                          int M, int N, int K, int ldc, int relu)
{
    __shared__ float As[16][65];
    __shared__ float Bs[16][65];
    int tid = threadIdx.x;
    int rowBase = blockIdx.y * 64;
    int colBase = blockIdx.x * 64;
    int tx = tid & 15, ty = tid >> 4;
    float acc[4][4] = {};

    int la_r = tid >> 2;
    int la_c = (tid & 3) << 2;
    int lb_r = tid >> 4;
    int lb_c = (tid & 15) << 2;

    for (int k0 = 0; k0 < K; k0 += 16) {
        const TA* ap = A + (size_t)(rowBase + la_r) * K + (k0 + la_c);
        As[la_c + 0][la_r] = toF(ap[0]);
        As[la_c + 1][la_r] = toF(ap[1]);
        As[la_c + 2][la_r] = toF(ap[2]);
        As[la_c + 3][la_r] = toF(ap[3]);
        const float* bp = B + (size_t)(k0 + lb_r) * N + (colBase + lb_c);
#pragma unroll
        for (int j = 0; j < 4; j++) {
            int c = colBase + lb_c + j;
            Bs[lb_r][lb_c + j] = (c < N) ? bp[j] : 0.f;
        }
        __syncthreads();
#pragma unroll
        for (int kk = 0; kk < 16; kk++) {
            float a[4], b[4];
#pragma unroll
            for (int i = 0; i < 4; i++) a[i] = As[kk][(ty << 2) + i];
#pragma unroll
            for (int j = 0; j < 4; j++) b[j] = Bs[kk][(tx << 2) + j];
#pragma unroll
            for (int i = 0; i < 4; i++)
#pragma unroll
                for (int j = 0; j < 4; j++) acc[i][j] += a[i] * b[j];
        }
        __syncthreads();
    }
#pragma unroll
    for (int i = 0; i < 4; i++) {
        int r = rowBase + (ty << 2) + i;
#pragma unroll
        for (int j = 0; j < 4; j++) {
            int c = colBase + (tx << 2) + j;
            if (c < N) {
                float v = acc[i][j];
                if (bias) v += bias[c];
                if (relu) v = fmaxf(v, 0.f);
                C[(size_t)r * ldc + c] = v;
            }
        }
    }
}

// Dual-pointer GEMM: selects bf16 or f32 A pointer by *flag (block-uniform).
__global__ __launch_bounds__(256) void gemm_dyn2(
    const void* __restrict__ A_bf, const void* __restrict__ A_f32,
    const float* __restrict__ B, const float* __restrict__ bias,
    float* __restrict__ C, int M, int N, int K, int ldc, int relu,
    const int* __restrict__ flag)
{
    if (*flag != 0) gemm_body<bf16>((const bf16*)A_bf, B, bias, C, M, N, K, ldc, relu);
    else            gemm_body<float>((const float*)A_f32, B, bias, C, M, N, K, ldc, relu);
}

// ---------------------------------------------------------------------------
// Fused delta GEMM: DELTA(N_NODES x 64) = HID @ w2 + b2, then
//   l_focus partial: block-sum of delta^2 -> ONE atomic per block
//   DELTA <- delta + tn[col]   (the delta_ik the edge kernel consumes)
// grid (1, 256): colBase = 0, N = 64, K = 256 fixed.
// ---------------------------------------------------------------------------
__global__ __launch_bounds__(256) void gemm_delta(
    const float* __restrict__ A, const float* __restrict__ B,
    const float* __restrict__ bias, const float* __restrict__ tn,
    float* __restrict__ C, float* __restrict__ lfocus_acc)
{
    __shared__ float As[16][65];
    __shared__ float Bs[16][65];
    __shared__ float s_red[256];
    int tid = threadIdx.x;
    int rowBase = blockIdx.y * 64;
    int tx = tid & 15, ty = tid >> 4;
    float acc[4][4] = {};

    int la_r = tid >> 2;
    int la_c = (tid & 3) << 2;
    int lb_r = tid >> 4;
    int lb_c = (tid & 15) << 2;

    for (int k0 = 0; k0 < 256; k0 += 16) {
        const float* ap = A + (size_t)(rowBase + la_r) * 256 + (k0 + la_c);
        As[la_c + 0][la_r] = ap[0];
        As[la_c + 1][la_r] = ap[1];
        As[la_c + 2][la_r] = ap[2];
        As[la_c + 3][la_r] = ap[3];
        const float* bp = B + (size_t)(k0 + lb_r) * 64 + lb_c;
#pragma unroll
        for (int j = 0; j < 4; j++) Bs[lb_r][lb_c + j] = bp[j];
        __syncthreads();
#pragma unroll
        for (int kk = 0; kk < 16; kk++) {
            float a[4], b[4];
#pragma unroll
            for (int i = 0; i < 4; i++) a[i] = As[kk][(ty << 2) + i];
#pragma unroll
            for (int j = 0; j < 4; j++) b[j] = Bs[kk][(tx << 2) + j];
#pragma unroll
            for (int i = 0; i < 4; i++)
#pragma unroll
                for (int j = 0; j < 4; j++) acc[i][j] += a[i] * b[j];
        }
        __syncthreads();
    }

    float sq = 0.f;
#pragma unroll
    for (int i = 0; i < 4; i++) {
        int r = rowBase + (ty << 2) + i;
#pragma unroll
        for (int j = 0; j < 4; j++) {
            int c = (tx << 2) + j;
            float v = acc[i][j] + bias[c];
            sq += v * v;
            C[(size_t)r * 64 + c] = v + tn[c];
        }
    }
    s_red[tid] = sq;
    __syncthreads();
    for (int s = 128; s > 0; s >>= 1) {
        if (tid < s) s_red[tid] += s_red[tid + s];
        __syncthreads();
    }
    if (tid == 0) atomicAdd(lfocus_acc, s_red[0]);
}

// ---------------------------------------------------------------------------
// tn = row-normalized tilde_phi (no epsilon), accumulate l_sep. 64 threads.
// ---------------------------------------------------------------------------
__global__ void tn_lsep_kernel(const float* __restrict__ tphi_l,
                               float* __restrict__ tn_out, float* __restrict__ acc)
{
    __shared__ float s_v[64], s_tn[64], s_red[64];
    int t = threadIdx.x;
    int row = t >> 4, p = t & 15;
    float v = tphi_l[t];
    s_v[t] = v;
    __syncthreads();
    float ss = 0.f;
    for (int q = 0; q < 16; q++) { float x = s_v[row * 16 + q]; ss += x * x; }
    float tnv = v / sqrtf(ss);
    tn_out[t] = tnv;
    s_tn[t] = tnv;
    __syncthreads();
    float s = 0.f;
    for (int j = 0; j < 4; j++) { float d = tnv - s_tn[j * 16 + p]; s += d * d; }
    s_red[t] = s;
    __syncthreads();
    if (t == 0) {
        float tot = 0.f;
        for (int i = 0; i < 64; i++) tot += s_red[i];
        atomicAdd(acc, tot * 0.25f);
    }
}

// ---------------------------------------------------------------------------
// Per-dst-node: dist -> logits -> edge softmax -> aggregation -> bias ->
// row-normalize. One 64-thread block per node (edges contiguous in memory).
// ---------------------------------------------------------------------------
__global__ __launch_bounds__(64) void edge_agg_kernel(
    const float* __restrict__ hk, const float* __restrict__ phi,
    const float* __restrict__ dik, const int* __restrict__ src_l,
    const float* __restrict__ bias_l, float* __restrict__ outs_l)
{
    int node = blockIdx.x;
    int tid = threadIdx.x;
    __shared__ float s_phi[15];
    __shared__ float s_dik[64];
    __shared__ int s_src[16];
    __shared__ float s_att[16][4];

    s_dik[tid] = dik[(size_t)node * 64 + tid];
    if (tid < 16) s_src[tid] = src_l[(size_t)node * 16 + tid];
    if (tid < 15) s_phi[tid] = phi[(size_t)node * 16 + tid];
    __syncthreads();

    // stage 1: per-(edge e, kernel k) logit
    int e = tid >> 2, k = tid & 3;
    int s = s_src[e];
    float dist[16];
    float ss = 0.f;
    bool allz = true;
    for (int p = 0; p < 15; p++) {
        float d = phi[(size_t)s * 16 + p] - s_phi[p];
        dist[p] = d;
        ss += d * d;
        if (d != 0.f) allz = false;
    }
    float last = allz ? 1.f : 0.f;
    dist[15] = last;
    ss += last * last;
    float inv = 1.f / fmaxf(sqrtf(ss), 1e-8f);
    float lg = 0.f;
    for (int p = 0; p < 16; p++) lg += dist[p] * inv * s_dik[k * 16 + p];
    s_att[e][k] = lg;
    __syncthreads();

    // stage 2: softmax over 16 edges for this k
    float mx = -1e30f;
    for (int ee = 0; ee < 16; ee++) mx = fmaxf(mx, s_att[ee][k]);
    float den = 0.f;
    for (int ee = 0; ee < 16; ee++) den += expf(s_att[ee][k] - mx);
    float att = expf(lg - mx) / den;
    __syncthreads();
    s_att[e][k] = att;
    __syncthreads();

    // stage 3: aggregation; thread = output dim
    float accv[4] = {0.f, 0.f, 0.f, 0.f};
    for (int ee = 0; ee < 16; ee++) {
        const float* hr = hk + (size_t)s_src[ee] * 256 + tid;
#pragma unroll
        for (int kk = 0; kk < 4; kk++) accv[kk] += s_att[ee][kk] * hr[kk * 64];
    }
    float o = accv[0] + accv[1] + accv[2] + accv[3] + bias_l[tid];

    // stage 4: row-normalize (full-wave shuffles)
    float s2 = o * o;
#pragma unroll
    for (int off = 32; off > 0; off >>= 1) s2 += __shfl_xor(s2, off);
    o /= fmaxf(sqrtf(s2), 1e-8f);
    outs_l[(size_t)node * 64 + tid] = o;
}

// Hop fusion + output store (dtype by flag).
__global__ __launch_bounds__(256) void fuse_kernel(
    const float* __restrict__ outs, const float* __restrict__ z,
    void* __restrict__ out, const int* __restrict__ flag)
{
    int tid = threadIdx.x;
    int node = blockIdx.x * 4 + (tid >> 6);
    int dd = tid & 63;
    float zv = z[dd];
    float o[4], sc[4];
#pragma unroll
    for (int h = 0; h < 4; h++) {
        o[h] = outs[((size_t)h * N_NODES + node) * 64 + dd];
        float v = o[h] * zv;
#pragma unroll
        for (int off = 32; off > 0; off >>= 1) v += __shfl_xor(v, off);
        sc[h] = v;
    }
    float mx = fmaxf(fmaxf(sc[0], sc[1]), fmaxf(sc[2], sc[3]));
    float e0 = expf(sc[0] - mx), e1 = expf(sc[1] - mx);
    float e2 = expf(sc[2] - mx), e3 = expf(sc[3] - mx);
    float den = e0 + e1 + e2 + e3;
    float t = (e0 * o[0] + e1 * o[1] + e2 * o[2] + e3 * o[3]) / den;
    size_t oi = (size_t)node * 64 + dd;
    if (*flag != 0) ((bf16*)out)[oi] = __float2bfloat16(t);
    else            ((float*)out)[oi] = t;
}

__global__ void init_kernel(float* acc)
{
    if (threadIdx.x < 2) acc[threadIdx.x] = 0.f;
}

__global__ void final_kernel(const float* __restrict__ acc, void* __restrict__ out,
                             const int* __restrict__ flag)
{
    if (threadIdx.x == 0) {
        float a = acc[0] * 0.25f;
        float b = acc[1] / ((float)N_NODES * 4.f * 4.f);
        size_t base = (size_t)N_NODES * 64;
        if (*flag != 0) {
            ((bf16*)out)[base]     = __float2bfloat16(a);
            ((bf16*)out)[base + 1] = __float2bfloat16(b);
        } else {
            ((float*)out)[base]     = a;
            ((float*)out)[base + 1] = b;
        }
    }
}

extern "C" void kernel_launch(void* const* d_in, const int* in_sizes, int n_in,
                              void* d_out, int out_size, void* d_ws, size_t ws_size,
                              hipStream_t stream)
{
    const void* h    = d_in[0];
    const void* e    = d_in[1];
    const int*  src  = (const int*)d_in[2];
    const void* Wphi = d_in[4];
    const void* w1   = d_in[5];
    const void* b1   = d_in[6];
    const void* w2   = d_in[7];
    const void* b2   = d_in[8];
    const void* tphi = d_in[9];
    const void* W    = d_in[10];
    const void* bias = d_in[11];
    const void* z    = d_in[12];

    float* ws    = (float*)d_ws;
    float* CV    = ws;
    float* OUTS  = CV + CV_END;
    float* HK    = OUTS + (size_t)4 * N_NODES * 64;
    float* HID   = HK + (size_t)N_NODES * 256;
    float* PHI   = HID + (size_t)N_NODES * 256;
    float* DELTA = PHI + (size_t)N_NODES * 16;
    float* TN    = DELTA + (size_t)N_NODES * 64;
    float* ACC   = TN + 64;
    int*   FLAG  = (int*)(ACC + 2);

    detect_kernel<<<1, 256, 0, stream>>>(h, FLAG);
    init_kernel<<<1, 64, 0, stream>>>(ACC);
    cvt_small_kernel<<<(CV_END + 255) / 256, 256, 0, stream>>>(
        Wphi, w1, b1, w2, b2, tphi, W, bias, z, CV, FLAG);

    for (int l = 0; l < HOPS; l++) {
        const int* src_l = src + (size_t)l * E_EDGES;
        size_t eoff = (size_t)l * N_NODES * RAW_DIM;
        const void* e_bf  = (const void*)((const bf16*)e + eoff);
        const void* e_f32 = (const void*)((const float*)e + eoff);

        // tn + l_sep (needed by gemm_delta epilogue)
        tn_lsep_kernel<<<1, 64, 0, stream>>>(CV + CV_TPHI + (size_t)l * 64, TN, ACC);
        // hk = h @ W_l                       (16384x256 @ 256x256)
        gemm_dyn2<<<dim3(4, 256), 256, 0, stream>>>(
            h, h, CV + CV_W + (size_t)l * 256 * 256, nullptr, HK,
            N_NODES, 256, 256, 256, 0, FLAG);
        // phi = e_l @ Wphi_l                 (16384x128 @ 128x15, ldc 16)
        gemm_dyn2<<<dim3(1, 256), 256, 0, stream>>>(
            e_bf, e_f32, CV + CV_WPHI + (size_t)l * 128 * 15, nullptr, PHI,
            N_NODES, 15, 128, 16, 0, FLAG);
        // hid = relu(e_l @ w1 + b1)          (16384x128 @ 128x256)
        gemm_dyn2<<<dim3(4, 256), 256, 0, stream>>>(
            e_bf, e_f32, CV + CV_W1 + (size_t)l * 128 * 256,
            CV + CV_B1 + (size_t)l * 256, HID,
            N_NODES, 256, 128, 256, 1, FLAG);
        // delta = hid @ w2 + b2; DELTA = delta + tn; l_focus partial (fused)
        gemm_delta<<<dim3(1, 256), 256, 0, stream>>>(
            HID, CV + CV_W2 + (size_t)l * 256 * 64,
            CV + CV_B2 + (size_t)l * 64, TN, DELTA, ACC + 1);
        // per-node edge softmax + aggregation + normalize
        edge_agg_kernel<<<dim3(N_NODES), 64, 0, stream>>>(
            HK, PHI, DELTA, src_l, CV + CV_BIAS + (size_t)l * 64,
            OUTS + (size_t)l * N_NODES * 64);
    }

    fuse_kernel<<<dim3(N_NODES / 4), 256, 0, stream>>>(OUTS, CV + CV_Z, d_out, FLAG);
    final_kernel<<<1, 64, 0, stream>>>(ACC, d_out, FLAG);
}

// Round 4
// 466.740 us; speedup vs baseline: 3.5388x; 1.6533x over previous
//
#include <hip/hip_runtime.h>
#include <hip/hip_bf16.h>

#define N_NODES 16384
#define K_NBR 16
#define HOPS 4
#define IN_DIM 256
#define RAW_DIM 128
#define OUT_DIM 64
#define PHI_DIM 16
#define N_KERN 4
#define E_EDGES (N_NODES * K_NBR)

typedef __hip_bfloat16 bf16;
typedef __attribute__((ext_vector_type(8))) short short8;
typedef __attribute__((ext_vector_type(4))) float f32x4;

__device__ __forceinline__ float toF(float x) { return x; }
__device__ __forceinline__ float toF(bf16 x) { return __bfloat162float(x); }

// --------------------------- f32 workspace layout --------------------------
#define CV_WPHI 0
#define CV_W1   (CV_WPHI + HOPS * RAW_DIM * (PHI_DIM - 1))
#define CV_B1   (CV_W1 + HOPS * RAW_DIM * IN_DIM)
#define CV_W2   (CV_B1 + HOPS * IN_DIM)
#define CV_B2   (CV_W2 + HOPS * IN_DIM * PHI_DIM * N_KERN)
#define CV_TPHI (CV_B2 + HOPS * PHI_DIM * N_KERN)
#define CV_W    (CV_TPHI + HOPS * N_KERN * PHI_DIM)
#define CV_BIAS (CV_W + HOPS * IN_DIM * OUT_DIM * N_KERN)
#define CV_Z    (CV_BIAS + HOPS * OUT_DIM)
#define CV_END  (CV_Z + OUT_DIM)

// transposed bf16 weight region sizes
#define WT_N  (HOPS * 256 * 256)
#define W1T_N (HOPS * 256 * 128)
#define W2T_N (HOPS * 64 * 256)
#define WPT_N (HOPS * 16 * 128)
#define CVT_TOTAL (WT_N + W1T_N + W2T_N + WPT_N)

// ---------------------------------------------------------------------------
// dtype detection: read h as bf16. Real bf16 -> max|v| ~ 4. f32 read as bf16
// halves -> garbage exponents, max >> 1e4.  *flag = 1 means inputs are bf16.
// ---------------------------------------------------------------------------
__global__ void detect_kernel(const void* __restrict__ h, int* __restrict__ flag)
{
    __shared__ float red[256];
    int t = threadIdx.x;
    const unsigned short* p = (const unsigned short*)h;
    float mx = 0.f;
    for (int i = t; i < 2048; i += 256) {
        unsigned int bits = ((unsigned int)p[i]) << 16;
        float v;
        __builtin_memcpy(&v, &bits, 4);
        v = fabsf(v);
        if (!(v == v) || v > 1e30f) v = 1e30f;
        mx = fmaxf(mx, v);
    }
    red[t] = mx;
    __syncthreads();
    for (int s = 128; s > 0; s >>= 1) {
        if (t < s) red[t] = fmaxf(red[t], red[t + s]);
        __syncthreads();
    }
    if (t == 0) *flag = (red[0] < 1e4f) ? 1 : 0;
}

__device__ __forceinline__ float loadDyn(const void* p, int i, bool isbf)
{
    return isbf ? toF(((const bf16*)p)[i]) : ((const float*)p)[i];
}

// Convert the 9 small weight tensors into one contiguous f32 region.
__global__ __launch_bounds__(256) void cvt_small_kernel(
    const void* wphi, const void* w1, const void* b1, const void* w2,
    const void* b2, const void* tphi, const void* W, const void* bias,
    const void* z, float* __restrict__ dst, const int* __restrict__ flag)
{
    int idx = blockIdx.x * 256 + threadIdx.x;
    if (idx >= CV_END) return;
    bool isbf = (*flag != 0);
    float v;
    if      (idx < CV_W1)   v = loadDyn(wphi, idx - CV_WPHI, isbf);
    else if (idx < CV_B1)   v = loadDyn(w1,   idx - CV_W1,   isbf);
    else if (idx < CV_W2)   v = loadDyn(b1,   idx - CV_B1,   isbf);
    else if (idx < CV_B2)   v = loadDyn(w2,   idx - CV_W2,   isbf);
    else if (idx < CV_TPHI) v = loadDyn(b2,   idx - CV_B2,   isbf);
    else if (idx < CV_W)    v = loadDyn(tphi, idx - CV_TPHI, isbf);
    else if (idx < CV_BIAS) v = loadDyn(W,    idx - CV_W,    isbf);
    else if (idx < CV_Z)    v = loadDyn(bias, idx - CV_BIAS, isbf);
    else                    v = loadDyn(z,    idx - CV_Z,    isbf);
    dst[idx] = v;
}

// Generic dyn -> bf16 conversion (same layout).
__global__ __launch_bounds__(256) void cvt_bf_kernel(
    bf16* __restrict__ dst, const void* __restrict__ src, size_t srcOff,
    int n, const int* __restrict__ flag)
{
    int i = blockIdx.x * 256 + threadIdx.x;
    if (i >= n) return;
    bool isbf = (*flag != 0);
    float v = isbf ? toF(((const bf16*)src)[srcOff + i])
                   : ((const float*)src)[srcOff + i];
    dst[i] = __float2bfloat16(v);
}

// Transposed bf16 weights: Wt (N x K) from W (K x N), per hop.
// Wphi^T is zero-padded from 15 to 16 output rows.
__global__ __launch_bounds__(256) void cvt_wt_kernel(
    const void* W, const void* w1, const void* w2, const void* wphi,
    bf16* __restrict__ wt, bf16* __restrict__ w1t, bf16* __restrict__ w2t,
    bf16* __restrict__ wpt, const int* __restrict__ flag)
{
    int idx = blockIdx.x * 256 + threadIdx.x;
    if (idx >= CVT_TOTAL) return;
    bool isbf = (*flag != 0);
    if (idx < WT_N) {                      // 256N x 256K per hop
        int o = idx, hop = o >> 16, rem = o & 65535, n = rem >> 8, k = rem & 255;
        wt[o] = __float2bfloat16(loadDyn(W, hop * 65536 + k * 256 + n, isbf));
    } else if (idx < WT_N + W1T_N) {       // 256N x 128K per hop
        int o = idx - WT_N, hop = o >> 15, rem = o & 32767, n = rem >> 7, k = rem & 127;
        w1t[o] = __float2bfloat16(loadDyn(w1, hop * 32768 + k * 256 + n, isbf));
    } else if (idx < WT_N + W1T_N + W2T_N) { // 64N x 256K per hop
        int o = idx - WT_N - W1T_N, hop = o >> 14, rem = o & 16383, n = rem >> 8, k = rem & 255;
        w2t[o] = __float2bfloat16(loadDyn(w2, hop * 16384 + k * 64 + n, isbf));
    } else {                               // 16N x 128K per hop (row 15 zero)
        int o = idx - WT_N - W1T_N - W2T_N, hop = o >> 11, rem = o & 2047, n = rem >> 7, k = rem & 127;
        float v = (n < 15) ? loadDyn(wphi, hop * 1920 + k * 15 + n, isbf) : 0.f;
        wpt[o] = __float2bfloat16(v);
    }
}

// ---------------------------------------------------------------------------
// MFMA GEMM: C = [relu](A @ B + bias), A (M x K) bf16 row-major,
// Bt (N x K) bf16 row-major (= B transposed). BM=128, BK=64, BN template.
// 256 threads = 4 waves arranged WR x WC. 16x16x32 bf16 MFMA.
// Optional: f32 out Cf (+tn per col), bf16 out Cbf, l_focus accumulation.
// Fragment layouts (HW-verified): A[m=lane&15][k=quad*8+j],
// B[k=quad*8+j][n=lane&15] (from Bt rows), C/D col=lane&15,row=quad*4+reg.
// ---------------------------------------------------------------------------
template <int BN, int WR, int WC>
__global__ __launch_bounds__(256) void mfma_gemm(
    const bf16* __restrict__ A, const bf16* __restrict__ Bt,
    const float* __restrict__ bias, const float* __restrict__ tn,
    float* __restrict__ Cf, bf16* __restrict__ Cbf,
    float* __restrict__ lfocus, int K, int N, int relu)
{
    constexpr int WM = 128 / WR;
    constexpr int WN = BN / WC;
    constexpr int MT = WM / 16;
    constexpr int NT = WN / 16;
    __shared__ short As[128 * 72];   // bf16 bits, row stride 72 (pad 8)
    __shared__ short Bs[BN * 72];
    __shared__ float s_w[4];

    int tid = threadIdx.x;
    int w = tid >> 6, lane = tid & 63;
    int wr = w / WC, wc = w % WC;
    int l16 = lane & 15, quad = lane >> 4;
    int rowBase = blockIdx.y * 128, colBase = blockIdx.x * BN;

    f32x4 acc[MT][NT] = {};

    for (int k0 = 0; k0 < K; k0 += 64) {
        // stage A tile (128 x 64) : 16B chunks, 8 per row
        for (int c = tid; c < 128 * 8; c += 256) {
            int row = c >> 3, c8 = c & 7;
            short8 v = *(const short8*)(A + (size_t)(rowBase + row) * K + k0 + c8 * 8);
            *(short8*)&As[row * 72 + c8 * 8] = v;
        }
        // stage Bt tile (BN x 64)
        for (int c = tid; c < BN * 8; c += 256) {
            int row = c >> 3, c8 = c & 7;
            short8 v = *(const short8*)(Bt + (size_t)(colBase + row) * K + k0 + c8 * 8);
            *(short8*)&Bs[row * 72 + c8 * 8] = v;
        }
        __syncthreads();
#pragma unroll
        for (int kc = 0; kc < 64; kc += 32) {
            short8 aF[MT], bF[NT];
#pragma unroll
            for (int mi = 0; mi < MT; mi++)
                aF[mi] = *(const short8*)&As[(wr * WM + mi * 16 + l16) * 72 + kc + quad * 8];
#pragma unroll
            for (int ni = 0; ni < NT; ni++)
                bF[ni] = *(const short8*)&Bs[(wc * WN + ni * 16 + l16) * 72 + kc + quad * 8];
#pragma unroll
            for (int mi = 0; mi < MT; mi++)
#pragma unroll
                for (int ni = 0; ni < NT; ni++)
                    acc[mi][ni] = __builtin_amdgcn_mfma_f32_16x16x32_bf16(
                        aF[mi], bF[ni], acc[mi][ni], 0, 0, 0);
        }
        __syncthreads();
    }

    // epilogue
    float sq = 0.f;
#pragma unroll
    for (int mi = 0; mi < MT; mi++) {
#pragma unroll
        for (int ni = 0; ni < NT; ni++) {
            int col = colBase + wc * WN + ni * 16 + l16;
            float bv = bias ? bias[col] : 0.f;
#pragma unroll
            for (int r = 0; r < 4; r++) {
                int row = rowBase + wr * WM + mi * 16 + quad * 4 + r;
                float v = acc[mi][ni][r] + bv;
                if (relu) v = fmaxf(v, 0.f);
                sq += v * v;
                if (Cf)  Cf[(size_t)row * N + col] = tn ? (v + tn[col]) : v;
                if (Cbf) Cbf[(size_t)row * N + col] = __float2bfloat16(v);
            }
        }
    }
    if (lfocus) {
#pragma unroll
        for (int off = 32; off > 0; off >>= 1) sq += __shfl_xor(sq, off);
        if (lane == 0) s_w[w] = sq;
        __syncthreads();
        if (tid == 0) atomicAdd(lfocus, s_w[0] + s_w[1] + s_w[2] + s_w[3]);
    }
}

// ---------------------------------------------------------------------------
// tn = row-normalized tilde_phi (no epsilon), accumulate l_sep. 64 threads.
// ---------------------------------------------------------------------------
__global__ void tn_lsep_kernel(const float* __restrict__ tphi_l,
                               float* __restrict__ tn_out, float* __restrict__ acc)
{
    __shared__ float s_v[64], s_tn[64], s_red[64];
    int t = threadIdx.x;
    int row = t >> 4, p = t & 15;
    float v = tphi_l[t];
    s_v[t] = v;
    __syncthreads();
    float ss = 0.f;
    for (int q = 0; q < 16; q++) { float x = s_v[row * 16 + q]; ss += x * x; }
    float tnv = v / sqrtf(ss);
    tn_out[t] = tnv;
    s_tn[t] = tnv;
    __syncthreads();
    float s = 0.f;
    for (int j = 0; j < 4; j++) { float d = tnv - s_tn[j * 16 + p]; s += d * d; }
    s_red[t] = s;
    __syncthreads();
    if (t == 0) {
        float tot = 0.f;
        for (int i = 0; i < 64; i++) tot += s_red[i];
        atomicAdd(acc, tot * 0.25f);
    }
}

// ---------------------------------------------------------------------------
// Per-dst-node: dist -> logits -> edge softmax -> aggregation -> bias ->
// row-normalize. One 64-thread block per node (edges contiguous). hk is bf16.
// ---------------------------------------------------------------------------
__global__ __launch_bounds__(64) void edge_agg_kernel(
    const bf16* __restrict__ hk, const float* __restrict__ phi,
    const float* __restrict__ dik, const int* __restrict__ src_l,
    const float* __restrict__ bias_l, float* __restrict__ outs_l)
{
    int node = blockIdx.x;
    int tid = threadIdx.x;
    __shared__ float s_phi[15];
    __shared__ float s_dik[64];
    __shared__ int s_src[16];
    __shared__ float s_att[16][4];

    s_dik[tid] = dik[(size_t)node * 64 + tid];
    if (tid < 16) s_src[tid] = src_l[(size_t)node * 16 + tid];
    if (tid < 15) s_phi[tid] = phi[(size_t)node * 16 + tid];
    __syncthreads();

    // stage 1: per-(edge e, kernel k) logit
    int e = tid >> 2, k = tid & 3;
    int s = s_src[e];
    float dist[16];
    float ss = 0.f;
    bool allz = true;
    for (int p = 0; p < 15; p++) {
        float d = phi[(size_t)s * 16 + p] - s_phi[p];
        dist[p] = d;
        ss += d * d;
        if (d != 0.f) allz = false;
    }
    float last = allz ? 1.f : 0.f;
    dist[15] = last;
    ss += last * last;
    float inv = 1.f / fmaxf(sqrtf(ss), 1e-8f);
    float lg = 0.f;
    for (int p = 0; p < 16; p++) lg += dist[p] * inv * s_dik[k * 16 + p];
    s_att[e][k] = lg;
    __syncthreads();

    // stage 2: softmax over 16 edges for this k
    float mx = -1e30f;
    for (int ee = 0; ee < 16; ee++) mx = fmaxf(mx, s_att[ee][k]);
    float den = 0.f;
    for (int ee = 0; ee < 16; ee++) den += expf(s_att[ee][k] - mx);
    float att = expf(lg - mx) / den;
    __syncthreads();
    s_att[e][k] = att;
    __syncthreads();

    // stage 3: aggregation; thread = output dim
    float accv[4] = {0.f, 0.f, 0.f, 0.f};
    for (int ee = 0; ee < 16; ee++) {
        const bf16* hr = hk + (size_t)s_src[ee] * 256 + tid;
#pragma unroll
        for (int kk = 0; kk < 4; kk++) accv[kk] += s_att[ee][kk] * toF(hr[kk * 64]);
    }
    float o = accv[0] + accv[1] + accv[2] + accv[3] + bias_l[tid];

    // stage 4: row-normalize
    float s2 = o * o;
#pragma unroll
    for (int off = 32; off > 0; off >>= 1) s2 += __shfl_xor(s2, off);
    o /= fmaxf(sqrtf(s2), 1e-8f);
    outs_l[(size_t)node * 64 + tid] = o;
}

// Hop fusion + output store (dtype by flag).
__global__ __launch_bounds__(256) void fuse_kernel(
    const float* __restrict__ outs, const float* __restrict__ z,
    void* __restrict__ out, const int* __restrict__ flag)
{
    int tid = threadIdx.x;
    int node = blockIdx.x * 4 + (tid >> 6);
    int dd = tid & 63;
    float zv = z[dd];
    float o[4], sc[4];
#pragma unroll
    for (int h = 0; h < 4; h++) {
        o[h] = outs[((size_t)h * N_NODES + node) * 64 + dd];
        float v = o[h] * zv;
#pragma unroll
        for (int off = 32; off > 0; off >>= 1) v += __shfl_xor(v, off);
        sc[h] = v;
    }
    float mx = fmaxf(fmaxf(sc[0], sc[1]), fmaxf(sc[2], sc[3]));
    float e0 = expf(sc[0] - mx), e1 = expf(sc[1] - mx);
    float e2 = expf(sc[2] - mx), e3 = expf(sc[3] - mx);
    float den = e0 + e1 + e2 + e3;
    float t = (e0 * o[0] + e1 * o[1] + e2 * o[2] + e3 * o[3]) / den;
    size_t oi = (size_t)node * 64 + dd;
    if (*flag != 0) ((bf16*)out)[oi] = __float2bfloat16(t);
    else            ((float*)out)[oi] = t;
}

__global__ void init_kernel(float* acc)
{
    if (threadIdx.x < 2) acc[threadIdx.x] = 0.f;
}

__global__ void final_kernel(const float* __restrict__ acc, void* __restrict__ out,
                             const int* __restrict__ flag)
{
    if (threadIdx.x == 0) {
        float a = acc[0] * 0.25f;
        float b = acc[1] / ((float)N_NODES * 4.f * 4.f);
        size_t base = (size_t)N_NODES * 64;
        if (*flag != 0) {
            ((bf16*)out)[base]     = __float2bfloat16(a);
            ((bf16*)out)[base + 1] = __float2bfloat16(b);
        } else {
            ((float*)out)[base]     = a;
            ((float*)out)[base + 1] = b;
        }
    }
}

extern "C" void kernel_launch(void* const* d_in, const int* in_sizes, int n_in,
                              void* d_out, int out_size, void* d_ws, size_t ws_size,
                              hipStream_t stream)
{
    const void* h    = d_in[0];
    const void* e    = d_in[1];
    const int*  src  = (const int*)d_in[2];
    const void* Wphi = d_in[4];
    const void* w1   = d_in[5];
    const void* b1   = d_in[6];
    const void* w2   = d_in[7];
    const void* b2   = d_in[8];
    const void* tphi = d_in[9];
    const void* W    = d_in[10];
    const void* bias = d_in[11];
    const void* z    = d_in[12];

    float* ws    = (float*)d_ws;
    float* CV    = ws;                                  // CV_END
    float* OUTS  = CV + CV_END;                         // 4*16384*64
    float* PHI   = OUTS + (size_t)4 * N_NODES * 64;     // 16384*16
    float* DELTA = PHI + (size_t)N_NODES * 16;          // 16384*64
    float* TN    = DELTA + (size_t)N_NODES * 64;        // 64
    float* ACC   = TN + 64;                             // 2 (+pad to 4)
    int*   FLAG  = (int*)(ACC + 2);                     // 1 (+pad)
    // bf16 regions (16B-aligned: all prior sizes are multiples of 4 floats)
    bf16*  H_BF   = (bf16*)(ACC + 4);
    bf16*  E_BF   = H_BF + (size_t)N_NODES * 256;       // per-hop, reused
    bf16*  HK_BF  = E_BF + (size_t)N_NODES * 128;
    bf16*  HID_BF = HK_BF + (size_t)N_NODES * 256;
    bf16*  WT     = HID_BF + (size_t)N_NODES * 256;
    bf16*  W1T    = WT + WT_N;
    bf16*  W2T    = W1T + W1T_N;
    bf16*  WPT    = W2T + W2T_N;

    detect_kernel<<<1, 256, 0, stream>>>(h, FLAG);
    init_kernel<<<1, 64, 0, stream>>>(ACC);
    cvt_small_kernel<<<(CV_END + 255) / 256, 256, 0, stream>>>(
        Wphi, w1, b1, w2, b2, tphi, W, bias, z, CV, FLAG);
    cvt_bf_kernel<<<(N_NODES * 256 + 255) / 256, 256, 0, stream>>>(
        H_BF, h, 0, N_NODES * 256, FLAG);
    cvt_wt_kernel<<<(CVT_TOTAL + 255) / 256, 256, 0, stream>>>(
        W, w1, w2, Wphi, WT, W1T, W2T, WPT, FLAG);

    for (int l = 0; l < HOPS; l++) {
        const int* src_l = src + (size_t)l * E_EDGES;

        // e_l -> bf16 (reused buffer)
        cvt_bf_kernel<<<(N_NODES * 128 + 255) / 256, 256, 0, stream>>>(
            E_BF, e, (size_t)l * N_NODES * RAW_DIM, N_NODES * 128, FLAG);
        // tn + l_sep (needed by delta epilogue)
        tn_lsep_kernel<<<1, 64, 0, stream>>>(CV + CV_TPHI + (size_t)l * 64, TN, ACC);
        // hk = h @ W_l -> bf16               (16384x256 @ 256x256)
        mfma_gemm<128, 2, 2><<<dim3(2, 128), 256, 0, stream>>>(
            H_BF, WT + (size_t)l * 256 * 256, nullptr, nullptr,
            nullptr, HK_BF, nullptr, 256, 256, 0);
        // phi = e_l @ Wphi_l -> f32, ldc 16  (16384x128 @ 128x16pad)
        mfma_gemm<16, 4, 1><<<dim3(1, 128), 256, 0, stream>>>(
            E_BF, WPT + (size_t)l * 16 * 128, nullptr, nullptr,
            PHI, nullptr, nullptr, 128, 16, 0);
        // hid = relu(e_l @ w1 + b1) -> bf16  (16384x128 @ 128x256)
        mfma_gemm<128, 2, 2><<<dim3(2, 128), 256, 0, stream>>>(
            E_BF, W1T + (size_t)l * 256 * 128, CV + CV_B1 + (size_t)l * 256, nullptr,
            nullptr, HID_BF, nullptr, 128, 256, 1);
        // delta = hid @ w2 + b2; DELTA = delta + tn; l_focus (fused)
        mfma_gemm<64, 4, 1><<<dim3(1, 128), 256, 0, stream>>>(
            HID_BF, W2T + (size_t)l * 64 * 256, CV + CV_B2 + (size_t)l * 64, TN,
            DELTA, nullptr, ACC + 1, 256, 64, 0);
        // per-node edge softmax + aggregation + normalize
        edge_agg_kernel<<<dim3(N_NODES), 64, 0, stream>>>(
            HK_BF, PHI, DELTA, src_l, CV + CV_BIAS + (size_t)l * 64,
            OUTS + (size_t)l * N_NODES * 64);
    }

    fuse_kernel<<<dim3(N_NODES / 4), 256, 0, stream>>>(OUTS, CV + CV_Z, d_out, FLAG);
    final_kernel<<<1, 64, 0, stream>>>(ACC, d_out, FLAG);
}

// Round 5
// 322.038 us; speedup vs baseline: 5.1289x; 1.4493x over previous
//
#include <hip/hip_runtime.h>
#include <hip/hip_bf16.h>

#define N_NODES 16384
#define K_NBR 16
#define HOPS 4
#define IN_DIM 256
#define RAW_DIM 128
#define OUT_DIM 64
#define PHI_DIM 16
#define N_KERN 4
#define E_EDGES (N_NODES * K_NBR)

typedef __hip_bfloat16 bf16;
typedef __attribute__((ext_vector_type(8))) short short8;
typedef __attribute__((ext_vector_type(4))) short short4v;
typedef __attribute__((ext_vector_type(4))) float f32x4;

__device__ __forceinline__ float toF(float x) { return x; }
__device__ __forceinline__ float toF(bf16 x) { return __bfloat162float(x); }
__device__ __forceinline__ float bfb2f(short s)
{
    unsigned int u = ((unsigned int)(unsigned short)s) << 16;
    float f; __builtin_memcpy(&f, &u, 4); return f;
}

// --------------------------- f32 workspace layout --------------------------
#define CV_WPHI 0
#define CV_W1   (CV_WPHI + HOPS * RAW_DIM * (PHI_DIM - 1))
#define CV_B1   (CV_W1 + HOPS * RAW_DIM * IN_DIM)
#define CV_W2   (CV_B1 + HOPS * IN_DIM)
#define CV_B2   (CV_W2 + HOPS * IN_DIM * PHI_DIM * N_KERN)
#define CV_TPHI (CV_B2 + HOPS * PHI_DIM * N_KERN)
#define CV_W    (CV_TPHI + HOPS * N_KERN * PHI_DIM)
#define CV_BIAS (CV_W + HOPS * IN_DIM * OUT_DIM * N_KERN)
#define CV_Z    (CV_BIAS + HOPS * OUT_DIM)
#define CV_END  (CV_Z + OUT_DIM)

// transposed bf16 weight region sizes
#define WT_N  (HOPS * 256 * 256)
#define W1T_N (HOPS * 256 * 128)
#define W2T_N (HOPS * 64 * 256)
#define WPT_N (HOPS * 16 * 128)
#define CVT_TOTAL (WT_N + W1T_N + W2T_N + WPT_N)

// ---------------------------------------------------------------------------
// dtype detection: read h as bf16. Real bf16 -> max|v| ~ 4. f32 read as bf16
// halves -> garbage exponents, max >> 1e4.  *flag = 1 means inputs are bf16.
// ---------------------------------------------------------------------------
__global__ void detect_kernel(const void* __restrict__ h, int* __restrict__ flag)
{
    __shared__ float red[256];
    int t = threadIdx.x;
    const unsigned short* p = (const unsigned short*)h;
    float mx = 0.f;
    for (int i = t; i < 2048; i += 256) {
        unsigned int bits = ((unsigned int)p[i]) << 16;
        float v;
        __builtin_memcpy(&v, &bits, 4);
        v = fabsf(v);
        if (!(v == v) || v > 1e30f) v = 1e30f;
        mx = fmaxf(mx, v);
    }
    red[t] = mx;
    __syncthreads();
    for (int s = 128; s > 0; s >>= 1) {
        if (t < s) red[t] = fmaxf(red[t], red[t + s]);
        __syncthreads();
    }
    if (t == 0) *flag = (red[0] < 1e4f) ? 1 : 0;
}

__device__ __forceinline__ float loadDyn(const void* p, int i, bool isbf)
{
    return isbf ? toF(((const bf16*)p)[i]) : ((const float*)p)[i];
}

// Convert the 9 small weight tensors into one contiguous f32 region.
__global__ __launch_bounds__(256) void cvt_small_kernel(
    const void* wphi, const void* w1, const void* b1, const void* w2,
    const void* b2, const void* tphi, const void* W, const void* bias,
    const void* z, float* __restrict__ dst, const int* __restrict__ flag)
{
    int idx = blockIdx.x * 256 + threadIdx.x;
    if (idx >= CV_END) return;
    bool isbf = (*flag != 0);
    float v;
    if      (idx < CV_W1)   v = loadDyn(wphi, idx - CV_WPHI, isbf);
    else if (idx < CV_B1)   v = loadDyn(w1,   idx - CV_W1,   isbf);
    else if (idx < CV_W2)   v = loadDyn(b1,   idx - CV_B1,   isbf);
    else if (idx < CV_B2)   v = loadDyn(w2,   idx - CV_W2,   isbf);
    else if (idx < CV_TPHI) v = loadDyn(b2,   idx - CV_B2,   isbf);
    else if (idx < CV_W)    v = loadDyn(tphi, idx - CV_TPHI, isbf);
    else if (idx < CV_BIAS) v = loadDyn(W,    idx - CV_W,    isbf);
    else if (idx < CV_Z)    v = loadDyn(bias, idx - CV_BIAS, isbf);
    else                    v = loadDyn(z,    idx - CV_Z,    isbf);
    dst[idx] = v;
}

// Generic dyn -> bf16 conversion (same layout).
__global__ __launch_bounds__(256) void cvt_bf_kernel(
    bf16* __restrict__ dst, const void* __restrict__ src, size_t srcOff,
    int n, const int* __restrict__ flag)
{
    int i = blockIdx.x * 256 + threadIdx.x;
    if (i >= n) return;
    bool isbf = (*flag != 0);
    float v = isbf ? toF(((const bf16*)src)[srcOff + i])
                   : ((const float*)src)[srcOff + i];
    dst[i] = __float2bfloat16(v);
}

// Transposed bf16 weights: Wt (N x K) from W (K x N), per hop.
// Wphi^T is zero-padded from 15 to 16 output rows.
__global__ __launch_bounds__(256) void cvt_wt_kernel(
    const void* W, const void* w1, const void* w2, const void* wphi,
    bf16* __restrict__ wt, bf16* __restrict__ w1t, bf16* __restrict__ w2t,
    bf16* __restrict__ wpt, const int* __restrict__ flag)
{
    int idx = blockIdx.x * 256 + threadIdx.x;
    if (idx >= CVT_TOTAL) return;
    bool isbf = (*flag != 0);
    if (idx < WT_N) {                      // 256N x 256K per hop
        int o = idx, hop = o >> 16, rem = o & 65535, n = rem >> 8, k = rem & 255;
        wt[o] = __float2bfloat16(loadDyn(W, hop * 65536 + k * 256 + n, isbf));
    } else if (idx < WT_N + W1T_N) {       // 256N x 128K per hop
        int o = idx - WT_N, hop = o >> 15, rem = o & 32767, n = rem >> 7, k = rem & 127;
        w1t[o] = __float2bfloat16(loadDyn(w1, hop * 32768 + k * 256 + n, isbf));
    } else if (idx < WT_N + W1T_N + W2T_N) { // 64N x 256K per hop
        int o = idx - WT_N - W1T_N, hop = o >> 14, rem = o & 16383, n = rem >> 8, k = rem & 255;
        w2t[o] = __float2bfloat16(loadDyn(w2, hop * 16384 + k * 64 + n, isbf));
    } else {                               // 16N x 128K per hop (row 15 zero)
        int o = idx - WT_N - W1T_N - W2T_N, hop = o >> 11, rem = o & 2047, n = rem >> 7, k = rem & 127;
        float v = (n < 15) ? loadDyn(wphi, hop * 1920 + k * 15 + n, isbf) : 0.f;
        wpt[o] = __float2bfloat16(v);
    }
}

// ---------------------------------------------------------------------------
// MFMA GEMM, hop-batched via blockIdx.z: C = [relu](A @ B + bias).
// A (M x K) bf16 row-major, Bt (N x K) bf16 row-major. BM=128, BK=64.
// 256 threads = 4 waves WR x WC. 16x16x32 bf16 MFMA.
// Fragment layouts (HW-verified): A[m=lane&15][k=quad*8+j],
// B[k=quad*8+j][n=lane&15] (rows of Bt), C/D col=lane&15,row=quad*4+reg.
// ---------------------------------------------------------------------------
template <int BN, int WR, int WC>
__global__ __launch_bounds__(256) void mfma_gemm(
    const bf16* __restrict__ A, const bf16* __restrict__ Bt,
    const float* __restrict__ bias, const float* __restrict__ tn,
    float* __restrict__ Cf, bf16* __restrict__ Cbf,
    float* __restrict__ lfocus, int K, int N, int relu,
    size_t aStride, size_t btStride, size_t cStride, int bStride, int tnStride)
{
    constexpr int WM = 128 / WR;
    constexpr int WN = BN / WC;
    constexpr int MT = WM / 16;
    constexpr int NT = WN / 16;
    __shared__ short As[128 * 72];   // bf16 bits, row stride 72 (pad 8)
    __shared__ short Bs[BN * 72];
    __shared__ float s_w[4];

    int hop = blockIdx.z;
    A  += (size_t)hop * aStride;
    Bt += (size_t)hop * btStride;
    if (bias) bias += (size_t)hop * bStride;
    if (tn)   tn   += (size_t)hop * tnStride;
    if (Cf)   Cf   += (size_t)hop * cStride;
    if (Cbf)  Cbf  += (size_t)hop * cStride;

    int tid = threadIdx.x;
    int w = tid >> 6, lane = tid & 63;
    int wr = w / WC, wc = w % WC;
    int l16 = lane & 15, quad = lane >> 4;
    int rowBase = blockIdx.y * 128, colBase = blockIdx.x * BN;

    f32x4 acc[MT][NT] = {};

    for (int k0 = 0; k0 < K; k0 += 64) {
        for (int c = tid; c < 128 * 8; c += 256) {
            int row = c >> 3, c8 = c & 7;
            short8 v = *(const short8*)(A + (size_t)(rowBase + row) * K + k0 + c8 * 8);
            *(short8*)&As[row * 72 + c8 * 8] = v;
        }
        for (int c = tid; c < BN * 8; c += 256) {
            int row = c >> 3, c8 = c & 7;
            short8 v = *(const short8*)(Bt + (size_t)(colBase + row) * K + k0 + c8 * 8);
            *(short8*)&Bs[row * 72 + c8 * 8] = v;
        }
        __syncthreads();
#pragma unroll
        for (int kc = 0; kc < 64; kc += 32) {
            short8 aF[MT], bF[NT];
#pragma unroll
            for (int mi = 0; mi < MT; mi++)
                aF[mi] = *(const short8*)&As[(wr * WM + mi * 16 + l16) * 72 + kc + quad * 8];
#pragma unroll
            for (int ni = 0; ni < NT; ni++)
                bF[ni] = *(const short8*)&Bs[(wc * WN + ni * 16 + l16) * 72 + kc + quad * 8];
#pragma unroll
            for (int mi = 0; mi < MT; mi++)
#pragma unroll
                for (int ni = 0; ni < NT; ni++)
                    acc[mi][ni] = __builtin_amdgcn_mfma_f32_16x16x32_bf16(
                        aF[mi], bF[ni], acc[mi][ni], 0, 0, 0);
        }
        __syncthreads();
    }

    float sq = 0.f;
#pragma unroll
    for (int mi = 0; mi < MT; mi++) {
#pragma unroll
        for (int ni = 0; ni < NT; ni++) {
            int col = colBase + wc * WN + ni * 16 + l16;
            float bv = bias ? bias[col] : 0.f;
#pragma unroll
            for (int r = 0; r < 4; r++) {
                int row = rowBase + wr * WM + mi * 16 + quad * 4 + r;
                float v = acc[mi][ni][r] + bv;
                if (relu) v = fmaxf(v, 0.f);
                sq += v * v;
                if (Cf)  Cf[(size_t)row * N + col] = tn ? (v + tn[col]) : v;
                if (Cbf) Cbf[(size_t)row * N + col] = __float2bfloat16(v);
            }
        }
    }
    if (lfocus) {
#pragma unroll
        for (int off = 32; off > 0; off >>= 1) sq += __shfl_xor(sq, off);
        if (lane == 0) s_w[w] = sq;
        __syncthreads();
        if (tid == 0) atomicAdd(lfocus, s_w[0] + s_w[1] + s_w[2] + s_w[3]);
    }
}

// ---------------------------------------------------------------------------
// tn = row-normalized tilde_phi (no epsilon), accumulate l_sep.
// One 64-thread block per hop (blockIdx.x = hop).
// ---------------------------------------------------------------------------
__global__ void tn_lsep_kernel(const float* __restrict__ tphi,
                               float* __restrict__ tn_out, float* __restrict__ acc)
{
    __shared__ float s_v[64], s_tn[64], s_red[64];
    int hop = blockIdx.x;
    const float* tphi_l = tphi + hop * 64;
    int t = threadIdx.x;
    int row = t >> 4, p = t & 15;
    float v = tphi_l[t];
    s_v[t] = v;
    __syncthreads();
    float ss = 0.f;
    for (int q = 0; q < 16; q++) { float x = s_v[row * 16 + q]; ss += x * x; }
    float tnv = v / sqrtf(ss);
    tn_out[hop * 64 + t] = tnv;
    s_tn[t] = tnv;
    __syncthreads();
    float s = 0.f;
    for (int j = 0; j < 4; j++) { float d = tnv - s_tn[j * 16 + p]; s += d * d; }
    s_red[t] = s;
    __syncthreads();
    if (t == 0) {
        float tot = 0.f;
        for (int i = 0; i < 64; i++) tot += s_red[i];
        atomicAdd(acc, tot * 0.25f);
    }
}

// ---------------------------------------------------------------------------
// edge_agg2: wave-synchronous, 4 nodes per 256-thread block, hop = blockIdx.y.
// Per wave (= node): dist via float4 gather (4 lanes/edge), logits via quad
// shuffles, softmax via xor-4/8/16/32 shuffles, aggregation via coalesced
// short4 hk gather (8B/lane), k-fold + normalize via shuffles, float4 store.
// ---------------------------------------------------------------------------
__global__ __launch_bounds__(256) void edge_agg2(
    const bf16* __restrict__ hk, const float* __restrict__ phi,
    const float* __restrict__ dik, const int* __restrict__ src,
    const float* __restrict__ biasAll, float* __restrict__ outs)
{
    int hop = blockIdx.y;
    int wave = threadIdx.x >> 6, lane = threadIdx.x & 63;
    int node = blockIdx.x * 4 + wave;
    const bf16*  hk_l   = hk  + (size_t)hop * N_NODES * 256;
    const float* phi_l  = phi + (size_t)hop * N_NODES * 16;
    const float* dik_l  = dik + (size_t)hop * N_NODES * 64;
    const int*   src_n  = src + (size_t)hop * E_EDGES + (size_t)node * 16;
    const float* bias_l = biasAll + hop * 64;
    float*       outs_n = outs + ((size_t)hop * N_NODES + node) * 64;

    __shared__ float s_dik[4][64];
    __shared__ float s_att[4][16][4];
    __shared__ int   s_src[4][16];

    s_dik[wave][lane] = dik_l[(size_t)node * 64 + lane];
    if (lane < 16) s_src[wave][lane] = src_n[lane];

    // ---- stage 1: dist + logits (4 lanes per edge; lane = 4e + q) ----
    int e = lane >> 2, q = lane & 3;
    int sN = s_src[wave][e];
    f32x4 ps = *(const f32x4*)(phi_l + (size_t)sN * 16 + q * 4);
    f32x4 pd = *(const f32x4*)(phi_l + (size_t)node * 16 + q * 4);
    float d0 = ps[0] - pd[0], d1 = ps[1] - pd[1];
    float d2 = ps[2] - pd[2], d3 = ps[3] - pd[3];
    bool q3 = (q == 3);                       // chunk q=3 holds p=12..15; p15 is the flag col (phi col15 == 0)
    float nzf = ((d0 != 0.f) | (d1 != 0.f) | (d2 != 0.f) | (!q3 && d3 != 0.f)) ? 1.f : 0.f;
    float ssp = d0 * d0 + d1 * d1 + d2 * d2 + (q3 ? 0.f : d3 * d3);
    nzf += __shfl_xor(nzf, 1); nzf += __shfl_xor(nzf, 2);
    ssp += __shfl_xor(ssp, 1); ssp += __shfl_xor(ssp, 2);
    float last = (nzf == 0.f) ? 1.f : 0.f;
    if (q3) d3 = last;
    float inv = 1.f / fmaxf(sqrtf(ssp + last * last), 1e-8f);
#pragma unroll
    for (int k = 0; k < 4; k++) {
        const float* dk = &s_dik[wave][k * 16 + q * 4];
        float pk = d0 * dk[0] + d1 * dk[1] + d2 * dk[2] + d3 * dk[3];
        pk += __shfl_xor(pk, 1); pk += __shfl_xor(pk, 2);
        if (q == k) s_att[wave][e][k] = pk * inv;
    }

    // ---- stage 2: softmax over 16 edges per k (lane = 4e + k) ----
    int k2 = lane & 3;
    float lgv = s_att[wave][e][k2];
    float mx = lgv;
    mx = fmaxf(mx, __shfl_xor(mx, 4));
    mx = fmaxf(mx, __shfl_xor(mx, 8));
    mx = fmaxf(mx, __shfl_xor(mx, 16));
    mx = fmaxf(mx, __shfl_xor(mx, 32));
    float ex = expf(lgv - mx);
    float den = ex;
    den += __shfl_xor(den, 4);
    den += __shfl_xor(den, 8);
    den += __shfl_xor(den, 16);
    den += __shfl_xor(den, 32);
    s_att[wave][e][k2] = ex / den;

    // ---- stage 3: aggregation (lane holds dims 4*lane..4*lane+3, k = lane>>4) ----
    int kk = lane >> 4, dsub = (lane & 15) * 4;
    float a0 = 0.f, a1 = 0.f, a2 = 0.f, a3 = 0.f;
#pragma unroll
    for (int ee = 0; ee < 16; ee++) {
        int sm = s_src[wave][ee];
        short4v v = *(const short4v*)(hk_l + (size_t)sm * 256 + lane * 4);
        float wgt = s_att[wave][ee][kk];
        a0 += wgt * bfb2f(v[0]);
        a1 += wgt * bfb2f(v[1]);
        a2 += wgt * bfb2f(v[2]);
        a3 += wgt * bfb2f(v[3]);
    }
    // fold k (lanes L, L+16, L+32, L+48 hold the same dims)
    a0 += __shfl_xor(a0, 16); a0 += __shfl_xor(a0, 32);
    a1 += __shfl_xor(a1, 16); a1 += __shfl_xor(a1, 32);
    a2 += __shfl_xor(a2, 16); a2 += __shfl_xor(a2, 32);
    a3 += __shfl_xor(a3, 16); a3 += __shfl_xor(a3, 32);
    float o0 = a0 + bias_l[dsub + 0];
    float o1 = a1 + bias_l[dsub + 1];
    float o2 = a2 + bias_l[dsub + 2];
    float o3 = a3 + bias_l[dsub + 3];
    float ssq = o0 * o0 + o1 * o1 + o2 * o2 + o3 * o3;
    ssq += __shfl_xor(ssq, 1);
    ssq += __shfl_xor(ssq, 2);
    ssq += __shfl_xor(ssq, 4);
    ssq += __shfl_xor(ssq, 8);
    float inv2 = 1.f / fmaxf(sqrtf(ssq), 1e-8f);
    if (kk == 0) {
        f32x4 st;
        st[0] = o0 * inv2; st[1] = o1 * inv2; st[2] = o2 * inv2; st[3] = o3 * inv2;
        *(f32x4*)(outs_n + dsub) = st;
    }
}

// Hop fusion + output store (dtype by flag).
__global__ __launch_bounds__(256) void fuse_kernel(
    const float* __restrict__ outs, const float* __restrict__ z,
    void* __restrict__ out, const int* __restrict__ flag)
{
    int tid = threadIdx.x;
    int node = blockIdx.x * 4 + (tid >> 6);
    int dd = tid & 63;
    float zv = z[dd];
    float o[4], sc[4];
#pragma unroll
    for (int h = 0; h < 4; h++) {
        o[h] = outs[((size_t)h * N_NODES + node) * 64 + dd];
        float v = o[h] * zv;
#pragma unroll
        for (int off = 32; off > 0; off >>= 1) v += __shfl_xor(v, off);
        sc[h] = v;
    }
    float mx = fmaxf(fmaxf(sc[0], sc[1]), fmaxf(sc[2], sc[3]));
    float e0 = expf(sc[0] - mx), e1 = expf(sc[1] - mx);
    float e2 = expf(sc[2] - mx), e3 = expf(sc[3] - mx);
    float den = e0 + e1 + e2 + e3;
    float t = (e0 * o[0] + e1 * o[1] + e2 * o[2] + e3 * o[3]) / den;
    size_t oi = (size_t)node * 64 + dd;
    if (*flag != 0) ((bf16*)out)[oi] = __float2bfloat16(t);
    else            ((float*)out)[oi] = t;
}

__global__ void init_kernel(float* acc)
{
    if (threadIdx.x < 2) acc[threadIdx.x] = 0.f;
}

__global__ void final_kernel(const float* __restrict__ acc, void* __restrict__ out,
                             const int* __restrict__ flag)
{
    if (threadIdx.x == 0) {
        float a = acc[0] * 0.25f;
        float b = acc[1] / ((float)N_NODES * 4.f * 4.f);
        size_t base = (size_t)N_NODES * 64;
        if (*flag != 0) {
            ((bf16*)out)[base]     = __float2bfloat16(a);
            ((bf16*)out)[base + 1] = __float2bfloat16(b);
        } else {
            ((float*)out)[base]     = a;
            ((float*)out)[base + 1] = b;
        }
    }
}

extern "C" void kernel_launch(void* const* d_in, const int* in_sizes, int n_in,
                              void* d_out, int out_size, void* d_ws, size_t ws_size,
                              hipStream_t stream)
{
    const void* h    = d_in[0];
    const void* e    = d_in[1];
    const int*  src  = (const int*)d_in[2];
    const void* Wphi = d_in[4];
    const void* w1   = d_in[5];
    const void* b1   = d_in[6];
    const void* w2   = d_in[7];
    const void* b2   = d_in[8];
    const void* tphi = d_in[9];
    const void* W    = d_in[10];
    const void* bias = d_in[11];
    const void* z    = d_in[12];

    float* ws    = (float*)d_ws;
    float* CV    = ws;                                  // CV_END
    float* OUTS  = CV + CV_END;                         // 4*16384*64
    float* PHI   = OUTS + (size_t)4 * N_NODES * 64;     // 4*16384*16
    float* DELTA = PHI + (size_t)4 * N_NODES * 16;      // 4*16384*64
    float* TN    = DELTA + (size_t)4 * N_NODES * 64;    // 4*64
    float* ACC   = TN + 256;                            // 2 (+pad)
    int*   FLAG  = (int*)(ACC + 2);
    bf16*  H_BF   = (bf16*)(ACC + 4);
    bf16*  E_BF   = H_BF + (size_t)N_NODES * 256;       // all 4 hops
    bf16*  HK_BF  = E_BF + (size_t)4 * N_NODES * 128;   // all 4 hops
    bf16*  HID_BF = HK_BF + (size_t)4 * N_NODES * 256;  // all 4 hops
    bf16*  WT     = HID_BF + (size_t)4 * N_NODES * 256;
    bf16*  W1T    = WT + WT_N;
    bf16*  W2T    = W1T + W1T_N;
    bf16*  WPT    = W2T + W2T_N;

    detect_kernel<<<1, 256, 0, stream>>>(h, FLAG);
    init_kernel<<<1, 64, 0, stream>>>(ACC);
    cvt_small_kernel<<<(CV_END + 255) / 256, 256, 0, stream>>>(
        Wphi, w1, b1, w2, b2, tphi, W, bias, z, CV, FLAG);
    cvt_bf_kernel<<<(N_NODES * 256 + 255) / 256, 256, 0, stream>>>(
        H_BF, h, 0, N_NODES * 256, FLAG);
    cvt_bf_kernel<<<(4 * N_NODES * 128 + 255) / 256, 256, 0, stream>>>(
        E_BF, e, 0, 4 * N_NODES * 128, FLAG);
    cvt_wt_kernel<<<(CVT_TOTAL + 255) / 256, 256, 0, stream>>>(
        W, w1, w2, Wphi, WT, W1T, W2T, WPT, FLAG);
    tn_lsep_kernel<<<HOPS, 64, 0, stream>>>(CV + CV_TPHI, TN, ACC);

    // hk = h @ W_l -> bf16   (all hops; A shared, stride 0)
    mfma_gemm<128, 2, 2><<<dim3(2, 128, HOPS), 256, 0, stream>>>(
        H_BF, WT, nullptr, nullptr, nullptr, HK_BF, nullptr,
        256, 256, 0, 0, 256 * 256, (size_t)N_NODES * 256, 0, 0);
    // phi = e_l @ Wphi_l -> f32 (16-wide, col15 = 0 via padded WPT)
    mfma_gemm<16, 4, 1><<<dim3(1, 128, HOPS), 256, 0, stream>>>(
        E_BF, WPT, nullptr, nullptr, PHI, nullptr, nullptr,
        128, 16, 0, (size_t)N_NODES * 128, 16 * 128, (size_t)N_NODES * 16, 0, 0);
    // hid = relu(e_l @ w1 + b1) -> bf16
    mfma_gemm<128, 2, 2><<<dim3(2, 128, HOPS), 256, 0, stream>>>(
        E_BF, W1T, CV + CV_B1, nullptr, nullptr, HID_BF, nullptr,
        128, 256, 1, (size_t)N_NODES * 128, 256 * 128, (size_t)N_NODES * 256, 256, 0);
    // delta = hid @ w2 + b2; DELTA = delta + tn; l_focus (fused)
    mfma_gemm<64, 4, 1><<<dim3(1, 128, HOPS), 256, 0, stream>>>(
        HID_BF, W2T, CV + CV_B2, TN, DELTA, nullptr, ACC + 1,
        256, 64, 0, (size_t)N_NODES * 256, 64 * 256, (size_t)N_NODES * 64, 64, 64);
    // per-node edge softmax + aggregation + normalize (all hops)
    edge_agg2<<<dim3(N_NODES / 4, HOPS), 256, 0, stream>>>(
        HK_BF, PHI, DELTA, src, CV + CV_BIAS, OUTS);

    fuse_kernel<<<dim3(N_NODES / 4), 256, 0, stream>>>(OUTS, CV + CV_Z, d_out, FLAG);
    final_kernel<<<1, 64, 0, stream>>>(ACC, d_out, FLAG);
}

// Round 6
// 284.675 us; speedup vs baseline: 5.8020x; 1.1312x over previous
//
#include <hip/hip_runtime.h>
#include <hip/hip_bf16.h>

#define N_NODES 16384
#define K_NBR 16
#define HOPS 4
#define IN_DIM 256
#define RAW_DIM 128
#define OUT_DIM 64
#define PHI_DIM 16
#define N_KERN 4
#define E_EDGES (N_NODES * K_NBR)

typedef __hip_bfloat16 bf16;
typedef __attribute__((ext_vector_type(8))) short short8;
typedef __attribute__((ext_vector_type(4))) float f32x4;
typedef __attribute__((ext_vector_type(4))) unsigned int uint4v;

__device__ __forceinline__ float toF(float x) { return x; }
__device__ __forceinline__ float toF(bf16 x) { return __bfloat162float(x); }

// --------------------------- f32 workspace layout --------------------------
#define CV_WPHI 0
#define CV_W1   (CV_WPHI + HOPS * RAW_DIM * (PHI_DIM - 1))
#define CV_B1   (CV_W1 + HOPS * RAW_DIM * IN_DIM)
#define CV_W2   (CV_B1 + HOPS * IN_DIM)
#define CV_B2   (CV_W2 + HOPS * IN_DIM * PHI_DIM * N_KERN)
#define CV_TPHI (CV_B2 + HOPS * PHI_DIM * N_KERN)
#define CV_W    (CV_TPHI + HOPS * N_KERN * PHI_DIM)
#define CV_BIAS (CV_W + HOPS * IN_DIM * OUT_DIM * N_KERN)
#define CV_Z    (CV_BIAS + HOPS * OUT_DIM)
#define CV_END  (CV_Z + OUT_DIM)

// transposed bf16 weight region sizes
#define WT_N  (HOPS * 256 * 256)
#define W1T_N (HOPS * 256 * 128)
#define W2T_N (HOPS * 64 * 256)
#define WPT_N (HOPS * 16 * 128)
#define CVT_TOTAL (WT_N + W1T_N + W2T_N + WPT_N)

// ---------------------------------------------------------------------------
// dtype detection (+ zero the scalar accumulators every call).
// Real bf16 -> max|v| ~ 4. f32 read as bf16 halves -> garbage exponents.
// ---------------------------------------------------------------------------
__global__ void detect_kernel(const void* __restrict__ h, int* __restrict__ flag,
                              float* __restrict__ acc)
{
    __shared__ float red[256];
    int t = threadIdx.x;
    if (t < 2) acc[t] = 0.f;
    const unsigned short* p = (const unsigned short*)h;
    float mx = 0.f;
    for (int i = t; i < 2048; i += 256) {
        unsigned int bits = ((unsigned int)p[i]) << 16;
        float v;
        __builtin_memcpy(&v, &bits, 4);
        v = fabsf(v);
        if (!(v == v) || v > 1e30f) v = 1e30f;
        mx = fmaxf(mx, v);
    }
    red[t] = mx;
    __syncthreads();
    for (int s = 128; s > 0; s >>= 1) {
        if (t < s) red[t] = fmaxf(red[t], red[t + s]);
        __syncthreads();
    }
    if (t == 0) *flag = (red[0] < 1e4f) ? 1 : 0;
}

__device__ __forceinline__ float loadDyn(const void* p, int i, bool isbf)
{
    return isbf ? toF(((const bf16*)p)[i]) : ((const float*)p)[i];
}

// Convert the 9 small weight tensors into one contiguous f32 region.
__global__ __launch_bounds__(256) void cvt_small_kernel(
    const void* wphi, const void* w1, const void* b1, const void* w2,
    const void* b2, const void* tphi, const void* W, const void* bias,
    const void* z, float* __restrict__ dst, const int* __restrict__ flag)
{
    int idx = blockIdx.x * 256 + threadIdx.x;
    if (idx >= CV_END) return;
    bool isbf = (*flag != 0);
    float v;
    if      (idx < CV_W1)   v = loadDyn(wphi, idx - CV_WPHI, isbf);
    else if (idx < CV_B1)   v = loadDyn(w1,   idx - CV_W1,   isbf);
    else if (idx < CV_W2)   v = loadDyn(b1,   idx - CV_B1,   isbf);
    else if (idx < CV_B2)   v = loadDyn(w2,   idx - CV_W2,   isbf);
    else if (idx < CV_TPHI) v = loadDyn(b2,   idx - CV_B2,   isbf);
    else if (idx < CV_W)    v = loadDyn(tphi, idx - CV_TPHI, isbf);
    else if (idx < CV_BIAS) v = loadDyn(W,    idx - CV_W,    isbf);
    else if (idx < CV_Z)    v = loadDyn(bias, idx - CV_BIAS, isbf);
    else                    v = loadDyn(z,    idx - CV_Z,    isbf);
    dst[idx] = v;
}

// Generic dyn -> bf16 conversion (same layout).
__global__ __launch_bounds__(256) void cvt_bf_kernel(
    bf16* __restrict__ dst, const void* __restrict__ src, size_t srcOff,
    int n, const int* __restrict__ flag)
{
    int i = blockIdx.x * 256 + threadIdx.x;
    if (i >= n) return;
    bool isbf = (*flag != 0);
    float v = isbf ? toF(((const bf16*)src)[srcOff + i])
                   : ((const float*)src)[srcOff + i];
    dst[i] = __float2bfloat16(v);
}

// Transposed bf16 weights: Wt (N x K) from W (K x N), per hop.
// Wphi^T is zero-padded from 15 to 16 output rows.
__global__ __launch_bounds__(256) void cvt_wt_kernel(
    const void* W, const void* w1, const void* w2, const void* wphi,
    bf16* __restrict__ wt, bf16* __restrict__ w1t, bf16* __restrict__ w2t,
    bf16* __restrict__ wpt, const int* __restrict__ flag)
{
    int idx = blockIdx.x * 256 + threadIdx.x;
    if (idx >= CVT_TOTAL) return;
    bool isbf = (*flag != 0);
    if (idx < WT_N) {                      // 256N x 256K per hop
        int o = idx, hop = o >> 16, rem = o & 65535, n = rem >> 8, k = rem & 255;
        wt[o] = __float2bfloat16(loadDyn(W, hop * 65536 + k * 256 + n, isbf));
    } else if (idx < WT_N + W1T_N) {       // 256N x 128K per hop
        int o = idx - WT_N, hop = o >> 15, rem = o & 32767, n = rem >> 7, k = rem & 127;
        w1t[o] = __float2bfloat16(loadDyn(w1, hop * 32768 + k * 256 + n, isbf));
    } else if (idx < WT_N + W1T_N + W2T_N) { // 64N x 256K per hop
        int o = idx - WT_N - W1T_N, hop = o >> 14, rem = o & 16383, n = rem >> 8, k = rem & 255;
        w2t[o] = __float2bfloat16(loadDyn(w2, hop * 16384 + k * 64 + n, isbf));
    } else {                               // 16N x 128K per hop (row 15 zero)
        int o = idx - WT_N - W1T_N - W2T_N, hop = o >> 11, rem = o & 2047, n = rem >> 7, k = rem & 127;
        float v = (n < 15) ? loadDyn(wphi, hop * 1920 + k * 15 + n, isbf) : 0.f;
        wpt[o] = __float2bfloat16(v);
    }
}

// ---------------------------------------------------------------------------
// MFMA GEMM, hop-batched via blockIdx.z: C = [relu](A @ B + bias).
// A (M x K) bf16 row-major, Bt (N x K) bf16 row-major. BM=128, BK=64.
// OUTMODE: 0 = f32 (+optional tn), 1 = bf16, 2 = fp8-e4m3.
// STAGED: restage C tile through LDS for fully-coalesced 16B stores.
// Fragment layouts (HW-verified): A[m=lane&15][k=quad*8+j],
// B[k=quad*8+j][n=lane&15] (rows of Bt), C/D col=lane&15,row=quad*4+reg.
// ---------------------------------------------------------------------------
template <int BN, int WR, int WC, int OUTMODE, bool STAGED>
__global__ __launch_bounds__(256) void mfma_gemm(
    const bf16* __restrict__ A, const bf16* __restrict__ Bt,
    const float* __restrict__ bias, const float* __restrict__ tn,
    void* __restrict__ Cout, float* __restrict__ lfocus,
    int K, int N, int relu,
    size_t aStride, size_t btStride, size_t cStride, int bStride, int tnStride)
{
    constexpr int WM = 128 / WR;
    constexpr int WN = BN / WC;
    constexpr int MT = WM / 16;
    constexpr int NT = WN / 16;
    constexpr int ESZ = (OUTMODE == 0) ? 4 : (OUTMODE == 1) ? 2 : 1;
    constexpr size_t KB = (size_t)128 * 72 * 2 + (size_t)BN * 72 * 2;
    constexpr size_t CB = STAGED ? (size_t)128 * BN * ESZ : 0;
    constexpr size_t SB = KB > CB ? KB : CB;
    __shared__ __align__(16) char smem[SB];
    __shared__ float s_w[4];
    short* As = (short*)smem;            // [128][72]
    short* Bs = As + 128 * 72;           // [BN][72]

    int hop = blockIdx.z;
    A  += (size_t)hop * aStride;
    Bt += (size_t)hop * btStride;
    if (bias) bias += (size_t)hop * bStride;
    if (tn)   tn   += (size_t)hop * tnStride;
    char* Cg = (char*)Cout + (size_t)hop * cStride * ESZ;

    int tid = threadIdx.x;
    int w = tid >> 6, lane = tid & 63;
    int wr = w / WC, wc = w % WC;
    int l16 = lane & 15, quad = lane >> 4;
    int rowBase = blockIdx.y * 128, colBase = blockIdx.x * BN;

    f32x4 acc[MT][NT] = {};

    for (int k0 = 0; k0 < K; k0 += 64) {
        for (int c = tid; c < 128 * 8; c += 256) {
            int row = c >> 3, c8 = c & 7;
            short8 v = *(const short8*)(A + (size_t)(rowBase + row) * K + k0 + c8 * 8);
            *(short8*)&As[row * 72 + c8 * 8] = v;
        }
        for (int c = tid; c < BN * 8; c += 256) {
            int row = c >> 3, c8 = c & 7;
            short8 v = *(const short8*)(Bt + (size_t)(colBase + row) * K + k0 + c8 * 8);
            *(short8*)&Bs[row * 72 + c8 * 8] = v;
        }
        __syncthreads();
#pragma unroll
        for (int kc = 0; kc < 64; kc += 32) {
            short8 aF[MT], bF[NT];
#pragma unroll
            for (int mi = 0; mi < MT; mi++)
                aF[mi] = *(const short8*)&As[(wr * WM + mi * 16 + l16) * 72 + kc + quad * 8];
#pragma unroll
            for (int ni = 0; ni < NT; ni++)
                bF[ni] = *(const short8*)&Bs[(wc * WN + ni * 16 + l16) * 72 + kc + quad * 8];
#pragma unroll
            for (int mi = 0; mi < MT; mi++)
#pragma unroll
                for (int ni = 0; ni < NT; ni++)
                    acc[mi][ni] = __builtin_amdgcn_mfma_f32_16x16x32_bf16(
                        aF[mi], bF[ni], acc[mi][ni], 0, 0, 0);
        }
        __syncthreads();
    }

    float sq = 0.f;
#pragma unroll
    for (int mi = 0; mi < MT; mi++) {
#pragma unroll
        for (int ni = 0; ni < NT; ni++) {
            int cl = wc * WN + ni * 16 + l16;
            int col = colBase + cl;
            float bv = bias ? bias[col] : 0.f;
#pragma unroll
            for (int r = 0; r < 4; r++) {
                int rl = wr * WM + mi * 16 + quad * 4 + r;
                float v = acc[mi][ni][r] + bv;
                if (relu) v = fmaxf(v, 0.f);
                sq += v * v;
                if (STAGED) {
                    size_t idx = (size_t)rl * BN + cl;
                    if (OUTMODE == 0)
                        ((float*)smem)[idx] = tn ? (v + tn[col]) : v;
                    else if (OUTMODE == 1)
                        ((bf16*)smem)[idx] = __float2bfloat16(v);
                    else {
                        int pk = __builtin_amdgcn_cvt_pk_fp8_f32(v, v, 0, false);
                        ((unsigned char*)smem)[idx] = (unsigned char)(pk & 0xFF);
                    }
                } else {
                    // direct store (f32 only path: phi)
                    ((float*)Cg)[(size_t)(rowBase + rl) * N + col] =
                        tn ? (v + tn[col]) : v;
                }
            }
        }
    }
    if (STAGED) {
        __syncthreads();
        constexpr int CPR = BN * ESZ / 16;           // 16B chunks per row
        for (int c = tid; c < 128 * CPR; c += 256) {
            int r = c / CPR, off = (c % CPR) * 16;
            *(uint4v*)(Cg + ((size_t)(rowBase + r) * N + colBase) * ESZ + off) =
                *(const uint4v*)(smem + (size_t)r * BN * ESZ + off);
        }
    }
    if (lfocus) {
#pragma unroll
        for (int off = 32; off > 0; off >>= 1) sq += __shfl_xor(sq, off);
        if (lane == 0) s_w[w] = sq;
        __syncthreads();
        if (tid == 0) atomicAdd(lfocus, s_w[0] + s_w[1] + s_w[2] + s_w[3]);
    }
}

// ---------------------------------------------------------------------------
// tn = row-normalized tilde_phi (no epsilon), accumulate l_sep.
// One 64-thread block per hop (blockIdx.x = hop).
// ---------------------------------------------------------------------------
__global__ void tn_lsep_kernel(const float* __restrict__ tphi,
                               float* __restrict__ tn_out, float* __restrict__ acc)
{
    __shared__ float s_v[64], s_tn[64], s_red[64];
    int hop = blockIdx.x;
    const float* tphi_l = tphi + hop * 64;
    int t = threadIdx.x;
    int row = t >> 4, p = t & 15;
    float v = tphi_l[t];
    s_v[t] = v;
    __syncthreads();
    float ss = 0.f;
    for (int q = 0; q < 16; q++) { float x = s_v[row * 16 + q]; ss += x * x; }
    float tnv = v / sqrtf(ss);
    tn_out[hop * 64 + t] = tnv;
    s_tn[t] = tnv;
    __syncthreads();
    float s = 0.f;
    for (int j = 0; j < 4; j++) { float d = tnv - s_tn[j * 16 + p]; s += d * d; }
    s_red[t] = s;
    __syncthreads();
    if (t == 0) {
        float tot = 0.f;
        for (int i = 0; i < 64; i++) tot += s_red[i];
        atomicAdd(acc, tot * 0.25f);
    }
}

// ---------------------------------------------------------------------------
// edge_agg2: wave-synchronous, 4 nodes per 256-thread block, hop = blockIdx.y.
// hk is fp8-e4m3 (256B rows): lane loads 4B = 4 dims, decoded with
// v_cvt_pk_f32_fp8. att kept transposed [k][e] so stage 3 prefetches all 16
// weights with 4 ds_read_b128.
// ---------------------------------------------------------------------------
__global__ __launch_bounds__(256) void edge_agg2(
    const unsigned char* __restrict__ hk, const float* __restrict__ phi,
    const float* __restrict__ dik, const int* __restrict__ src,
    const float* __restrict__ biasAll, float* __restrict__ outs)
{
    int hop = blockIdx.y;
    int wave = threadIdx.x >> 6, lane = threadIdx.x & 63;
    int node = blockIdx.x * 4 + wave;
    const unsigned char* hk_l = hk + (size_t)hop * N_NODES * 256;
    const float* phi_l  = phi + (size_t)hop * N_NODES * 16;
    const float* dik_l  = dik + (size_t)hop * N_NODES * 64;
    const int*   src_n  = src + (size_t)hop * E_EDGES + (size_t)node * 16;
    const float* bias_l = biasAll + hop * 64;
    float*       outs_n = outs + ((size_t)hop * N_NODES + node) * 64;

    __shared__ float s_dik[4][64];
    __shared__ float s_attT[4][4][20];   // [wave][k][edge], padded
    __shared__ int   s_src[4][16];

    s_dik[wave][lane] = dik_l[(size_t)node * 64 + lane];
    if (lane < 16) s_src[wave][lane] = src_n[lane];

    // ---- stage 1: dist + logits (4 lanes per edge; lane = 4e + q) ----
    int e = lane >> 2, q = lane & 3;
    int sN = s_src[wave][e];
    f32x4 ps = *(const f32x4*)(phi_l + (size_t)sN * 16 + q * 4);
    f32x4 pd = *(const f32x4*)(phi_l + (size_t)node * 16 + q * 4);
    float d0 = ps[0] - pd[0], d1 = ps[1] - pd[1];
    float d2 = ps[2] - pd[2], d3 = ps[3] - pd[3];
    bool q3 = (q == 3);            // chunk q=3 holds p=12..15; p15 = flag col (phi col15 == 0)
    float nzf = ((d0 != 0.f) | (d1 != 0.f) | (d2 != 0.f) | (!q3 && d3 != 0.f)) ? 1.f : 0.f;
    float ssp = d0 * d0 + d1 * d1 + d2 * d2 + (q3 ? 0.f : d3 * d3);
    nzf += __shfl_xor(nzf, 1); nzf += __shfl_xor(nzf, 2);
    ssp += __shfl_xor(ssp, 1); ssp += __shfl_xor(ssp, 2);
    float last = (nzf == 0.f) ? 1.f : 0.f;
    if (q3) d3 = last;
    float inv = 1.f / fmaxf(sqrtf(ssp + last * last), 1e-8f);
#pragma unroll
    for (int k = 0; k < 4; k++) {
        const float* dk = &s_dik[wave][k * 16 + q * 4];
        float pk = d0 * dk[0] + d1 * dk[1] + d2 * dk[2] + d3 * dk[3];
        pk += __shfl_xor(pk, 1); pk += __shfl_xor(pk, 2);
        if (q == k) s_attT[wave][k][e] = pk * inv;
    }

    // ---- stage 2: softmax over 16 edges per k (lane = 4e + k) ----
    int k2 = lane & 3;
    float lgv = s_attT[wave][k2][e];
    float mx = lgv;
    mx = fmaxf(mx, __shfl_xor(mx, 4));
    mx = fmaxf(mx, __shfl_xor(mx, 8));
    mx = fmaxf(mx, __shfl_xor(mx, 16));
    mx = fmaxf(mx, __shfl_xor(mx, 32));
    float ex = expf(lgv - mx);
    float den = ex;
    den += __shfl_xor(den, 4);
    den += __shfl_xor(den, 8);
    den += __shfl_xor(den, 16);
    den += __shfl_xor(den, 32);
    s_attT[wave][k2][e] = ex / den;

    // ---- stage 3: aggregation (lane = kk*16 + dim-group; 4 dims/lane) ----
    int kk = lane >> 4, dsub = (lane & 15) * 4;
    f32x4 attv[4];
#pragma unroll
    for (int g = 0; g < 4; g++) attv[g] = *(const f32x4*)&s_attT[wave][kk][g * 4];
    float a0 = 0.f, a1 = 0.f, a2 = 0.f, a3 = 0.f;
#pragma unroll
    for (int ee = 0; ee < 16; ee++) {
        int sm = s_src[wave][ee];
        unsigned int u = *(const unsigned int*)(hk_l + (size_t)sm * 256 + lane * 4);
        float wgt = attv[ee >> 2][ee & 3];
        auto lo = __builtin_amdgcn_cvt_pk_f32_fp8((int)u, false);
        auto hi = __builtin_amdgcn_cvt_pk_f32_fp8((int)u, true);
        a0 += wgt * lo[0];
        a1 += wgt * lo[1];
        a2 += wgt * hi[0];
        a3 += wgt * hi[1];
    }
    // fold k (lanes L, L+16, L+32, L+48 hold the same dims)
    a0 += __shfl_xor(a0, 16); a0 += __shfl_xor(a0, 32);
    a1 += __shfl_xor(a1, 16); a1 += __shfl_xor(a1, 32);
    a2 += __shfl_xor(a2, 16); a2 += __shfl_xor(a2, 32);
    a3 += __shfl_xor(a3, 16); a3 += __shfl_xor(a3, 32);
    float o0 = a0 + bias_l[dsub + 0];
    float o1 = a1 + bias_l[dsub + 1];
    float o2 = a2 + bias_l[dsub + 2];
    float o3 = a3 + bias_l[dsub + 3];
    float ssq = o0 * o0 + o1 * o1 + o2 * o2 + o3 * o3;
    ssq += __shfl_xor(ssq, 1);
    ssq += __shfl_xor(ssq, 2);
    ssq += __shfl_xor(ssq, 4);
    ssq += __shfl_xor(ssq, 8);
    float inv2 = 1.f / fmaxf(sqrtf(ssq), 1e-8f);
    if (kk == 0) {
        f32x4 st;
        st[0] = o0 * inv2; st[1] = o1 * inv2; st[2] = o2 * inv2; st[3] = o3 * inv2;
        *(f32x4*)(outs_n + dsub) = st;
    }
}

// Hop fusion + output store (dtype by flag).
__global__ __launch_bounds__(256) void fuse_kernel(
    const float* __restrict__ outs, const float* __restrict__ z,
    void* __restrict__ out, const int* __restrict__ flag)
{
    int tid = threadIdx.x;
    int node = blockIdx.x * 4 + (tid >> 6);
    int dd = tid & 63;
    float zv = z[dd];
    float o[4], sc[4];
#pragma unroll
    for (int h = 0; h < 4; h++) {
        o[h] = outs[((size_t)h * N_NODES + node) * 64 + dd];
        float v = o[h] * zv;
#pragma unroll
        for (int off = 32; off > 0; off >>= 1) v += __shfl_xor(v, off);
        sc[h] = v;
    }
    float mx = fmaxf(fmaxf(sc[0], sc[1]), fmaxf(sc[2], sc[3]));
    float e0 = expf(sc[0] - mx), e1 = expf(sc[1] - mx);
    float e2 = expf(sc[2] - mx), e3 = expf(sc[3] - mx);
    float den = e0 + e1 + e2 + e3;
    float t = (e0 * o[0] + e1 * o[1] + e2 * o[2] + e3 * o[3]) / den;
    size_t oi = (size_t)node * 64 + dd;
    if (*flag != 0) ((bf16*)out)[oi] = __float2bfloat16(t);
    else            ((float*)out)[oi] = t;
}

__global__ void final_kernel(const float* __restrict__ acc, void* __restrict__ out,
                             const int* __restrict__ flag)
{
    if (threadIdx.x == 0) {
        float a = acc[0] * 0.25f;
        float b = acc[1] / ((float)N_NODES * 4.f * 4.f);
        size_t base = (size_t)N_NODES * 64;
        if (*flag != 0) {
            ((bf16*)out)[base]     = __float2bfloat16(a);
            ((bf16*)out)[base + 1] = __float2bfloat16(b);
        } else {
            ((float*)out)[base]     = a;
            ((float*)out)[base + 1] = b;
        }
    }
}

extern "C" void kernel_launch(void* const* d_in, const int* in_sizes, int n_in,
                              void* d_out, int out_size, void* d_ws, size_t ws_size,
                              hipStream_t stream)
{
    const void* h    = d_in[0];
    const void* e    = d_in[1];
    const int*  src  = (const int*)d_in[2];
    const void* Wphi = d_in[4];
    const void* w1   = d_in[5];
    const void* b1   = d_in[6];
    const void* w2   = d_in[7];
    const void* b2   = d_in[8];
    const void* tphi = d_in[9];
    const void* W    = d_in[10];
    const void* bias = d_in[11];
    const void* z    = d_in[12];

    float* ws    = (float*)d_ws;
    float* CV    = ws;                                  // CV_END
    float* OUTS  = CV + CV_END;                         // 4*16384*64
    float* PHI   = OUTS + (size_t)4 * N_NODES * 64;     // 4*16384*16
    float* DELTA = PHI + (size_t)4 * N_NODES * 16;      // 4*16384*64
    float* TN    = DELTA + (size_t)4 * N_NODES * 64;    // 4*64
    float* ACC   = TN + 256;                            // 2 (+pad)
    int*   FLAG  = (int*)(ACC + 2);
    bf16*  H_BF   = (bf16*)(ACC + 4);
    bf16*  E_BF   = H_BF + (size_t)N_NODES * 256;       // all 4 hops
    bf16*  HID_BF = E_BF + (size_t)4 * N_NODES * 128;   // all 4 hops
    bf16*  WT     = HID_BF + (size_t)4 * N_NODES * 256;
    bf16*  W1T    = WT + WT_N;
    bf16*  W2T    = W1T + W1T_N;
    bf16*  WPT    = W2T + W2T_N;
    unsigned char* HK_F8 = (unsigned char*)(WPT + WPT_N);  // 4*16384*256 bytes

    detect_kernel<<<1, 256, 0, stream>>>(h, FLAG, ACC);
    cvt_small_kernel<<<(CV_END + 255) / 256, 256, 0, stream>>>(
        Wphi, w1, b1, w2, b2, tphi, W, bias, z, CV, FLAG);
    cvt_bf_kernel<<<(N_NODES * 256 + 255) / 256, 256, 0, stream>>>(
        H_BF, h, 0, N_NODES * 256, FLAG);
    cvt_bf_kernel<<<(4 * N_NODES * 128 + 255) / 256, 256, 0, stream>>>(
        E_BF, e, 0, 4 * N_NODES * 128, FLAG);
    cvt_wt_kernel<<<(CVT_TOTAL + 255) / 256, 256, 0, stream>>>(
        W, w1, w2, Wphi, WT, W1T, W2T, WPT, FLAG);
    tn_lsep_kernel<<<HOPS, 64, 0, stream>>>(CV + CV_TPHI, TN, ACC);

    // hk = h @ W_l -> fp8 (staged stores; A shared across hops, stride 0)
    mfma_gemm<128, 2, 2, 2, true><<<dim3(2, 128, HOPS), 256, 0, stream>>>(
        H_BF, WT, nullptr, nullptr, HK_F8, nullptr,
        256, 256, 0, 0, 256 * 256, (size_t)N_NODES * 256, 0, 0);
    // phi = e_l @ Wphi_l -> f32 (16-wide, col15 = 0 via padded WPT; direct store)
    mfma_gemm<16, 4, 1, 0, false><<<dim3(1, 128, HOPS), 256, 0, stream>>>(
        E_BF, WPT, nullptr, nullptr, PHI, nullptr,
        128, 16, 0, (size_t)N_NODES * 128, 16 * 128, (size_t)N_NODES * 16, 0, 0);
    // hid = relu(e_l @ w1 + b1) -> bf16 (staged stores)
    mfma_gemm<128, 2, 2, 1, true><<<dim3(2, 128, HOPS), 256, 0, stream>>>(
        E_BF, W1T, CV + CV_B1, nullptr, HID_BF, nullptr,
        128, 256, 1, (size_t)N_NODES * 128, 256 * 128, (size_t)N_NODES * 256, 256, 0);
    // delta = hid @ w2 + b2; DELTA = delta + tn; l_focus (staged stores)
    mfma_gemm<64, 4, 1, 0, true><<<dim3(1, 128, HOPS), 256, 0, stream>>>(
        HID_BF, W2T, CV + CV_B2, TN, DELTA, ACC + 1,
        256, 64, 0, (size_t)N_NODES * 256, 64 * 256, (size_t)N_NODES * 64, 64, 64);
    // per-node edge softmax + aggregation + normalize (all hops)
    edge_agg2<<<dim3(N_NODES / 4, HOPS), 256, 0, stream>>>(
        HK_F8, PHI, DELTA, src, CV + CV_BIAS, OUTS);

    fuse_kernel<<<dim3(N_NODES / 4), 256, 0, stream>>>(OUTS, CV + CV_Z, d_out, FLAG);
    final_kernel<<<1, 64, 0, stream>>>(ACC, d_out, FLAG);
}

// Round 7
// 259.041 us; speedup vs baseline: 6.3762x; 1.0990x over previous
//
#include <hip/hip_runtime.h>
#include <hip/hip_bf16.h>

#define N_NODES 16384
#define K_NBR 16
#define HOPS 4
#define IN_DIM 256
#define RAW_DIM 128
#define OUT_DIM 64
#define PHI_DIM 16
#define N_KERN 4
#define E_EDGES (N_NODES * K_NBR)

typedef __hip_bfloat16 bf16;
typedef __attribute__((ext_vector_type(8))) short short8;
typedef __attribute__((ext_vector_type(4))) float f32x4;
typedef __attribute__((ext_vector_type(4))) unsigned int uint4v;

__device__ __forceinline__ float toF(float x) { return x; }
__device__ __forceinline__ float toF(bf16 x) { return __bfloat162float(x); }
__device__ __forceinline__ short f2bfbits(float f)
{
    bf16 b = __float2bfloat16(f);
    short s; __builtin_memcpy(&s, &b, 2); return s;
}

// --------------------------- f32 workspace layout --------------------------
#define CV_WPHI 0
#define CV_W1   (CV_WPHI + HOPS * RAW_DIM * (PHI_DIM - 1))
#define CV_B1   (CV_W1 + HOPS * RAW_DIM * IN_DIM)
#define CV_W2   (CV_B1 + HOPS * IN_DIM)
#define CV_B2   (CV_W2 + HOPS * IN_DIM * PHI_DIM * N_KERN)
#define CV_TPHI (CV_B2 + HOPS * PHI_DIM * N_KERN)
#define CV_W    (CV_TPHI + HOPS * N_KERN * PHI_DIM)
#define CV_BIAS (CV_W + HOPS * IN_DIM * OUT_DIM * N_KERN)
#define CV_Z    (CV_BIAS + HOPS * OUT_DIM)
#define CV_END  (CV_Z + OUT_DIM)

// transposed bf16 weight region sizes
#define WT_N  (HOPS * 256 * 256)
#define W1T_N (HOPS * 256 * 128)
#define W2T_N (HOPS * 64 * 256)
#define WPT_N (HOPS * 16 * 128)
#define CVT_TOTAL (WT_N + W1T_N + W2T_N + WPT_N)
#define CVT_ALL_WORK (CV_END + CVT_TOTAL)

// ---------------------------------------------------------------------------
// dtype detection (+ zero the scalar accumulators every call).
// Real bf16 -> max|v| ~ 4. f32 read as bf16 halves -> garbage exponents.
// ---------------------------------------------------------------------------
__global__ void detect_kernel(const void* __restrict__ h, int* __restrict__ flag,
                              float* __restrict__ acc)
{
    __shared__ float red[256];
    int t = threadIdx.x;
    if (t < 2) acc[t] = 0.f;
    const unsigned short* p = (const unsigned short*)h;
    float mx = 0.f;
    for (int i = t; i < 2048; i += 256) {
        unsigned int bits = ((unsigned int)p[i]) << 16;
        float v;
        __builtin_memcpy(&v, &bits, 4);
        v = fabsf(v);
        if (!(v == v) || v > 1e30f) v = 1e30f;
        mx = fmaxf(mx, v);
    }
    red[t] = mx;
    __syncthreads();
    for (int s = 128; s > 0; s >>= 1) {
        if (t < s) red[t] = fmaxf(red[t], red[t + s]);
        __syncthreads();
    }
    if (t == 0) *flag = (red[0] < 1e4f) ? 1 : 0;
}

__device__ __forceinline__ float loadDyn(const void* p, int i, bool isbf)
{
    return isbf ? toF(((const bf16*)p)[i]) : ((const float*)p)[i];
}

// ---------------------------------------------------------------------------
// cvt_all: one kernel for (a) small weights -> f32 CV region, (b) transposed
// bf16 weights, (c) tn + l_sep (last block: 256 thr = 4 hops x 64).
// ---------------------------------------------------------------------------
__global__ __launch_bounds__(256) void cvt_all(
    const void* wphi, const void* w1, const void* b1, const void* w2,
    const void* b2, const void* tphi, const void* W, const void* bias,
    const void* z, float* __restrict__ CV,
    bf16* __restrict__ wt, bf16* __restrict__ w1t, bf16* __restrict__ w2t,
    bf16* __restrict__ wpt, float* __restrict__ tn_out, float* __restrict__ acc,
    const int* __restrict__ flag)
{
    bool isbf = (*flag != 0);
    if (blockIdx.x == gridDim.x - 1) {
        // ---- tn = row-normalized tilde_phi (no eps) + l_sep, 4 hops ----
        __shared__ float s_v[256], s_tn[256], s_red[256];
        int tid = threadIdx.x;
        int hop = tid >> 6, t64 = tid & 63;
        int row = t64 >> 4, p = t64 & 15;
        float v = loadDyn(tphi, hop * 64 + t64, isbf);
        s_v[tid] = v;
        __syncthreads();
        float ss = 0.f;
        for (int q = 0; q < 16; q++) { float x = s_v[hop * 64 + row * 16 + q]; ss += x * x; }
        float tnv = v / sqrtf(ss);
        tn_out[hop * 64 + t64] = tnv;
        s_tn[tid] = tnv;
        __syncthreads();
        float s = 0.f;
        for (int j = 0; j < 4; j++) {
            float d = tnv - s_tn[hop * 64 + j * 16 + p];
            s += d * d;
        }
        s_red[tid] = s;
        __syncthreads();
        if (t64 == 0) {
            float tot = 0.f;
            for (int i = 0; i < 64; i++) tot += s_red[hop * 64 + i];
            atomicAdd(acc, tot * 0.25f);
        }
        return;
    }
    int idx = blockIdx.x * 256 + threadIdx.x;
    if (idx < CV_END) {
        float v;
        if      (idx < CV_W1)   v = loadDyn(wphi, idx - CV_WPHI, isbf);
        else if (idx < CV_B1)   v = loadDyn(w1,   idx - CV_W1,   isbf);
        else if (idx < CV_W2)   v = loadDyn(b1,   idx - CV_B1,   isbf);
        else if (idx < CV_B2)   v = loadDyn(w2,   idx - CV_W2,   isbf);
        else if (idx < CV_TPHI) v = loadDyn(b2,   idx - CV_B2,   isbf);
        else if (idx < CV_W)    v = loadDyn(tphi, idx - CV_TPHI, isbf);
        else if (idx < CV_BIAS) v = loadDyn(W,    idx - CV_W,    isbf);
        else if (idx < CV_Z)    v = loadDyn(bias, idx - CV_BIAS, isbf);
        else                    v = loadDyn(z,    idx - CV_Z,    isbf);
        CV[idx] = v;
        return;
    }
    idx -= CV_END;
    if (idx >= CVT_TOTAL) return;
    if (idx < WT_N) {                      // 256N x 256K per hop
        int o = idx, hop = o >> 16, rem = o & 65535, n = rem >> 8, k = rem & 255;
        wt[o] = __float2bfloat16(loadDyn(W, hop * 65536 + k * 256 + n, isbf));
    } else if (idx < WT_N + W1T_N) {       // 256N x 128K per hop
        int o = idx - WT_N, hop = o >> 15, rem = o & 32767, n = rem >> 7, k = rem & 127;
        w1t[o] = __float2bfloat16(loadDyn(w1, hop * 32768 + k * 256 + n, isbf));
    } else if (idx < WT_N + W1T_N + W2T_N) { // 64N x 256K per hop
        int o = idx - WT_N - W1T_N, hop = o >> 14, rem = o & 16383, n = rem >> 8, k = rem & 255;
        w2t[o] = __float2bfloat16(loadDyn(w2, hop * 16384 + k * 64 + n, isbf));
    } else {                               // 16N x 128K per hop (row 15 zero)
        int o = idx - WT_N - W1T_N - W2T_N, hop = o >> 11, rem = o & 2047, n = rem >> 7, k = rem & 127;
        float v = (n < 15) ? loadDyn(wphi, hop * 1920 + k * 15 + n, isbf) : 0.f;
        wpt[o] = __float2bfloat16(v);
    }
}

// ---------------------------------------------------------------------------
// MFMA GEMM, hop-batched via blockIdx.z: C = [relu](A @ B + bias).
// A (M x K) row-major: ADYN ? (bf16 or f32 selected by *flag, f32 converted
// to bf16 in registers during staging) : always bf16.
// Bt (N x K) bf16 row-major. BM=128, BK=64.
// OUTMODE: 0 = f32 (+optional tn), 1 = bf16, 2 = fp8-e4m3.
// STAGED: restage C tile through LDS for fully-coalesced 16B stores.
// Fragment layouts (HW-verified): A[m=lane&15][k=quad*8+j],
// B[k=quad*8+j][n=lane&15] (rows of Bt), C/D col=lane&15,row=quad*4+reg.
// ---------------------------------------------------------------------------
template <int BN, int WR, int WC, int OUTMODE, bool STAGED, bool ADYN>
__global__ __launch_bounds__(256) void mfma_gemm(
    const bf16* __restrict__ Abf, const float* __restrict__ Af32,
    const int* __restrict__ flag, const bf16* __restrict__ Bt,
    const float* __restrict__ bias, const float* __restrict__ tn,
    void* __restrict__ Cout, float* __restrict__ lfocus,
    int K, int N, int relu,
    size_t aStride, size_t btStride, size_t cStride, int bStride, int tnStride)
{
    constexpr int WM = 128 / WR;
    constexpr int WN = BN / WC;
    constexpr int MT = WM / 16;
    constexpr int NT = WN / 16;
    constexpr int ESZ = (OUTMODE == 0) ? 4 : (OUTMODE == 1) ? 2 : 1;
    constexpr size_t KB = (size_t)128 * 72 * 2 + (size_t)BN * 72 * 2;
    constexpr size_t CB = STAGED ? (size_t)128 * BN * ESZ : 0;
    constexpr size_t SB = KB > CB ? KB : CB;
    __shared__ __align__(16) char smem[SB];
    __shared__ float s_w[4];
    short* As = (short*)smem;            // [128][72]
    short* Bs = As + 128 * 72;           // [BN][72]

    bool abf = ADYN ? (*flag != 0) : true;

    int hop = blockIdx.z;
    Abf += (size_t)hop * aStride;
    if (ADYN) Af32 += (size_t)hop * aStride;
    Bt += (size_t)hop * btStride;
    if (bias) bias += (size_t)hop * bStride;
    if (tn)   tn   += (size_t)hop * tnStride;
    char* Cg = (char*)Cout + (size_t)hop * cStride * ESZ;

    int tid = threadIdx.x;
    int w = tid >> 6, lane = tid & 63;
    int wr = w / WC, wc = w % WC;
    int l16 = lane & 15, quad = lane >> 4;
    int rowBase = blockIdx.y * 128, colBase = blockIdx.x * BN;

    f32x4 acc[MT][NT] = {};

    for (int k0 = 0; k0 < K; k0 += 64) {
        for (int c = tid; c < 128 * 8; c += 256) {
            int row = c >> 3, c8 = c & 7;
            short8 v;
            if (abf) {
                v = *(const short8*)(Abf + (size_t)(rowBase + row) * K + k0 + c8 * 8);
            } else {
                const float* ap = Af32 + (size_t)(rowBase + row) * K + k0 + c8 * 8;
                f32x4 f0 = *(const f32x4*)ap;
                f32x4 f1 = *(const f32x4*)(ap + 4);
#pragma unroll
                for (int j = 0; j < 4; j++) {
                    v[j] = f2bfbits(f0[j]);
                    v[4 + j] = f2bfbits(f1[j]);
                }
            }
            *(short8*)&As[row * 72 + c8 * 8] = v;
        }
        for (int c = tid; c < BN * 8; c += 256) {
            int row = c >> 3, c8 = c & 7;
            short8 v = *(const short8*)(Bt + (size_t)(colBase + row) * K + k0 + c8 * 8);
            *(short8*)&Bs[row * 72 + c8 * 8] = v;
        }
        __syncthreads();
#pragma unroll
        for (int kc = 0; kc < 64; kc += 32) {
            short8 aF[MT], bF[NT];
#pragma unroll
            for (int mi = 0; mi < MT; mi++)
                aF[mi] = *(const short8*)&As[(wr * WM + mi * 16 + l16) * 72 + kc + quad * 8];
#pragma unroll
            for (int ni = 0; ni < NT; ni++)
                bF[ni] = *(const short8*)&Bs[(wc * WN + ni * 16 + l16) * 72 + kc + quad * 8];
#pragma unroll
            for (int mi = 0; mi < MT; mi++)
#pragma unroll
                for (int ni = 0; ni < NT; ni++)
                    acc[mi][ni] = __builtin_amdgcn_mfma_f32_16x16x32_bf16(
                        aF[mi], bF[ni], acc[mi][ni], 0, 0, 0);
        }
        __syncthreads();
    }

    float sq = 0.f;
#pragma unroll
    for (int mi = 0; mi < MT; mi++) {
#pragma unroll
        for (int ni = 0; ni < NT; ni++) {
            int cl = wc * WN + ni * 16 + l16;
            int col = colBase + cl;
            float bv = bias ? bias[col] : 0.f;
#pragma unroll
            for (int r = 0; r < 4; r++) {
                int rl = wr * WM + mi * 16 + quad * 4 + r;
                float v = acc[mi][ni][r] + bv;
                if (relu) v = fmaxf(v, 0.f);
                sq += v * v;
                if (STAGED) {
                    size_t idx = (size_t)rl * BN + cl;
                    if (OUTMODE == 0)
                        ((float*)smem)[idx] = tn ? (v + tn[col]) : v;
                    else if (OUTMODE == 1)
                        ((bf16*)smem)[idx] = __float2bfloat16(v);
                    else {
                        int pk = __builtin_amdgcn_cvt_pk_fp8_f32(v, v, 0, false);
                        ((unsigned char*)smem)[idx] = (unsigned char)(pk & 0xFF);
                    }
                } else {
                    ((float*)Cg)[(size_t)(rowBase + rl) * N + col] =
                        tn ? (v + tn[col]) : v;
                }
            }
        }
    }
    if (STAGED) {
        __syncthreads();
        constexpr int CPR = BN * ESZ / 16;           // 16B chunks per row
        for (int c = tid; c < 128 * CPR; c += 256) {
            int r = c / CPR, off = (c % CPR) * 16;
            *(uint4v*)(Cg + ((size_t)(rowBase + r) * N + colBase) * ESZ + off) =
                *(const uint4v*)(smem + (size_t)r * BN * ESZ + off);
        }
    }
    if (lfocus) {
#pragma unroll
        for (int off = 32; off > 0; off >>= 1) sq += __shfl_xor(sq, off);
        if (lane == 0) s_w[w] = sq;
        __syncthreads();
        if (tid == 0) atomicAdd(lfocus, s_w[0] + s_w[1] + s_w[2] + s_w[3]);
    }
}

// ---------------------------------------------------------------------------
// edge_agg2: wave-synchronous, 4 nodes per 256-thread block, hop = blockIdx.y.
// hk is fp8-e4m3 (256B rows): lane loads 4B = 4 dims, decoded with
// v_cvt_pk_f32_fp8. att kept transposed [k][e].
// ---------------------------------------------------------------------------
__global__ __launch_bounds__(256) void edge_agg2(
    const unsigned char* __restrict__ hk, const float* __restrict__ phi,
    const float* __restrict__ dik, const int* __restrict__ src,
    const float* __restrict__ biasAll, float* __restrict__ outs)
{
    int hop = blockIdx.y;
    int wave = threadIdx.x >> 6, lane = threadIdx.x & 63;
    int node = blockIdx.x * 4 + wave;
    const unsigned char* hk_l = hk + (size_t)hop * N_NODES * 256;
    const float* phi_l  = phi + (size_t)hop * N_NODES * 16;
    const float* dik_l  = dik + (size_t)hop * N_NODES * 64;
    const int*   src_n  = src + (size_t)hop * E_EDGES + (size_t)node * 16;
    const float* bias_l = biasAll + hop * 64;
    float*       outs_n = outs + ((size_t)hop * N_NODES + node) * 64;

    __shared__ float s_dik[4][64];
    __shared__ float s_attT[4][4][20];   // [wave][k][edge], padded
    __shared__ int   s_src[4][16];

    s_dik[wave][lane] = dik_l[(size_t)node * 64 + lane];
    if (lane < 16) s_src[wave][lane] = src_n[lane];

    // ---- stage 1: dist + logits (4 lanes per edge; lane = 4e + q) ----
    int e = lane >> 2, q = lane & 3;
    int sN = s_src[wave][e];
    f32x4 ps = *(const f32x4*)(phi_l + (size_t)sN * 16 + q * 4);
    f32x4 pd = *(const f32x4*)(phi_l + (size_t)node * 16 + q * 4);
    float d0 = ps[0] - pd[0], d1 = ps[1] - pd[1];
    float d2 = ps[2] - pd[2], d3 = ps[3] - pd[3];
    bool q3 = (q == 3);            // p15 = flag col (phi col15 == 0)
    float nzf = ((d0 != 0.f) | (d1 != 0.f) | (d2 != 0.f) | (!q3 && d3 != 0.f)) ? 1.f : 0.f;
    float ssp = d0 * d0 + d1 * d1 + d2 * d2 + (q3 ? 0.f : d3 * d3);
    nzf += __shfl_xor(nzf, 1); nzf += __shfl_xor(nzf, 2);
    ssp += __shfl_xor(ssp, 1); ssp += __shfl_xor(ssp, 2);
    float last = (nzf == 0.f) ? 1.f : 0.f;
    if (q3) d3 = last;
    float inv = 1.f / fmaxf(sqrtf(ssp + last * last), 1e-8f);
#pragma unroll
    for (int k = 0; k < 4; k++) {
        const float* dk = &s_dik[wave][k * 16 + q * 4];
        float pk = d0 * dk[0] + d1 * dk[1] + d2 * dk[2] + d3 * dk[3];
        pk += __shfl_xor(pk, 1); pk += __shfl_xor(pk, 2);
        if (q == k) s_attT[wave][k][e] = pk * inv;
    }

    // ---- stage 2: softmax over 16 edges per k (lane = 4e + k) ----
    int k2 = lane & 3;
    float lgv = s_attT[wave][k2][e];
    float mx = lgv;
    mx = fmaxf(mx, __shfl_xor(mx, 4));
    mx = fmaxf(mx, __shfl_xor(mx, 8));
    mx = fmaxf(mx, __shfl_xor(mx, 16));
    mx = fmaxf(mx, __shfl_xor(mx, 32));
    float ex = expf(lgv - mx);
    float den = ex;
    den += __shfl_xor(den, 4);
    den += __shfl_xor(den, 8);
    den += __shfl_xor(den, 16);
    den += __shfl_xor(den, 32);
    s_attT[wave][k2][e] = ex / den;

    // ---- stage 3: aggregation (lane = kk*16 + dim-group; 4 dims/lane) ----
    int kk = lane >> 4, dsub = (lane & 15) * 4;
    f32x4 attv[4];
#pragma unroll
    for (int g = 0; g < 4; g++) attv[g] = *(const f32x4*)&s_attT[wave][kk][g * 4];
    float a0 = 0.f, a1 = 0.f, a2 = 0.f, a3 = 0.f;
#pragma unroll
    for (int ee = 0; ee < 16; ee++) {
        int sm = s_src[wave][ee];
        unsigned int u = *(const unsigned int*)(hk_l + (size_t)sm * 256 + lane * 4);
        float wgt = attv[ee >> 2][ee & 3];
        auto lo = __builtin_amdgcn_cvt_pk_f32_fp8((int)u, false);
        auto hi = __builtin_amdgcn_cvt_pk_f32_fp8((int)u, true);
        a0 += wgt * lo[0];
        a1 += wgt * lo[1];
        a2 += wgt * hi[0];
        a3 += wgt * hi[1];
    }
    a0 += __shfl_xor(a0, 16); a0 += __shfl_xor(a0, 32);
    a1 += __shfl_xor(a1, 16); a1 += __shfl_xor(a1, 32);
    a2 += __shfl_xor(a2, 16); a2 += __shfl_xor(a2, 32);
    a3 += __shfl_xor(a3, 16); a3 += __shfl_xor(a3, 32);
    float o0 = a0 + bias_l[dsub + 0];
    float o1 = a1 + bias_l[dsub + 1];
    float o2 = a2 + bias_l[dsub + 2];
    float o3 = a3 + bias_l[dsub + 3];
    float ssq = o0 * o0 + o1 * o1 + o2 * o2 + o3 * o3;
    ssq += __shfl_xor(ssq, 1);
    ssq += __shfl_xor(ssq, 2);
    ssq += __shfl_xor(ssq, 4);
    ssq += __shfl_xor(ssq, 8);
    float inv2 = 1.f / fmaxf(sqrtf(ssq), 1e-8f);
    if (kk == 0) {
        f32x4 st;
        st[0] = o0 * inv2; st[1] = o1 * inv2; st[2] = o2 * inv2; st[3] = o3 * inv2;
        *(f32x4*)(outs_n + dsub) = st;
    }
}

// Hop fusion + output store (dtype by flag) + scalar outputs (block 0).
__global__ __launch_bounds__(256) void fuse_kernel(
    const float* __restrict__ outs, const float* __restrict__ z,
    void* __restrict__ out, const int* __restrict__ flag,
    const float* __restrict__ acc)
{
    int tid = threadIdx.x;
    int node = blockIdx.x * 4 + (tid >> 6);
    int dd = tid & 63;
    float zv = z[dd];
    float o[4], sc[4];
#pragma unroll
    for (int h = 0; h < 4; h++) {
        o[h] = outs[((size_t)h * N_NODES + node) * 64 + dd];
        float v = o[h] * zv;
#pragma unroll
        for (int off = 32; off > 0; off >>= 1) v += __shfl_xor(v, off);
        sc[h] = v;
    }
    float mx = fmaxf(fmaxf(sc[0], sc[1]), fmaxf(sc[2], sc[3]));
    float e0 = expf(sc[0] - mx), e1 = expf(sc[1] - mx);
    float e2 = expf(sc[2] - mx), e3 = expf(sc[3] - mx);
    float den = e0 + e1 + e2 + e3;
    float t = (e0 * o[0] + e1 * o[1] + e2 * o[2] + e3 * o[3]) / den;
    size_t oi = (size_t)node * 64 + dd;
    bool isbf = (*flag != 0);
    if (isbf) ((bf16*)out)[oi] = __float2bfloat16(t);
    else      ((float*)out)[oi] = t;
    if (blockIdx.x == 0 && tid == 0) {
        float a = acc[0] * 0.25f;
        float b = acc[1] / ((float)N_NODES * 4.f * 4.f);
        size_t base = (size_t)N_NODES * 64;
        if (isbf) {
            ((bf16*)out)[base]     = __float2bfloat16(a);
            ((bf16*)out)[base + 1] = __float2bfloat16(b);
        } else {
            ((float*)out)[base]     = a;
            ((float*)out)[base + 1] = b;
        }
    }
}

extern "C" void kernel_launch(void* const* d_in, const int* in_sizes, int n_in,
                              void* d_out, int out_size, void* d_ws, size_t ws_size,
                              hipStream_t stream)
{
    const void* h    = d_in[0];
    const void* e    = d_in[1];
    const int*  src  = (const int*)d_in[2];
    const void* Wphi = d_in[4];
    const void* w1   = d_in[5];
    const void* b1   = d_in[6];
    const void* w2   = d_in[7];
    const void* b2   = d_in[8];
    const void* tphi = d_in[9];
    const void* W    = d_in[10];
    const void* bias = d_in[11];
    const void* z    = d_in[12];

    float* ws    = (float*)d_ws;
    float* CV    = ws;                                  // CV_END
    float* OUTS  = CV + CV_END;                         // 4*16384*64
    float* PHI   = OUTS + (size_t)4 * N_NODES * 64;     // 4*16384*16
    float* DELTA = PHI + (size_t)4 * N_NODES * 16;      // 4*16384*64
    float* TN    = DELTA + (size_t)4 * N_NODES * 64;    // 4*64
    float* ACC   = TN + 256;                            // 2 (+pad)
    int*   FLAG  = (int*)(ACC + 2);
    bf16*  HID_BF = (bf16*)(ACC + 4);                   // 4*16384*256
    bf16*  WT     = HID_BF + (size_t)4 * N_NODES * 256;
    bf16*  W1T    = WT + WT_N;
    bf16*  W2T    = W1T + W1T_N;
    bf16*  WPT    = W2T + W2T_N;
    unsigned char* HK_F8 = (unsigned char*)(WPT + WPT_N);  // 4*16384*256 bytes

    detect_kernel<<<1, 256, 0, stream>>>(h, FLAG, ACC);
    cvt_all<<<(CVT_ALL_WORK + 255) / 256 + 1, 256, 0, stream>>>(
        Wphi, w1, b1, w2, b2, tphi, W, bias, z, CV,
        WT, W1T, W2T, WPT, TN, ACC, FLAG);

    // hk = h @ W_l -> fp8 (staged; A = h, dtype-dynamic, shared across hops)
    mfma_gemm<128, 2, 2, 2, true, true><<<dim3(2, 128, HOPS), 256, 0, stream>>>(
        (const bf16*)h, (const float*)h, FLAG, WT, nullptr, nullptr, HK_F8, nullptr,
        256, 256, 0, 0, 256 * 256, (size_t)N_NODES * 256, 0, 0);
    // phi = e_l @ Wphi_l -> f32 (16-wide, col15 = 0 via padded WPT; direct store)
    mfma_gemm<16, 4, 1, 0, false, true><<<dim3(1, 128, HOPS), 256, 0, stream>>>(
        (const bf16*)e, (const float*)e, FLAG, WPT, nullptr, nullptr, PHI, nullptr,
        128, 16, 0, (size_t)N_NODES * 128, 16 * 128, (size_t)N_NODES * 16, 0, 0);
    // hid = relu(e_l @ w1 + b1) -> bf16 (staged)
    mfma_gemm<128, 2, 2, 1, true, true><<<dim3(2, 128, HOPS), 256, 0, stream>>>(
        (const bf16*)e, (const float*)e, FLAG, W1T, CV + CV_B1, nullptr, HID_BF, nullptr,
        128, 256, 1, (size_t)N_NODES * 128, 256 * 128, (size_t)N_NODES * 256, 256, 0);
    // delta = hid @ w2 + b2; DELTA = delta + tn; l_focus (staged)
    mfma_gemm<64, 4, 1, 0, true, false><<<dim3(1, 128, HOPS), 256, 0, stream>>>(
        HID_BF, nullptr, FLAG, W2T, CV + CV_B2, TN, DELTA, ACC + 1,
        256, 64, 0, (size_t)N_NODES * 256, 64 * 256, (size_t)N_NODES * 64, 64, 64);
    // per-node edge softmax + aggregation + normalize (all hops)
    edge_agg2<<<dim3(N_NODES / 4, HOPS), 256, 0, stream>>>(
        HK_F8, PHI, DELTA, src, CV + CV_BIAS, OUTS);

    fuse_kernel<<<dim3(N_NODES / 4), 256, 0, stream>>>(
        OUTS, CV + CV_Z, d_out, FLAG, ACC);
}

// Round 8
// 238.900 us; speedup vs baseline: 6.9137x; 1.0843x over previous
//
#include <hip/hip_runtime.h>
#include <hip/hip_bf16.h>

#define N_NODES 16384
#define K_NBR 16
#define HOPS 4
#define IN_DIM 256
#define RAW_DIM 128
#define OUT_DIM 64
#define PHI_DIM 16
#define N_KERN 4
#define E_EDGES (N_NODES * K_NBR)

typedef __hip_bfloat16 bf16;
typedef __attribute__((ext_vector_type(8))) short short8;
typedef __attribute__((ext_vector_type(4))) float f32x4;
typedef __attribute__((ext_vector_type(4))) unsigned int uint4v;

__device__ __forceinline__ float toF(float x) { return x; }
__device__ __forceinline__ float toF(bf16 x) { return __bfloat162float(x); }
__device__ __forceinline__ short f2bfbits(float f)
{
    bf16 b = __float2bfloat16(f);
    short s; __builtin_memcpy(&s, &b, 2); return s;
}

// --------------------------- f32 workspace layout --------------------------
#define CV_WPHI 0
#define CV_W1   (CV_WPHI + HOPS * RAW_DIM * (PHI_DIM - 1))
#define CV_B1   (CV_W1 + HOPS * RAW_DIM * IN_DIM)
#define CV_W2   (CV_B1 + HOPS * IN_DIM)
#define CV_B2   (CV_W2 + HOPS * IN_DIM * PHI_DIM * N_KERN)
#define CV_TPHI (CV_B2 + HOPS * PHI_DIM * N_KERN)
#define CV_W    (CV_TPHI + HOPS * N_KERN * PHI_DIM)
#define CV_BIAS (CV_W + HOPS * IN_DIM * OUT_DIM * N_KERN)
#define CV_Z    (CV_BIAS + HOPS * OUT_DIM)
#define CV_END  (CV_Z + OUT_DIM)

// transposed bf16 weight region sizes
#define WT_N  (HOPS * 256 * 256)
#define W1T_N (HOPS * 256 * 128)
#define W2T_N (HOPS * 64 * 256)
#define WPT_N (HOPS * 16 * 128)
#define CVT_TOTAL (WT_N + W1T_N + W2T_N + WPT_N)

// cvt_all block ranges
#define NB_CV ((CV_END + 255) / 256)
#define NB_WT (CVT_TOTAL / 256)                      // exact
#define NB_H  (N_NODES * 256 / 8 / 256)              // h vec8 units
#define NB_E  (HOPS * N_NODES * 128 / 8 / 256)       // e vec8 units
#define NB_ALL (NB_CV + NB_WT + NB_H + NB_E + 1)

// ---------------------------------------------------------------------------
// dtype detection (+ zero the scalar accumulators every call).
// Real bf16 -> max|v| ~ 4. f32 read as bf16 halves -> garbage exponents.
// ---------------------------------------------------------------------------
__global__ void detect_kernel(const void* __restrict__ h, int* __restrict__ flag,
                              float* __restrict__ acc)
{
    __shared__ float red[256];
    int t = threadIdx.x;
    if (t < 2) acc[t] = 0.f;
    const unsigned short* p = (const unsigned short*)h;
    float mx = 0.f;
    for (int i = t; i < 2048; i += 256) {
        unsigned int bits = ((unsigned int)p[i]) << 16;
        float v;
        __builtin_memcpy(&v, &bits, 4);
        v = fabsf(v);
        if (!(v == v) || v > 1e30f) v = 1e30f;
        mx = fmaxf(mx, v);
    }
    red[t] = mx;
    __syncthreads();
    for (int s = 128; s > 0; s >>= 1) {
        if (t < s) red[t] = fmaxf(red[t], red[t + s]);
        __syncthreads();
    }
    if (t == 0) *flag = (red[0] < 1e4f) ? 1 : 0;
}

__device__ __forceinline__ float loadDyn(const void* p, int i, bool isbf)
{
    return isbf ? toF(((const bf16*)p)[i]) : ((const float*)p)[i];
}

// 8-wide dyn -> bf16 conversion helper
__device__ __forceinline__ void cvt8(bf16* dst, const void* src, size_t base, bool isbf)
{
    short8 v;
    if (isbf) {
        v = *(const short8*)((const bf16*)src + base);
    } else {
        const float* sp = (const float*)src + base;
        f32x4 f0 = *(const f32x4*)sp;
        f32x4 f1 = *(const f32x4*)(sp + 4);
#pragma unroll
        for (int j = 0; j < 4; j++) { v[j] = f2bfbits(f0[j]); v[4 + j] = f2bfbits(f1[j]); }
    }
    *(short8*)(dst + base) = v;
}

// ---------------------------------------------------------------------------
// cvt_all: (a) small weights -> f32 CV, (b) transposed bf16 weights,
// (c) h -> bf16, (d) e -> bf16 (vec8), (e) tn + l_sep (last block).
// ---------------------------------------------------------------------------
__global__ __launch_bounds__(256) void cvt_all(
    const void* h, const void* e,
    const void* wphi, const void* w1, const void* b1, const void* w2,
    const void* b2, const void* tphi, const void* W, const void* bias,
    const void* z, float* __restrict__ CV,
    bf16* __restrict__ wt, bf16* __restrict__ w1t, bf16* __restrict__ w2t,
    bf16* __restrict__ wpt, bf16* __restrict__ h_bf, bf16* __restrict__ e_bf,
    float* __restrict__ tn_out, float* __restrict__ acc,
    const int* __restrict__ flag)
{
    bool isbf = (*flag != 0);
    int b = blockIdx.x;
    if (b == NB_ALL - 1) {
        // ---- tn = row-normalized tilde_phi (no eps) + l_sep, 4 hops ----
        __shared__ float s_v[256], s_tn[256], s_red[256];
        int tid = threadIdx.x;
        int hop = tid >> 6, t64 = tid & 63;
        int row = t64 >> 4, p = t64 & 15;
        float v = loadDyn(tphi, hop * 64 + t64, isbf);
        s_v[tid] = v;
        __syncthreads();
        float ss = 0.f;
        for (int q = 0; q < 16; q++) { float x = s_v[hop * 64 + row * 16 + q]; ss += x * x; }
        float tnv = v / sqrtf(ss);
        tn_out[hop * 64 + t64] = tnv;
        s_tn[tid] = tnv;
        __syncthreads();
        float s = 0.f;
        for (int j = 0; j < 4; j++) {
            float d = tnv - s_tn[hop * 64 + j * 16 + p];
            s += d * d;
        }
        s_red[tid] = s;
        __syncthreads();
        if (t64 == 0) {
            float tot = 0.f;
            for (int i = 0; i < 64; i++) tot += s_red[hop * 64 + i];
            atomicAdd(acc, tot * 0.25f);
        }
        return;
    }
    if (b < NB_CV) {
        int idx = b * 256 + threadIdx.x;
        if (idx >= CV_END) return;
        float v;
        if      (idx < CV_W1)   v = loadDyn(wphi, idx - CV_WPHI, isbf);
        else if (idx < CV_B1)   v = loadDyn(w1,   idx - CV_W1,   isbf);
        else if (idx < CV_W2)   v = loadDyn(b1,   idx - CV_B1,   isbf);
        else if (idx < CV_B2)   v = loadDyn(w2,   idx - CV_W2,   isbf);
        else if (idx < CV_TPHI) v = loadDyn(b2,   idx - CV_B2,   isbf);
        else if (idx < CV_W)    v = loadDyn(tphi, idx - CV_TPHI, isbf);
        else if (idx < CV_BIAS) v = loadDyn(W,    idx - CV_W,    isbf);
        else if (idx < CV_Z)    v = loadDyn(bias, idx - CV_BIAS, isbf);
        else                    v = loadDyn(z,    idx - CV_Z,    isbf);
        CV[idx] = v;
        return;
    }
    b -= NB_CV;
    if (b < NB_WT) {
        int idx = b * 256 + threadIdx.x;
        if (idx < WT_N) {                      // 256N x 256K per hop
            int o = idx, hop = o >> 16, rem = o & 65535, n = rem >> 8, k = rem & 255;
            wt[o] = __float2bfloat16(loadDyn(W, hop * 65536 + k * 256 + n, isbf));
        } else if (idx < WT_N + W1T_N) {       // 256N x 128K per hop
            int o = idx - WT_N, hop = o >> 15, rem = o & 32767, n = rem >> 7, k = rem & 127;
            w1t[o] = __float2bfloat16(loadDyn(w1, hop * 32768 + k * 256 + n, isbf));
        } else if (idx < WT_N + W1T_N + W2T_N) { // 64N x 256K per hop
            int o = idx - WT_N - W1T_N, hop = o >> 14, rem = o & 16383, n = rem >> 8, k = rem & 255;
            w2t[o] = __float2bfloat16(loadDyn(w2, hop * 16384 + k * 64 + n, isbf));
        } else {                               // 16N x 128K per hop (row 15 zero)
            int o = idx - WT_N - W1T_N - W2T_N, hop = o >> 11, rem = o & 2047, n = rem >> 7, k = rem & 127;
            float v = (n < 15) ? loadDyn(wphi, hop * 1920 + k * 15 + n, isbf) : 0.f;
            wpt[o] = __float2bfloat16(v);
        }
        return;
    }
    b -= NB_WT;
    if (b < NB_H) {
        size_t base = ((size_t)b * 256 + threadIdx.x) * 8;
        cvt8(h_bf, h, base, isbf);
        return;
    }
    b -= NB_H;
    {
        size_t base = ((size_t)b * 256 + threadIdx.x) * 8;
        cvt8(e_bf, e, base, isbf);
    }
}

// ---------------------------------------------------------------------------
// MFMA GEMM device body: C = A @ B, A (M x K) bf16, Bt (N x K) bf16.
// BM=128, BK=64. OUTMODE: 0 = f32 direct store, 2 = fp8-e4m3 staged.
// Fragment layouts (HW-verified): A[m=lane&15][k=quad*8+j],
// B[k=quad*8+j][n=lane&15] (rows of Bt), C/D col=lane&15,row=quad*4+reg.
// ---------------------------------------------------------------------------
template <int BN, int WR, int WC, int OUTMODE, bool STAGED>
__device__ __forceinline__ void gemm_dev(
    char* smem, const bf16* __restrict__ A, const bf16* __restrict__ Bt,
    void* __restrict__ Cg, int K, int N, int colBase)
{
    constexpr int WM = 128 / WR;
    constexpr int WN = BN / WC;
    constexpr int MT = WM / 16;
    constexpr int NT = WN / 16;
    constexpr int ESZ = (OUTMODE == 0) ? 4 : 1;
    short* As = (short*)smem;            // [128][72]
    short* Bs = As + 128 * 72;           // [BN][72]

    int tid = threadIdx.x;
    int w = tid >> 6, lane = tid & 63;
    int wr = w / WC, wc = w % WC;
    int l16 = lane & 15, quad = lane >> 4;
    int rowBase = blockIdx.y * 128;

    f32x4 acc[MT][NT] = {};

    for (int k0 = 0; k0 < K; k0 += 64) {
        for (int c = tid; c < 128 * 8; c += 256) {
            int row = c >> 3, c8 = c & 7;
            *(short8*)&As[row * 72 + c8 * 8] =
                *(const short8*)(A + (size_t)(rowBase + row) * K + k0 + c8 * 8);
        }
        for (int c = tid; c < BN * 8; c += 256) {
            int row = c >> 3, c8 = c & 7;
            *(short8*)&Bs[row * 72 + c8 * 8] =
                *(const short8*)(Bt + (size_t)(colBase + row) * K + k0 + c8 * 8);
        }
        __syncthreads();
#pragma unroll
        for (int kc = 0; kc < 64; kc += 32) {
            short8 aF[MT], bF[NT];
#pragma unroll
            for (int mi = 0; mi < MT; mi++)
                aF[mi] = *(const short8*)&As[(wr * WM + mi * 16 + l16) * 72 + kc + quad * 8];
#pragma unroll
            for (int ni = 0; ni < NT; ni++)
                bF[ni] = *(const short8*)&Bs[(wc * WN + ni * 16 + l16) * 72 + kc + quad * 8];
#pragma unroll
            for (int mi = 0; mi < MT; mi++)
#pragma unroll
                for (int ni = 0; ni < NT; ni++)
                    acc[mi][ni] = __builtin_amdgcn_mfma_f32_16x16x32_bf16(
                        aF[mi], bF[ni], acc[mi][ni], 0, 0, 0);
        }
        __syncthreads();
    }

#pragma unroll
    for (int mi = 0; mi < MT; mi++) {
#pragma unroll
        for (int ni = 0; ni < NT; ni++) {
            int cl = wc * WN + ni * 16 + l16;
            int col = colBase + cl;
#pragma unroll
            for (int r = 0; r < 4; r++) {
                int rl = wr * WM + mi * 16 + quad * 4 + r;
                float v = acc[mi][ni][r];
                if (STAGED) {
                    size_t idx = (size_t)rl * BN + cl;
                    if (OUTMODE == 0) ((float*)smem)[idx] = v;
                    else {
                        int pk = __builtin_amdgcn_cvt_pk_fp8_f32(v, v, 0, false);
                        ((unsigned char*)smem)[idx] = (unsigned char)(pk & 0xFF);
                    }
                } else {
                    ((float*)Cg)[(size_t)(rowBase + rl) * N + col] = v;
                }
            }
        }
    }
    if (STAGED) {
        __syncthreads();
        constexpr int CPR = BN * ESZ / 16;           // 16B chunks per row
        for (int c = tid; c < 128 * CPR; c += 256) {
            int r = c / CPR, off = (c % CPR) * 16;
            *(uint4v*)((char*)Cg + ((size_t)(rowBase + r) * N + colBase) * ESZ + off) =
                *(const uint4v*)(smem + (size_t)r * BN * ESZ + off);
        }
    }
}

// Combined hk (fp8 out) + phi (f32 out) dispatch. grid (3, 128, HOPS):
// x<2 -> hk col block x; x==2 -> phi.
__global__ __launch_bounds__(256) void hkphi_kernel(
    const bf16* __restrict__ h_bf, const bf16* __restrict__ e_bf,
    const bf16* __restrict__ WT, const bf16* __restrict__ WPT,
    unsigned char* __restrict__ hk_f8, float* __restrict__ phi)
{
    __shared__ __align__(16) char smem[128 * 72 * 2 + 128 * 72 * 2];  // 36.9 kB
    int hop = blockIdx.z;
    if (blockIdx.x < 2) {
        gemm_dev<128, 2, 2, 2, true>(
            smem, h_bf, WT + (size_t)hop * 256 * 256,
            hk_f8 + (size_t)hop * N_NODES * 256, 256, 256, blockIdx.x * 128);
    } else {
        gemm_dev<16, 4, 1, 0, false>(
            smem, e_bf + (size_t)hop * N_NODES * 128, WPT + (size_t)hop * 16 * 128,
            phi + (size_t)hop * N_NODES * 16, 128, 16, 0);
    }
}

// ---------------------------------------------------------------------------
// hid_delta: fused  hid = relu(e@w1+b1)  ->  delta = hid@w2+b2 (+tn, l_focus).
// The hid tile (128x256) lives only in LDS. grid (128, HOPS).
// Phase 1: 4 waves 2x2, WM=64 WN=128. Phase 2: 4 waves row-split, WM=32 N=64,
// B-fragments read directly from L2-resident W2T.
// ---------------------------------------------------------------------------
__global__ __launch_bounds__(256) void hid_delta_kernel(
    const bf16* __restrict__ e_bf, const bf16* __restrict__ W1T,
    const bf16* __restrict__ W2T, const float* __restrict__ b1All,
    const float* __restrict__ b2All, const float* __restrict__ tnAll,
    float* __restrict__ DELTA, float* __restrict__ lfocus)
{
    __shared__ __align__(16) char smem[128 * 72 * 2 + 256 * 72 * 2 + 128 * 264 * 2]; // 120 kB
    __shared__ float s_w[4];
    short* As = (short*)smem;            // [128][72]
    short* Bs = As + 128 * 72;           // [256][72]
    short* Hs = Bs + 256 * 72;           // [128][264] hid tile (bf16 bits)
    float* Ds = (float*)smem;            // reuse As/Bs region: [128][64] f32

    int hop = blockIdx.y;
    int rowBase = blockIdx.x * 128;
    const bf16* A  = e_bf + (size_t)hop * N_NODES * 128;
    const bf16* B1 = W1T + (size_t)hop * 256 * 128;
    const bf16* B2 = W2T + (size_t)hop * 64 * 256;
    const float* b1 = b1All + hop * 256;
    const float* b2 = b2All + hop * 64;
    const float* tn = tnAll + hop * 64;

    int tid = threadIdx.x;
    int w = tid >> 6, lane = tid & 63;
    int l16 = lane & 15, quad = lane >> 4;

    // ---- phase 1: hid = relu(e @ w1 + b1) -> Hs ----
    {
        int wr = w >> 1, wc = w & 1;     // 2x2, WM=64, WN=128, MT=4, NT=8
        f32x4 acc[4][8] = {};
        for (int k0 = 0; k0 < 128; k0 += 64) {
            for (int c = tid; c < 128 * 8; c += 256) {
                int row = c >> 3, c8 = c & 7;
                *(short8*)&As[row * 72 + c8 * 8] =
                    *(const short8*)(A + (size_t)(rowBase + row) * 128 + k0 + c8 * 8);
            }
            for (int c = tid; c < 256 * 8; c += 256) {
                int row = c >> 3, c8 = c & 7;
                *(short8*)&Bs[row * 72 + c8 * 8] =
                    *(const short8*)(B1 + (size_t)row * 128 + k0 + c8 * 8);
            }
            __syncthreads();
#pragma unroll
            for (int kc = 0; kc < 64; kc += 32) {
                short8 aF[4], bF[8];
#pragma unroll
                for (int mi = 0; mi < 4; mi++)
                    aF[mi] = *(const short8*)&As[(wr * 64 + mi * 16 + l16) * 72 + kc + quad * 8];
#pragma unroll
                for (int ni = 0; ni < 8; ni++)
                    bF[ni] = *(const short8*)&Bs[(wc * 128 + ni * 16 + l16) * 72 + kc + quad * 8];
#pragma unroll
                for (int mi = 0; mi < 4; mi++)
#pragma unroll
                    for (int ni = 0; ni < 8; ni++)
                        acc[mi][ni] = __builtin_amdgcn_mfma_f32_16x16x32_bf16(
                            aF[mi], bF[ni], acc[mi][ni], 0, 0, 0);
            }
            __syncthreads();
        }
#pragma unroll
        for (int mi = 0; mi < 4; mi++) {
#pragma unroll
            for (int ni = 0; ni < 8; ni++) {
                int col = wc * 128 + ni * 16 + l16;
                float bv = b1[col];
#pragma unroll
                for (int r = 0; r < 4; r++) {
                    int row = wr * 64 + mi * 16 + quad * 4 + r;
                    float v = fmaxf(acc[mi][ni][r] + bv, 0.f);
                    Hs[row * 264 + col] = f2bfbits(v);
                }
            }
        }
        __syncthreads();
    }

    // ---- phase 2: delta = Hs @ w2 + b2; DELTA = delta + tn; l_focus ----
    {
        // 4 waves row-split: wave w -> rows w*32..w*32+31. MT=2, NT=4 (N=64).
        f32x4 acc[2][4] = {};
        for (int kc = 0; kc < 256; kc += 32) {
            short8 aF[2], bF[4];
#pragma unroll
            for (int mi = 0; mi < 2; mi++)
                aF[mi] = *(const short8*)&Hs[(w * 32 + mi * 16 + l16) * 264 + kc + quad * 8];
#pragma unroll
            for (int ni = 0; ni < 4; ni++)
                bF[ni] = *(const short8*)(B2 + (size_t)(ni * 16 + l16) * 256 + kc + quad * 8);
#pragma unroll
            for (int mi = 0; mi < 2; mi++)
#pragma unroll
                for (int ni = 0; ni < 4; ni++)
                    acc[mi][ni] = __builtin_amdgcn_mfma_f32_16x16x32_bf16(
                        aF[mi], bF[ni], acc[mi][ni], 0, 0, 0);
        }
        float sq = 0.f;
#pragma unroll
        for (int mi = 0; mi < 2; mi++) {
#pragma unroll
            for (int ni = 0; ni < 4; ni++) {
                int col = ni * 16 + l16;
                float bv = b2[col], tv = tn[col];
#pragma unroll
                for (int r = 0; r < 4; r++) {
                    int row = w * 32 + mi * 16 + quad * 4 + r;
                    float v = acc[mi][ni][r] + bv;
                    sq += v * v;
                    Ds[row * 64 + col] = v + tv;
                }
            }
        }
#pragma unroll
        for (int off = 32; off > 0; off >>= 1) sq += __shfl_xor(sq, off);
        if (lane == 0) s_w[w] = sq;
        __syncthreads();
        float* Dg = DELTA + (size_t)hop * N_NODES * 64;
        for (int c = tid; c < 128 * 16; c += 256) {       // 16 x 16B chunks/row
            int r = c >> 4, off = (c & 15) * 4;
            *(uint4v*)(Dg + (size_t)(rowBase + r) * 64 + off) =
                *(const uint4v*)(Ds + (size_t)r * 64 + off);
        }
        if (tid == 0) atomicAdd(lfocus, s_w[0] + s_w[1] + s_w[2] + s_w[3]);
    }
}

// ---------------------------------------------------------------------------
// edge_agg2: wave-synchronous, 4 nodes per 256-thread block, hop = blockIdx.y.
// hk is fp8-e4m3 (256B rows): lane loads 4B = 4 dims, decoded with
// v_cvt_pk_f32_fp8. att kept transposed [k][e].
// ---------------------------------------------------------------------------
__global__ __launch_bounds__(256) void edge_agg2(
    const unsigned char* __restrict__ hk, const float* __restrict__ phi,
    const float* __restrict__ dik, const int* __restrict__ src,
    const float* __restrict__ biasAll, float* __restrict__ outs)
{
    int hop = blockIdx.y;
    int wave = threadIdx.x >> 6, lane = threadIdx.x & 63;
    int node = blockIdx.x * 4 + wave;
    const unsigned char* hk_l = hk + (size_t)hop * N_NODES * 256;
    const float* phi_l  = phi + (size_t)hop * N_NODES * 16;
    const float* dik_l  = dik + (size_t)hop * N_NODES * 64;
    const int*   src_n  = src + (size_t)hop * E_EDGES + (size_t)node * 16;
    const float* bias_l = biasAll + hop * 64;
    float*       outs_n = outs + ((size_t)hop * N_NODES + node) * 64;

    __shared__ float s_dik[4][64];
    __shared__ float s_attT[4][4][20];   // [wave][k][edge], padded
    __shared__ int   s_src[4][16];

    s_dik[wave][lane] = dik_l[(size_t)node * 64 + lane];
    if (lane < 16) s_src[wave][lane] = src_n[lane];

    // ---- stage 1: dist + logits (4 lanes per edge; lane = 4e + q) ----
    int e = lane >> 2, q = lane & 3;
    int sN = s_src[wave][e];
    f32x4 ps = *(const f32x4*)(phi_l + (size_t)sN * 16 + q * 4);
    f32x4 pd = *(const f32x4*)(phi_l + (size_t)node * 16 + q * 4);
    float d0 = ps[0] - pd[0], d1 = ps[1] - pd[1];
    float d2 = ps[2] - pd[2], d3 = ps[3] - pd[3];
    bool q3 = (q == 3);            // p15 = flag col (phi col15 == 0)
    float nzf = ((d0 != 0.f) | (d1 != 0.f) | (d2 != 0.f) | (!q3 && d3 != 0.f)) ? 1.f : 0.f;
    float ssp = d0 * d0 + d1 * d1 + d2 * d2 + (q3 ? 0.f : d3 * d3);
    nzf += __shfl_xor(nzf, 1); nzf += __shfl_xor(nzf, 2);
    ssp += __shfl_xor(ssp, 1); ssp += __shfl_xor(ssp, 2);
    float last = (nzf == 0.f) ? 1.f : 0.f;
    if (q3) d3 = last;
    float inv = 1.f / fmaxf(sqrtf(ssp + last * last), 1e-8f);
#pragma unroll
    for (int k = 0; k < 4; k++) {
        const float* dk = &s_dik[wave][k * 16 + q * 4];
        float pk = d0 * dk[0] + d1 * dk[1] + d2 * dk[2] + d3 * dk[3];
        pk += __shfl_xor(pk, 1); pk += __shfl_xor(pk, 2);
        if (q == k) s_attT[wave][k][e] = pk * inv;
    }

    // ---- stage 2: softmax over 16 edges per k (lane = 4e + k) ----
    int k2 = lane & 3;
    float lgv = s_attT[wave][k2][e];
    float mx = lgv;
    mx = fmaxf(mx, __shfl_xor(mx, 4));
    mx = fmaxf(mx, __shfl_xor(mx, 8));
    mx = fmaxf(mx, __shfl_xor(mx, 16));
    mx = fmaxf(mx, __shfl_xor(mx, 32));
    float ex = expf(lgv - mx);
    float den = ex;
    den += __shfl_xor(den, 4);
    den += __shfl_xor(den, 8);
    den += __shfl_xor(den, 16);
    den += __shfl_xor(den, 32);
    s_attT[wave][k2][e] = ex / den;

    // ---- stage 3: aggregation (lane = kk*16 + dim-group; 4 dims/lane) ----
    int kk = lane >> 4, dsub = (lane & 15) * 4;
    f32x4 attv[4];
#pragma unroll
    for (int g = 0; g < 4; g++) attv[g] = *(const f32x4*)&s_attT[wave][kk][g * 4];
    float a0 = 0.f, a1 = 0.f, a2 = 0.f, a3 = 0.f;
#pragma unroll
    for (int ee = 0; ee < 16; ee++) {
        int sm = s_src[wave][ee];
        unsigned int u = *(const unsigned int*)(hk_l + (size_t)sm * 256 + lane * 4);
        float wgt = attv[ee >> 2][ee & 3];
        auto lo = __builtin_amdgcn_cvt_pk_f32_fp8((int)u, false);
        auto hi = __builtin_amdgcn_cvt_pk_f32_fp8((int)u, true);
        a0 += wgt * lo[0];
        a1 += wgt * lo[1];
        a2 += wgt * hi[0];
        a3 += wgt * hi[1];
    }
    a0 += __shfl_xor(a0, 16); a0 += __shfl_xor(a0, 32);
    a1 += __shfl_xor(a1, 16); a1 += __shfl_xor(a1, 32);
    a2 += __shfl_xor(a2, 16); a2 += __shfl_xor(a2, 32);
    a3 += __shfl_xor(a3, 16); a3 += __shfl_xor(a3, 32);
    float o0 = a0 + bias_l[dsub + 0];
    float o1 = a1 + bias_l[dsub + 1];
    float o2 = a2 + bias_l[dsub + 2];
    float o3 = a3 + bias_l[dsub + 3];
    float ssq = o0 * o0 + o1 * o1 + o2 * o2 + o3 * o3;
    ssq += __shfl_xor(ssq, 1);
    ssq += __shfl_xor(ssq, 2);
    ssq += __shfl_xor(ssq, 4);
    ssq += __shfl_xor(ssq, 8);
    float inv2 = 1.f / fmaxf(sqrtf(ssq), 1e-8f);
    if (kk == 0) {
        f32x4 st;
        st[0] = o0 * inv2; st[1] = o1 * inv2; st[2] = o2 * inv2; st[3] = o3 * inv2;
        *(f32x4*)(outs_n + dsub) = st;
    }
}

// Hop fusion + output store (dtype by flag) + scalar outputs (block 0).
__global__ __launch_bounds__(256) void fuse_kernel(
    const float* __restrict__ outs, const float* __restrict__ z,
    void* __restrict__ out, const int* __restrict__ flag,
    const float* __restrict__ acc)
{
    int tid = threadIdx.x;
    int node = blockIdx.x * 4 + (tid >> 6);
    int dd = tid & 63;
    float zv = z[dd];
    float o[4], sc[4];
#pragma unroll
    for (int h = 0; h < 4; h++) {
        o[h] = outs[((size_t)h * N_NODES + node) * 64 + dd];
        float v = o[h] * zv;
#pragma unroll
        for (int off = 32; off > 0; off >>= 1) v += __shfl_xor(v, off);
        sc[h] = v;
    }
    float mx = fmaxf(fmaxf(sc[0], sc[1]), fmaxf(sc[2], sc[3]));
    float e0 = expf(sc[0] - mx), e1 = expf(sc[1] - mx);
    float e2 = expf(sc[2] - mx), e3 = expf(sc[3] - mx);
    float den = e0 + e1 + e2 + e3;
    float t = (e0 * o[0] + e1 * o[1] + e2 * o[2] + e3 * o[3]) / den;
    size_t oi = (size_t)node * 64 + dd;
    bool isbf = (*flag != 0);
    if (isbf) ((bf16*)out)[oi] = __float2bfloat16(t);
    else      ((float*)out)[oi] = t;
    if (blockIdx.x == 0 && tid == 0) {
        float a = acc[0] * 0.25f;
        float b = acc[1] / ((float)N_NODES * 4.f * 4.f);
        size_t base = (size_t)N_NODES * 64;
        if (isbf) {
            ((bf16*)out)[base]     = __float2bfloat16(a);
            ((bf16*)out)[base + 1] = __float2bfloat16(b);
        } else {
            ((float*)out)[base]     = a;
            ((float*)out)[base + 1] = b;
        }
    }
}

extern "C" void kernel_launch(void* const* d_in, const int* in_sizes, int n_in,
                              void* d_out, int out_size, void* d_ws, size_t ws_size,
                              hipStream_t stream)
{
    const void* h    = d_in[0];
    const void* e    = d_in[1];
    const int*  src  = (const int*)d_in[2];
    const void* Wphi = d_in[4];
    const void* w1   = d_in[5];
    const void* b1   = d_in[6];
    const void* w2   = d_in[7];
    const void* b2   = d_in[8];
    const void* tphi = d_in[9];
    const void* W    = d_in[10];
    const void* bias = d_in[11];
    const void* z    = d_in[12];

    float* ws    = (float*)d_ws;
    float* CV    = ws;                                  // CV_END
    float* OUTS  = CV + CV_END;                         // 4*16384*64
    float* PHI   = OUTS + (size_t)4 * N_NODES * 64;     // 4*16384*16
    float* DELTA = PHI + (size_t)4 * N_NODES * 16;      // 4*16384*64
    float* TN    = DELTA + (size_t)4 * N_NODES * 64;    // 4*64
    float* ACC   = TN + 256;                            // 2 (+pad)
    int*   FLAG  = (int*)(ACC + 2);
    bf16*  H_BF  = (bf16*)(ACC + 4);                    // 16384*256
    bf16*  E_BF  = H_BF + (size_t)N_NODES * 256;        // 4*16384*128
    bf16*  WT    = E_BF + (size_t)HOPS * N_NODES * 128;
    bf16*  W1T   = WT + WT_N;
    bf16*  W2T   = W1T + W1T_N;
    bf16*  WPT   = W2T + W2T_N;
    unsigned char* HK_F8 = (unsigned char*)(WPT + WPT_N);  // 4*16384*256 bytes

    detect_kernel<<<1, 256, 0, stream>>>(h, FLAG, ACC);
    cvt_all<<<NB_ALL, 256, 0, stream>>>(
        h, e, Wphi, w1, b1, w2, b2, tphi, W, bias, z, CV,
        WT, W1T, W2T, WPT, H_BF, E_BF, TN, ACC, FLAG);

    // hk (fp8) + phi (f32) in one dispatch
    hkphi_kernel<<<dim3(3, 128, HOPS), 256, 0, stream>>>(
        H_BF, E_BF, WT, WPT, HK_F8, PHI);
    // hid (LDS-only) -> delta (+tn, l_focus) fused
    hid_delta_kernel<<<dim3(128, HOPS), 256, 0, stream>>>(
        E_BF, W1T, W2T, CV + CV_B1, CV + CV_B2, TN, DELTA, ACC + 1);
    // per-node edge softmax + aggregation + normalize (all hops)
    edge_agg2<<<dim3(N_NODES / 4, HOPS), 256, 0, stream>>>(
        HK_F8, PHI, DELTA, src, CV + CV_BIAS, OUTS);

    fuse_kernel<<<dim3(N_NODES / 4), 256, 0, stream>>>(
        OUTS, CV + CV_Z, d_out, FLAG, ACC);
}

// Round 10
// 232.875 us; speedup vs baseline: 7.0926x; 1.0259x over previous
//
#include <hip/hip_runtime.h>
#include <hip/hip_bf16.h>

#define N_NODES 16384
#define K_NBR 16
#define HOPS 4
#define IN_DIM 256
#define RAW_DIM 128
#define OUT_DIM 64
#define PHI_DIM 16
#define N_KERN 4
#define E_EDGES (N_NODES * K_NBR)

typedef __hip_bfloat16 bf16;
typedef __attribute__((ext_vector_type(8))) short short8;
typedef __attribute__((ext_vector_type(4))) float f32x4;
typedef __attribute__((ext_vector_type(4))) unsigned int uint4v;

__device__ __forceinline__ float toF(float x) { return x; }
__device__ __forceinline__ float toF(bf16 x) { return __bfloat162float(x); }
__device__ __forceinline__ short f2bfbits(float f)
{
    bf16 b = __float2bfloat16(f);
    short s; __builtin_memcpy(&s, &b, 2); return s;
}

// --------------------------- f32 workspace layout --------------------------
#define CV_WPHI 0
#define CV_W1   (CV_WPHI + HOPS * RAW_DIM * (PHI_DIM - 1))
#define CV_B1   (CV_W1 + HOPS * RAW_DIM * IN_DIM)
#define CV_W2   (CV_B1 + HOPS * IN_DIM)
#define CV_B2   (CV_W2 + HOPS * IN_DIM * PHI_DIM * N_KERN)
#define CV_TPHI (CV_B2 + HOPS * PHI_DIM * N_KERN)
#define CV_W    (CV_TPHI + HOPS * N_KERN * PHI_DIM)
#define CV_BIAS (CV_W + HOPS * IN_DIM * OUT_DIM * N_KERN)
#define CV_Z    (CV_BIAS + HOPS * OUT_DIM)
#define CV_END  (CV_Z + OUT_DIM)

// transposed bf16 weight region sizes
#define WT_N  (HOPS * 256 * 256)
#define W1T_N (HOPS * 256 * 128)
#define W2T_N (HOPS * 64 * 256)
#define WPT_N (HOPS * 16 * 128)
#define CVT_TOTAL (WT_N + W1T_N + W2T_N + WPT_N)

// cvt_all block ranges
#define NB_CV ((CV_END + 255) / 256)
#define NB_WT (CVT_TOTAL / 256)                      // exact
#define NB_H  (N_NODES * 256 / 8 / 256)              // h vec8 units
#define NB_E  (HOPS * N_NODES * 128 / 8 / 256)       // e vec8 units
#define NB_ALL (NB_CV + NB_WT + NB_H + NB_E + 1)

__device__ __forceinline__ float loadDyn(const void* p, int i, bool isbf)
{
    return isbf ? toF(((const bf16*)p)[i]) : ((const float*)p)[i];
}

// 8-wide dyn -> bf16 conversion helper
__device__ __forceinline__ void cvt8(bf16* dst, const void* src, size_t base, bool isbf)
{
    short8 v;
    if (isbf) {
        v = *(const short8*)((const bf16*)src + base);
    } else {
        const float* sp = (const float*)src + base;
        f32x4 f0 = *(const f32x4*)sp;
        f32x4 f1 = *(const f32x4*)(sp + 4);
#pragma unroll
        for (int j = 0; j < 4; j++) { v[j] = f2bfbits(f0[j]); v[4 + j] = f2bfbits(f1[j]); }
    }
    *(short8*)(dst + base) = v;
}

// ---------------------------------------------------------------------------
// cvt_all: (a) small weights -> f32 CV, (b) transposed bf16 weights,
// (c) h -> bf16, (d) e -> bf16 (vec8), (e) tn + l_sep + FLAG/ACC (last block).
// Each block SELF-DETECTS dtype from h's first 256 shorts: f32 data read as
// bf16 halves yields garbage exponents (>1e4 w.p. 1-1e-33); real bf16 ~ N(0,1).
// ---------------------------------------------------------------------------
__global__ __launch_bounds__(256) void cvt_all(
    const void* h, const void* e,
    const void* wphi, const void* w1, const void* b1, const void* w2,
    const void* b2, const void* tphi, const void* W, const void* bias,
    const void* z, float* __restrict__ CV,
    bf16* __restrict__ wt, bf16* __restrict__ w1t, bf16* __restrict__ w2t,
    bf16* __restrict__ wpt, bf16* __restrict__ h_bf, bf16* __restrict__ e_bf,
    float* __restrict__ tn_out, float* __restrict__ acc, int* __restrict__ flagOut)
{
    __shared__ float s_det[4];
    int tid = threadIdx.x;
    // ---- self-detect ----
    {
        unsigned short pv = ((const unsigned short*)h)[tid];
        unsigned int bits = ((unsigned int)pv) << 16;
        float v; __builtin_memcpy(&v, &bits, 4);
        v = fabsf(v);
        if (!(v == v) || v > 1e30f) v = 1e30f;
#pragma unroll
        for (int off = 32; off > 0; off >>= 1) v = fmaxf(v, __shfl_xor(v, off));
        if ((tid & 63) == 0) s_det[tid >> 6] = v;
    }
    __syncthreads();
    bool isbf = fmaxf(fmaxf(s_det[0], s_det[1]), fmaxf(s_det[2], s_det[3])) < 1e4f;

    int b = blockIdx.x;
    if (b == NB_ALL - 1) {
        // ---- tn = row-normalized tilde_phi (no eps) + l_sep; writes ACC/FLAG ----
        __shared__ float s_v[256], s_tn[256], s_red[256], s_hop[4];
        int hop = tid >> 6, t64 = tid & 63;
        int row = t64 >> 4, p = t64 & 15;
        float v = loadDyn(tphi, hop * 64 + t64, isbf);
        s_v[tid] = v;
        __syncthreads();
        float ss = 0.f;
        for (int q = 0; q < 16; q++) { float x = s_v[hop * 64 + row * 16 + q]; ss += x * x; }
        float tnv = v / sqrtf(ss);
        tn_out[hop * 64 + t64] = tnv;
        s_tn[tid] = tnv;
        __syncthreads();
        float s = 0.f;
        for (int j = 0; j < 4; j++) {
            float d = tnv - s_tn[hop * 64 + j * 16 + p];
            s += d * d;
        }
        s_red[tid] = s;
        __syncthreads();
        if (t64 == 0) {
            float tot = 0.f;
            for (int i = 0; i < 64; i++) tot += s_red[hop * 64 + i];
            s_hop[hop] = tot;
        }
        __syncthreads();
        if (tid == 0) {
            // l_sep = mean over hops of (tot_hop / nk) = sum * (1/4) * (1/4)
            acc[0] = (s_hop[0] + s_hop[1] + s_hop[2] + s_hop[3]) * 0.0625f;
            acc[1] = 0.f;                        // l_focus accumulator (hid_delta adds)
            *flagOut = isbf ? 1 : 0;
        }
        return;
    }
    if (b < NB_CV) {
        int idx = b * 256 + tid;
        if (idx >= CV_END) return;
        float v;
        if      (idx < CV_W1)   v = loadDyn(wphi, idx - CV_WPHI, isbf);
        else if (idx < CV_B1)   v = loadDyn(w1,   idx - CV_W1,   isbf);
        else if (idx < CV_W2)   v = loadDyn(b1,   idx - CV_B1,   isbf);
        else if (idx < CV_B2)   v = loadDyn(w2,   idx - CV_W2,   isbf);
        else if (idx < CV_TPHI) v = loadDyn(b2,   idx - CV_B2,   isbf);
        else if (idx < CV_W)    v = loadDyn(tphi, idx - CV_TPHI, isbf);
        else if (idx < CV_BIAS) v = loadDyn(W,    idx - CV_W,    isbf);
        else if (idx < CV_Z)    v = loadDyn(bias, idx - CV_BIAS, isbf);
        else                    v = loadDyn(z,    idx - CV_Z,    isbf);
        CV[idx] = v;
        return;
    }
    b -= NB_CV;
    if (b < NB_WT) {
        int idx = b * 256 + tid;
        if (idx < WT_N) {                      // 256N x 256K per hop
            int o = idx, hop = o >> 16, rem = o & 65535, n = rem >> 8, k = rem & 255;
            wt[o] = __float2bfloat16(loadDyn(W, hop * 65536 + k * 256 + n, isbf));
        } else if (idx < WT_N + W1T_N) {       // 256N x 128K per hop
            int o = idx - WT_N, hop = o >> 15, rem = o & 32767, n = rem >> 7, k = rem & 127;
            w1t[o] = __float2bfloat16(loadDyn(w1, hop * 32768 + k * 256 + n, isbf));
        } else if (idx < WT_N + W1T_N + W2T_N) { // 64N x 256K per hop
            int o = idx - WT_N - W1T_N, hop = o >> 14, rem = o & 16383, n = rem >> 8, k = rem & 255;
            w2t[o] = __float2bfloat16(loadDyn(w2, hop * 16384 + k * 64 + n, isbf));
        } else {                               // 16N x 128K per hop (row 15 zero)
            int o = idx - WT_N - W1T_N - W2T_N, hop = o >> 11, rem = o & 2047, n = rem >> 7, k = rem & 127;
            float v = (n < 15) ? loadDyn(wphi, hop * 1920 + k * 15 + n, isbf) : 0.f;
            wpt[o] = __float2bfloat16(v);
        }
        return;
    }
    b -= NB_WT;
    if (b < NB_H) {
        size_t base = ((size_t)b * 256 + tid) * 8;
        cvt8(h_bf, h, base, isbf);
        return;
    }
    b -= NB_H;
    {
        size_t base = ((size_t)b * 256 + tid) * 8;
        cvt8(e_bf, e, base, isbf);
    }
}

// ---------------------------------------------------------------------------
// MFMA GEMM device body: C = A @ B, A (M x K) bf16, Bt (N x K) bf16.
// BM=128, BK=64. OUTMODE: 0 = f32 direct store, 2 = fp8-e4m3 staged.
// Fragment layouts (HW-verified): A[m=lane&15][k=quad*8+j],
// B[k=quad*8+j][n=lane&15] (rows of Bt), C/D col=lane&15,row=quad*4+reg.
// ---------------------------------------------------------------------------
template <int BN, int WR, int WC, int OUTMODE, bool STAGED>
__device__ __forceinline__ void gemm_dev(
    char* smem, const bf16* __restrict__ A, const bf16* __restrict__ Bt,
    void* __restrict__ Cg, int K, int N, int colBase)
{
    constexpr int WM = 128 / WR;
    constexpr int WN = BN / WC;
    constexpr int MT = WM / 16;
    constexpr int NT = WN / 16;
    constexpr int ESZ = (OUTMODE == 0) ? 4 : 1;
    short* As = (short*)smem;            // [128][72]
    short* Bs = As + 128 * 72;           // [BN][72]

    int tid = threadIdx.x;
    int w = tid >> 6, lane = tid & 63;
    int wr = w / WC, wc = w % WC;
    int l16 = lane & 15, quad = lane >> 4;
    int rowBase = blockIdx.y * 128;

    f32x4 acc[MT][NT] = {};

    for (int k0 = 0; k0 < K; k0 += 64) {
        for (int c = tid; c < 128 * 8; c += 256) {
            int row = c >> 3, c8 = c & 7;
            *(short8*)&As[row * 72 + c8 * 8] =
                *(const short8*)(A + (size_t)(rowBase + row) * K + k0 + c8 * 8);
        }
        for (int c = tid; c < BN * 8; c += 256) {
            int row = c >> 3, c8 = c & 7;
            *(short8*)&Bs[row * 72 + c8 * 8] =
                *(const short8*)(Bt + (size_t)(colBase + row) * K + k0 + c8 * 8);
        }
        __syncthreads();
#pragma unroll
        for (int kc = 0; kc < 64; kc += 32) {
            short8 aF[MT], bF[NT];
#pragma unroll
            for (int mi = 0; mi < MT; mi++)
                aF[mi] = *(const short8*)&As[(wr * WM + mi * 16 + l16) * 72 + kc + quad * 8];
#pragma unroll
            for (int ni = 0; ni < NT; ni++)
                bF[ni] = *(const short8*)&Bs[(wc * WN + ni * 16 + l16) * 72 + kc + quad * 8];
#pragma unroll
            for (int mi = 0; mi < MT; mi++)
#pragma unroll
                for (int ni = 0; ni < NT; ni++)
                    acc[mi][ni] = __builtin_amdgcn_mfma_f32_16x16x32_bf16(
                        aF[mi], bF[ni], acc[mi][ni], 0, 0, 0);
        }
        __syncthreads();
    }

#pragma unroll
    for (int mi = 0; mi < MT; mi++) {
#pragma unroll
        for (int ni = 0; ni < NT; ni++) {
            int cl = wc * WN + ni * 16 + l16;
            int col = colBase + cl;
#pragma unroll
            for (int r = 0; r < 4; r++) {
                int rl = wr * WM + mi * 16 + quad * 4 + r;
                float v = acc[mi][ni][r];
                if (STAGED) {
                    size_t idx = (size_t)rl * BN + cl;
                    if (OUTMODE == 0) ((float*)smem)[idx] = v;
                    else {
                        int pk = __builtin_amdgcn_cvt_pk_fp8_f32(v, v, 0, false);
                        ((unsigned char*)smem)[idx] = (unsigned char)(pk & 0xFF);
                    }
                } else {
                    ((float*)Cg)[(size_t)(rowBase + rl) * N + col] = v;
                }
            }
        }
    }
    if (STAGED) {
        __syncthreads();
        constexpr int CPR = BN * ESZ / 16;           // 16B chunks per row
        for (int c = tid; c < 128 * CPR; c += 256) {
            int r = c / CPR, off = (c % CPR) * 16;
            *(uint4v*)((char*)Cg + ((size_t)(rowBase + r) * N + colBase) * ESZ + off) =
                *(const uint4v*)(smem + (size_t)r * BN * ESZ + off);
        }
    }
}

// Combined hk (fp8 out) + phi (f32 out) dispatch. grid (3, 128, HOPS):
// x<2 -> hk col block x; x==2 -> phi.
__global__ __launch_bounds__(256) void hkphi_kernel(
    const bf16* __restrict__ h_bf, const bf16* __restrict__ e_bf,
    const bf16* __restrict__ WT, const bf16* __restrict__ WPT,
    unsigned char* __restrict__ hk_f8, float* __restrict__ phi)
{
    __shared__ __align__(16) char smem[128 * 72 * 2 + 128 * 72 * 2];  // 36.9 kB
    int hop = blockIdx.z;
    if (blockIdx.x < 2) {
        gemm_dev<128, 2, 2, 2, true>(
            smem, h_bf, WT + (size_t)hop * 256 * 256,
            hk_f8 + (size_t)hop * N_NODES * 256, 256, 256, blockIdx.x * 128);
    } else {
        gemm_dev<16, 4, 1, 0, false>(
            smem, e_bf + (size_t)hop * N_NODES * 128, WPT + (size_t)hop * 16 * 128,
            phi + (size_t)hop * N_NODES * 16, 128, 16, 0);
    }
}

// ---------------------------------------------------------------------------
// hid_delta: fused  hid = relu(e@w1+b1)  ->  delta = hid@w2+b2 (+tn, l_focus).
// The hid tile (128x256) lives only in LDS. grid (128, HOPS).
// ---------------------------------------------------------------------------
__global__ __launch_bounds__(256) void hid_delta_kernel(
    const bf16* __restrict__ e_bf, const bf16* __restrict__ W1T,
    const bf16* __restrict__ W2T, const float* __restrict__ b1All,
    const float* __restrict__ b2All, const float* __restrict__ tnAll,
    float* __restrict__ DELTA, float* __restrict__ lfocus)
{
    __shared__ __align__(16) char smem[128 * 72 * 2 + 256 * 72 * 2 + 128 * 264 * 2]; // 120 kB
    __shared__ float s_w[4];
    short* As = (short*)smem;            // [128][72]
    short* Bs = As + 128 * 72;           // [256][72]
    short* Hs = Bs + 256 * 72;           // [128][264] hid tile (bf16 bits)
    float* Ds = (float*)smem;            // reuse As/Bs region: [128][64] f32

    int hop = blockIdx.y;
    int rowBase = blockIdx.x * 128;
    const bf16* A  = e_bf + (size_t)hop * N_NODES * 128;
    const bf16* B1 = W1T + (size_t)hop * 256 * 128;
    const bf16* B2 = W2T + (size_t)hop * 64 * 256;
    const float* b1 = b1All + hop * 256;
    const float* b2 = b2All + hop * 64;
    const float* tn = tnAll + hop * 64;

    int tid = threadIdx.x;
    int w = tid >> 6, lane = tid & 63;
    int l16 = lane & 15, quad = lane >> 4;

    // ---- phase 1: hid = relu(e @ w1 + b1) -> Hs ----
    {
        int wr = w >> 1, wc = w & 1;     // 2x2, WM=64, WN=128, MT=4, NT=8
        f32x4 acc[4][8] = {};
        for (int k0 = 0; k0 < 128; k0 += 64) {
            for (int c = tid; c < 128 * 8; c += 256) {
                int row = c >> 3, c8 = c & 7;
                *(short8*)&As[row * 72 + c8 * 8] =
                    *(const short8*)(A + (size_t)(rowBase + row) * 128 + k0 + c8 * 8);
            }
            for (int c = tid; c < 256 * 8; c += 256) {
                int row = c >> 3, c8 = c & 7;
                *(short8*)&Bs[row * 72 + c8 * 8] =
                    *(const short8*)(B1 + (size_t)row * 128 + k0 + c8 * 8);
            }
            __syncthreads();
#pragma unroll
            for (int kc = 0; kc < 64; kc += 32) {
                short8 aF[4], bF[8];
#pragma unroll
                for (int mi = 0; mi < 4; mi++)
                    aF[mi] = *(const short8*)&As[(wr * 64 + mi * 16 + l16) * 72 + kc + quad * 8];
#pragma unroll
                for (int ni = 0; ni < 8; ni++)
                    bF[ni] = *(const short8*)&Bs[(wc * 128 + ni * 16 + l16) * 72 + kc + quad * 8];
#pragma unroll
                for (int mi = 0; mi < 4; mi++)
#pragma unroll
                    for (int ni = 0; ni < 8; ni++)
                        acc[mi][ni] = __builtin_amdgcn_mfma_f32_16x16x32_bf16(
                            aF[mi], bF[ni], acc[mi][ni], 0, 0, 0);
            }
            __syncthreads();
        }
#pragma unroll
        for (int mi = 0; mi < 4; mi++) {
#pragma unroll
            for (int ni = 0; ni < 8; ni++) {
                int col = wc * 128 + ni * 16 + l16;
                float bv = b1[col];
#pragma unroll
                for (int r = 0; r < 4; r++) {
                    int row = wr * 64 + mi * 16 + quad * 4 + r;
                    float v = fmaxf(acc[mi][ni][r] + bv, 0.f);
                    Hs[row * 264 + col] = f2bfbits(v);
                }
            }
        }
        __syncthreads();
    }

    // ---- phase 2: delta = Hs @ w2 + b2; DELTA = delta + tn; l_focus ----
    {
        f32x4 acc[2][4] = {};
        for (int kc = 0; kc < 256; kc += 32) {
            short8 aF[2], bF[4];
#pragma unroll
            for (int mi = 0; mi < 2; mi++)
                aF[mi] = *(const short8*)&Hs[(w * 32 + mi * 16 + l16) * 264 + kc + quad * 8];
#pragma unroll
            for (int ni = 0; ni < 4; ni++)
                bF[ni] = *(const short8*)(B2 + (size_t)(ni * 16 + l16) * 256 + kc + quad * 8);
#pragma unroll
            for (int mi = 0; mi < 2; mi++)
#pragma unroll
                for (int ni = 0; ni < 4; ni++)
                    acc[mi][ni] = __builtin_amdgcn_mfma_f32_16x16x32_bf16(
                        aF[mi], bF[ni], acc[mi][ni], 0, 0, 0);
        }
        float sq = 0.f;
#pragma unroll
        for (int mi = 0; mi < 2; mi++) {
#pragma unroll
            for (int ni = 0; ni < 4; ni++) {
                int col = ni * 16 + l16;
                float bv = b2[col], tv = tn[col];
#pragma unroll
                for (int r = 0; r < 4; r++) {
                    int row = w * 32 + mi * 16 + quad * 4 + r;
                    float v = acc[mi][ni][r] + bv;
                    sq += v * v;
                    Ds[row * 64 + col] = v + tv;
                }
            }
        }
#pragma unroll
        for (int off = 32; off > 0; off >>= 1) sq += __shfl_xor(sq, off);
        if (lane == 0) s_w[w] = sq;
        __syncthreads();
        float* Dg = DELTA + (size_t)hop * N_NODES * 64;
        for (int c = tid; c < 128 * 16; c += 256) {       // 16 x 16B chunks/row
            int r = c >> 4, off = (c & 15) * 4;
            *(uint4v*)(Dg + (size_t)(rowBase + r) * 64 + off) =
                *(const uint4v*)(Ds + (size_t)r * 64 + off);
        }
        if (tid == 0) atomicAdd(lfocus, s_w[0] + s_w[1] + s_w[2] + s_w[3]);
    }
}

// ---------------------------------------------------------------------------
// edge_agg2: wave-synchronous, 4 nodes (one hop) per 256-thread block.
// 1-D grid, hop = blockIdx.x & 3: consecutive linear block ids carry
// different hops, so each XCD (round-robin by id) sees ONE hop -> its 4.2 MB
// fp8 hk fits that XCD's L2. src indices scalarized via readfirstlane
// (wave-uniform) so gather addresses are SGPR-base + lane*4.
// ---------------------------------------------------------------------------
__global__ __launch_bounds__(256) void edge_agg2(
    const unsigned char* __restrict__ hk, const float* __restrict__ phi,
    const float* __restrict__ dik, const int* __restrict__ src,
    const float* __restrict__ biasAll, float* __restrict__ outs)
{
    int b = blockIdx.x;
    int hop = b & 3;                 // XCD affinity: hop h -> XCDs {h, h+4}
    int wave = threadIdx.x >> 6, lane = threadIdx.x & 63;
    int node = (b >> 2) * 4 + wave;
    const unsigned char* hk_l = hk + (size_t)hop * N_NODES * 256;
    const float* phi_l  = phi + (size_t)hop * N_NODES * 16;
    const float* dik_l  = dik + (size_t)hop * N_NODES * 64;
    const int*   src_n  = src + (size_t)hop * E_EDGES + (size_t)node * 16;
    const float* bias_l = biasAll + hop * 64;
    float*       outs_n = outs + ((size_t)hop * N_NODES + node) * 64;

    __shared__ float s_dik[4][64];
    __shared__ float s_attT[4][4][20];   // [wave][k][edge], padded
    __shared__ int   s_src[4][16];

    s_dik[wave][lane] = dik_l[(size_t)node * 64 + lane];
    if (lane < 16) s_src[wave][lane] = src_n[lane];

    // ---- stage 1: dist + logits (4 lanes per edge; lane = 4e + q) ----
    int e = lane >> 2, q = lane & 3;
    int sN = s_src[wave][e];
    f32x4 ps = *(const f32x4*)(phi_l + (size_t)sN * 16 + q * 4);
    f32x4 pd = *(const f32x4*)(phi_l + (size_t)node * 16 + q * 4);
    float d0 = ps[0] - pd[0], d1 = ps[1] - pd[1];
    float d2 = ps[2] - pd[2], d3 = ps[3] - pd[3];
    bool q3 = (q == 3);            // p15 = flag col (phi col15 == 0)
    float nzf = ((d0 != 0.f) | (d1 != 0.f) | (d2 != 0.f) | (!q3 && d3 != 0.f)) ? 1.f : 0.f;
    float ssp = d0 * d0 + d1 * d1 + d2 * d2 + (q3 ? 0.f : d3 * d3);
    nzf += __shfl_xor(nzf, 1); nzf += __shfl_xor(nzf, 2);
    ssp += __shfl_xor(ssp, 1); ssp += __shfl_xor(ssp, 2);
    float last = (nzf == 0.f) ? 1.f : 0.f;
    if (q3) d3 = last;
    float inv = 1.f / fmaxf(sqrtf(ssp + last * last), 1e-8f);
#pragma unroll
    for (int k = 0; k < 4; k++) {
        const float* dk = &s_dik[wave][k * 16 + q * 4];
        float pk = d0 * dk[0] + d1 * dk[1] + d2 * dk[2] + d3 * dk[3];
        pk += __shfl_xor(pk, 1); pk += __shfl_xor(pk, 2);
        if (q == k) s_attT[wave][k][e] = pk * inv;
    }

    // ---- stage 2: softmax over 16 edges per k (lane = 4e + k) ----
    int k2 = lane & 3;
    float lgv = s_attT[wave][k2][e];
    float mx = lgv;
    mx = fmaxf(mx, __shfl_xor(mx, 4));
    mx = fmaxf(mx, __shfl_xor(mx, 8));
    mx = fmaxf(mx, __shfl_xor(mx, 16));
    mx = fmaxf(mx, __shfl_xor(mx, 32));
    float ex = expf(lgv - mx);
    float den = ex;
    den += __shfl_xor(den, 4);
    den += __shfl_xor(den, 8);
    den += __shfl_xor(den, 16);
    den += __shfl_xor(den, 32);
    s_attT[wave][k2][e] = ex / den;

    // ---- stage 3: aggregation (lane = kk*16 + dim-group; 4 dims/lane) ----
    int kk = lane >> 4, dsub = (lane & 15) * 4;
    f32x4 attv[4];
#pragma unroll
    for (int g = 0; g < 4; g++) attv[g] = *(const f32x4*)&s_attT[wave][kk][g * 4];
    float a0 = 0.f, a1 = 0.f, a2 = 0.f, a3 = 0.f;
#pragma unroll
    for (int ee = 0; ee < 16; ee++) {
        int sm = __builtin_amdgcn_readfirstlane(s_src[wave][ee]);  // wave-uniform
        unsigned int u = *(const unsigned int*)(hk_l + (size_t)sm * 256 + lane * 4);
        float wgt = attv[ee >> 2][ee & 3];
        auto lo = __builtin_amdgcn_cvt_pk_f32_fp8((int)u, false);
        auto hi = __builtin_amdgcn_cvt_pk_f32_fp8((int)u, true);
        a0 += wgt * lo[0];
        a1 += wgt * lo[1];
        a2 += wgt * hi[0];
        a3 += wgt * hi[1];
    }
    a0 += __shfl_xor(a0, 16); a0 += __shfl_xor(a0, 32);
    a1 += __shfl_xor(a1, 16); a1 += __shfl_xor(a1, 32);
    a2 += __shfl_xor(a2, 16); a2 += __shfl_xor(a2, 32);
    a3 += __shfl_xor(a3, 16); a3 += __shfl_xor(a3, 32);
    float o0 = a0 + bias_l[dsub + 0];
    float o1 = a1 + bias_l[dsub + 1];
    float o2 = a2 + bias_l[dsub + 2];
    float o3 = a3 + bias_l[dsub + 3];
    float ssq = o0 * o0 + o1 * o1 + o2 * o2 + o3 * o3;
    ssq += __shfl_xor(ssq, 1);
    ssq += __shfl_xor(ssq, 2);
    ssq += __shfl_xor(ssq, 4);
    ssq += __shfl_xor(ssq, 8);
    float inv2 = 1.f / fmaxf(sqrtf(ssq), 1e-8f);
    if (kk == 0) {
        f32x4 st;
        st[0] = o0 * inv2; st[1] = o1 * inv2; st[2] = o2 * inv2; st[3] = o3 * inv2;
        *(f32x4*)(outs_n + dsub) = st;
    }
}

// Hop fusion + output store (dtype by flag) + scalar outputs (block 0).
__global__ __launch_bounds__(256) void fuse_kernel(
    const float* __restrict__ outs, const float* __restrict__ z,
    void* __restrict__ out, const int* __restrict__ flag,
    const float* __restrict__ acc)
{
    int tid = threadIdx.x;
    int node = blockIdx.x * 4 + (tid >> 6);
    int dd = tid & 63;
    float zv = z[dd];
    float o[4], sc[4];
#pragma unroll
    for (int h = 0; h < 4; h++) {
        o[h] = outs[((size_t)h * N_NODES + node) * 64 + dd];
        float v = o[h] * zv;
#pragma unroll
        for (int off = 32; off > 0; off >>= 1) v += __shfl_xor(v, off);
        sc[h] = v;
    }
    float mx = fmaxf(fmaxf(sc[0], sc[1]), fmaxf(sc[2], sc[3]));
    float e0 = expf(sc[0] - mx), e1 = expf(sc[1] - mx);
    float e2 = expf(sc[2] - mx), e3 = expf(sc[3] - mx);
    float den = e0 + e1 + e2 + e3;
    float t = (e0 * o[0] + e1 * o[1] + e2 * o[2] + e3 * o[3]) / den;
    size_t oi = (size_t)node * 64 + dd;
    bool isbf = (*flag != 0);
    if (isbf) ((bf16*)out)[oi] = __float2bfloat16(t);
    else      ((float*)out)[oi] = t;
    if (blockIdx.x == 0 && tid == 0) {
        float a = acc[0];                                 // l_sep (already scaled)
        float b = acc[1] / ((float)N_NODES * 4.f * 4.f);  // l_focus mean
        size_t base = (size_t)N_NODES * 64;
        if (isbf) {
            ((bf16*)out)[base]     = __float2bfloat16(a);
            ((bf16*)out)[base + 1] = __float2bfloat16(b);
        } else {
            ((float*)out)[base]     = a;
            ((float*)out)[base + 1] = b;
        }
    }
}

extern "C" void kernel_launch(void* const* d_in, const int* in_sizes, int n_in,
                              void* d_out, int out_size, void* d_ws, size_t ws_size,
                              hipStream_t stream)
{
    const void* h    = d_in[0];
    const void* e    = d_in[1];
    const int*  src  = (const int*)d_in[2];
    const void* Wphi = d_in[4];
    const void* w1   = d_in[5];
    const void* b1   = d_in[6];
    const void* w2   = d_in[7];
    const void* b2   = d_in[8];
    const void* tphi = d_in[9];
    const void* W    = d_in[10];
    const void* bias = d_in[11];
    const void* z    = d_in[12];

    float* ws    = (float*)d_ws;
    float* CV    = ws;                                  // CV_END
    float* OUTS  = CV + CV_END;                         // 4*16384*64
    float* PHI   = OUTS + (size_t)4 * N_NODES * 64;     // 4*16384*16
    float* DELTA = PHI + (size_t)4 * N_NODES * 16;      // 4*16384*64
    float* TN    = DELTA + (size_t)4 * N_NODES * 64;    // 4*64
    float* ACC   = TN + 256;                            // 2 (+pad)
    int*   FLAG  = (int*)(ACC + 2);
    bf16*  H_BF  = (bf16*)(ACC + 4);                    // 16384*256
    bf16*  E_BF  = H_BF + (size_t)N_NODES * 256;        // 4*16384*128
    bf16*  WT    = E_BF + (size_t)HOPS * N_NODES * 128;
    bf16*  W1T   = WT + WT_N;
    bf16*  W2T   = W1T + W1T_N;
    bf16*  WPT   = W2T + W2T_N;
    unsigned char* HK_F8 = (unsigned char*)(WPT + WPT_N);  // 4*16384*256 bytes

    // conversions + tn/l_sep + dtype flag + ACC init (self-detecting blocks)
    cvt_all<<<NB_ALL, 256, 0, stream>>>(
        h, e, Wphi, w1, b1, w2, b2, tphi, W, bias, z, CV,
        WT, W1T, W2T, WPT, H_BF, E_BF, TN, ACC, FLAG);

    // hk (fp8) + phi (f32) in one dispatch
    hkphi_kernel<<<dim3(3, 128, HOPS), 256, 0, stream>>>(
        H_BF, E_BF, WT, WPT, HK_F8, PHI);
    // hid (LDS-only) -> delta (+tn, l_focus) fused
    hid_delta_kernel<<<dim3(128, HOPS), 256, 0, stream>>>(
        E_BF, W1T, W2T, CV + CV_B1, CV + CV_B2, TN, DELTA, ACC + 1);
    // per-node edge softmax + aggregation + normalize (hop-XCD-affine)
    edge_agg2<<<dim3(N_NODES), 256, 0, stream>>>(
        HK_F8, PHI, DELTA, src, CV + CV_BIAS, OUTS);

    fuse_kernel<<<dim3(N_NODES / 4), 256, 0, stream>>>(
        OUTS, CV + CV_Z, d_out, FLAG, ACC);
}

// Round 11
// 232.580 us; speedup vs baseline: 7.1016x; 1.0013x over previous
//
#include <hip/hip_runtime.h>
#include <hip/hip_bf16.h>

#define N_NODES 16384
#define K_NBR 16
#define HOPS 4
#define IN_DIM 256
#define RAW_DIM 128
#define OUT_DIM 64
#define PHI_DIM 16
#define N_KERN 4
#define E_EDGES (N_NODES * K_NBR)

typedef __hip_bfloat16 bf16;
typedef __attribute__((ext_vector_type(8))) short short8;
typedef __attribute__((ext_vector_type(4))) float f32x4;
typedef __attribute__((ext_vector_type(4))) unsigned int uint4v;

__device__ __forceinline__ float toF(float x) { return x; }
__device__ __forceinline__ float toF(bf16 x) { return __bfloat162float(x); }
__device__ __forceinline__ short f2bfbits(float f)
{
    bf16 b = __float2bfloat16(f);
    short s; __builtin_memcpy(&s, &b, 2); return s;
}

// --------------------------- f32 workspace layout --------------------------
#define CV_WPHI 0
#define CV_W1   (CV_WPHI + HOPS * RAW_DIM * (PHI_DIM - 1))
#define CV_B1   (CV_W1 + HOPS * RAW_DIM * IN_DIM)
#define CV_W2   (CV_B1 + HOPS * IN_DIM)
#define CV_B2   (CV_W2 + HOPS * IN_DIM * PHI_DIM * N_KERN)
#define CV_TPHI (CV_B2 + HOPS * PHI_DIM * N_KERN)
#define CV_W    (CV_TPHI + HOPS * N_KERN * PHI_DIM)
#define CV_BIAS (CV_W + HOPS * IN_DIM * OUT_DIM * N_KERN)
#define CV_Z    (CV_BIAS + HOPS * OUT_DIM)
#define CV_END  (CV_Z + OUT_DIM)

// transposed bf16 weight region sizes
#define WT_N  (HOPS * 256 * 256)
#define W1T_N (HOPS * 256 * 128)
#define W2T_N (HOPS * 64 * 256)
#define WPT_N (HOPS * 16 * 128)
#define CVT_TOTAL (WT_N + W1T_N + W2T_N + WPT_N)

// cvt_all block ranges
#define NB_CV ((CV_END + 255) / 256)
#define NB_WT (CVT_TOTAL / 256)                      // exact
#define NB_H  (N_NODES * 256 / 8 / 256)              // h vec8 units
#define NB_E  (HOPS * N_NODES * 128 / 8 / 256)       // e vec8 units
#define NB_ALL (NB_CV + NB_WT + NB_H + NB_E + 1)

__device__ __forceinline__ float loadDyn(const void* p, int i, bool isbf)
{
    return isbf ? toF(((const bf16*)p)[i]) : ((const float*)p)[i];
}

// 8-wide dyn -> bf16 conversion helper
__device__ __forceinline__ void cvt8(bf16* dst, const void* src, size_t base, bool isbf)
{
    short8 v;
    if (isbf) {
        v = *(const short8*)((const bf16*)src + base);
    } else {
        const float* sp = (const float*)src + base;
        f32x4 f0 = *(const f32x4*)sp;
        f32x4 f1 = *(const f32x4*)(sp + 4);
#pragma unroll
        for (int j = 0; j < 4; j++) { v[j] = f2bfbits(f0[j]); v[4 + j] = f2bfbits(f1[j]); }
    }
    *(short8*)(dst + base) = v;
}

// ---------------------------------------------------------------------------
// cvt_all: (a) small weights -> f32 CV, (b) transposed bf16 weights,
// (c) h -> bf16, (d) e -> bf16 (vec8), (e) tn + l_sep + FLAG/ACC (last block).
// Each block SELF-DETECTS dtype from h's first 256 shorts: f32 data read as
// bf16 halves yields garbage exponents (>1e4 w.p. 1-1e-33); real bf16 ~ N(0,1).
// ---------------------------------------------------------------------------
__global__ __launch_bounds__(256) void cvt_all(
    const void* h, const void* e,
    const void* wphi, const void* w1, const void* b1, const void* w2,
    const void* b2, const void* tphi, const void* W, const void* bias,
    const void* z, float* __restrict__ CV,
    bf16* __restrict__ wt, bf16* __restrict__ w1t, bf16* __restrict__ w2t,
    bf16* __restrict__ wpt, bf16* __restrict__ h_bf, bf16* __restrict__ e_bf,
    float* __restrict__ tn_out, float* __restrict__ acc, int* __restrict__ flagOut)
{
    __shared__ float s_det[4];
    int tid = threadIdx.x;
    // ---- self-detect ----
    {
        unsigned short pv = ((const unsigned short*)h)[tid];
        unsigned int bits = ((unsigned int)pv) << 16;
        float v; __builtin_memcpy(&v, &bits, 4);
        v = fabsf(v);
        if (!(v == v) || v > 1e30f) v = 1e30f;
#pragma unroll
        for (int off = 32; off > 0; off >>= 1) v = fmaxf(v, __shfl_xor(v, off));
        if ((tid & 63) == 0) s_det[tid >> 6] = v;
    }
    __syncthreads();
    bool isbf = fmaxf(fmaxf(s_det[0], s_det[1]), fmaxf(s_det[2], s_det[3])) < 1e4f;

    int b = blockIdx.x;
    if (b == NB_ALL - 1) {
        // ---- tn = row-normalized tilde_phi (no eps) + l_sep; writes ACC/FLAG ----
        __shared__ float s_v[256], s_tn[256], s_red[256], s_hop[4];
        int hop = tid >> 6, t64 = tid & 63;
        int row = t64 >> 4, p = t64 & 15;
        float v = loadDyn(tphi, hop * 64 + t64, isbf);
        s_v[tid] = v;
        __syncthreads();
        float ss = 0.f;
        for (int q = 0; q < 16; q++) { float x = s_v[hop * 64 + row * 16 + q]; ss += x * x; }
        float tnv = v / sqrtf(ss);
        tn_out[hop * 64 + t64] = tnv;
        s_tn[tid] = tnv;
        __syncthreads();
        float s = 0.f;
        for (int j = 0; j < 4; j++) {
            float d = tnv - s_tn[hop * 64 + j * 16 + p];
            s += d * d;
        }
        s_red[tid] = s;
        __syncthreads();
        if (t64 == 0) {
            float tot = 0.f;
            for (int i = 0; i < 64; i++) tot += s_red[hop * 64 + i];
            s_hop[hop] = tot;
        }
        __syncthreads();
        if (tid == 0) {
            // l_sep = mean over hops of (tot_hop / nk) = sum * (1/4) * (1/4)
            acc[0] = (s_hop[0] + s_hop[1] + s_hop[2] + s_hop[3]) * 0.0625f;
            acc[1] = 0.f;                        // l_focus accumulator (hid_delta adds)
            *flagOut = isbf ? 1 : 0;
        }
        return;
    }
    if (b < NB_CV) {
        int idx = b * 256 + tid;
        if (idx >= CV_END) return;
        float v;
        if      (idx < CV_W1)   v = loadDyn(wphi, idx - CV_WPHI, isbf);
        else if (idx < CV_B1)   v = loadDyn(w1,   idx - CV_W1,   isbf);
        else if (idx < CV_W2)   v = loadDyn(b1,   idx - CV_B1,   isbf);
        else if (idx < CV_B2)   v = loadDyn(w2,   idx - CV_W2,   isbf);
        else if (idx < CV_TPHI) v = loadDyn(b2,   idx - CV_B2,   isbf);
        else if (idx < CV_W)    v = loadDyn(tphi, idx - CV_TPHI, isbf);
        else if (idx < CV_BIAS) v = loadDyn(W,    idx - CV_W,    isbf);
        else if (idx < CV_Z)    v = loadDyn(bias, idx - CV_BIAS, isbf);
        else                    v = loadDyn(z,    idx - CV_Z,    isbf);
        CV[idx] = v;
        return;
    }
    b -= NB_CV;
    if (b < NB_WT) {
        int idx = b * 256 + tid;
        if (idx < WT_N) {                      // 256N x 256K per hop
            int o = idx, hop = o >> 16, rem = o & 65535, n = rem >> 8, k = rem & 255;
            wt[o] = __float2bfloat16(loadDyn(W, hop * 65536 + k * 256 + n, isbf));
        } else if (idx < WT_N + W1T_N) {       // 256N x 128K per hop
            int o = idx - WT_N, hop = o >> 15, rem = o & 32767, n = rem >> 7, k = rem & 127;
            w1t[o] = __float2bfloat16(loadDyn(w1, hop * 32768 + k * 256 + n, isbf));
        } else if (idx < WT_N + W1T_N + W2T_N) { // 64N x 256K per hop
            int o = idx - WT_N - W1T_N, hop = o >> 14, rem = o & 16383, n = rem >> 8, k = rem & 255;
            w2t[o] = __float2bfloat16(loadDyn(w2, hop * 16384 + k * 64 + n, isbf));
        } else {                               // 16N x 128K per hop (row 15 zero)
            int o = idx - WT_N - W1T_N - W2T_N, hop = o >> 11, rem = o & 2047, n = rem >> 7, k = rem & 127;
            float v = (n < 15) ? loadDyn(wphi, hop * 1920 + k * 15 + n, isbf) : 0.f;
            wpt[o] = __float2bfloat16(v);
        }
        return;
    }
    b -= NB_WT;
    if (b < NB_H) {
        size_t base = ((size_t)b * 256 + tid) * 8;
        cvt8(h_bf, h, base, isbf);
        return;
    }
    b -= NB_H;
    {
        size_t base = ((size_t)b * 256 + tid) * 8;
        cvt8(e_bf, e, base, isbf);
    }
}

// ---------------------------------------------------------------------------
// MFMA GEMM device body: C = A @ B, A (M x K) bf16, Bt (N x K) bf16.
// BM=128, BK=64. OUTMODE: 0 = f32 direct store, 2 = fp8-e4m3 staged.
// Fragment layouts (HW-verified): A[m=lane&15][k=quad*8+j],
// B[k=quad*8+j][n=lane&15] (rows of Bt), C/D col=lane&15,row=quad*4+reg.
// ---------------------------------------------------------------------------
template <int BN, int WR, int WC, int OUTMODE, bool STAGED>
__device__ __forceinline__ void gemm_dev(
    char* smem, const bf16* __restrict__ A, const bf16* __restrict__ Bt,
    void* __restrict__ Cg, int K, int N, int colBase)
{
    constexpr int WM = 128 / WR;
    constexpr int WN = BN / WC;
    constexpr int MT = WM / 16;
    constexpr int NT = WN / 16;
    constexpr int ESZ = (OUTMODE == 0) ? 4 : 1;
    short* As = (short*)smem;            // [128][72]
    short* Bs = As + 128 * 72;           // [BN][72]

    int tid = threadIdx.x;
    int w = tid >> 6, lane = tid & 63;
    int wr = w / WC, wc = w % WC;
    int l16 = lane & 15, quad = lane >> 4;
    int rowBase = blockIdx.y * 128;

    f32x4 acc[MT][NT] = {};

    for (int k0 = 0; k0 < K; k0 += 64) {
        for (int c = tid; c < 128 * 8; c += 256) {
            int row = c >> 3, c8 = c & 7;
            *(short8*)&As[row * 72 + c8 * 8] =
                *(const short8*)(A + (size_t)(rowBase + row) * K + k0 + c8 * 8);
        }
        for (int c = tid; c < BN * 8; c += 256) {
            int row = c >> 3, c8 = c & 7;
            *(short8*)&Bs[row * 72 + c8 * 8] =
                *(const short8*)(Bt + (size_t)(colBase + row) * K + k0 + c8 * 8);
        }
        __syncthreads();
#pragma unroll
        for (int kc = 0; kc < 64; kc += 32) {
            short8 aF[MT], bF[NT];
#pragma unroll
            for (int mi = 0; mi < MT; mi++)
                aF[mi] = *(const short8*)&As[(wr * WM + mi * 16 + l16) * 72 + kc + quad * 8];
#pragma unroll
            for (int ni = 0; ni < NT; ni++)
                bF[ni] = *(const short8*)&Bs[(wc * WN + ni * 16 + l16) * 72 + kc + quad * 8];
#pragma unroll
            for (int mi = 0; mi < MT; mi++)
#pragma unroll
                for (int ni = 0; ni < NT; ni++)
                    acc[mi][ni] = __builtin_amdgcn_mfma_f32_16x16x32_bf16(
                        aF[mi], bF[ni], acc[mi][ni], 0, 0, 0);
        }
        __syncthreads();
    }

#pragma unroll
    for (int mi = 0; mi < MT; mi++) {
#pragma unroll
        for (int ni = 0; ni < NT; ni++) {
            int cl = wc * WN + ni * 16 + l16;
            int col = colBase + cl;
#pragma unroll
            for (int r = 0; r < 4; r++) {
                int rl = wr * WM + mi * 16 + quad * 4 + r;
                float v = acc[mi][ni][r];
                if (STAGED) {
                    size_t idx = (size_t)rl * BN + cl;
                    if (OUTMODE == 0) ((float*)smem)[idx] = v;
                    else {
                        int pk = __builtin_amdgcn_cvt_pk_fp8_f32(v, v, 0, false);
                        ((unsigned char*)smem)[idx] = (unsigned char)(pk & 0xFF);
                    }
                } else {
                    ((float*)Cg)[(size_t)(rowBase + rl) * N + col] = v;
                }
            }
        }
    }
    if (STAGED) {
        __syncthreads();
        constexpr int CPR = BN * ESZ / 16;           // 16B chunks per row
        for (int c = tid; c < 128 * CPR; c += 256) {
            int r = c / CPR, off = (c % CPR) * 16;
            *(uint4v*)((char*)Cg + ((size_t)(rowBase + r) * N + colBase) * ESZ + off) =
                *(const uint4v*)(smem + (size_t)r * BN * ESZ + off);
        }
    }
}

// Combined hk (fp8 out) + phi (f32 out) dispatch. grid (3, 128, HOPS):
// x<2 -> hk col block x; x==2 -> phi.
__global__ __launch_bounds__(256) void hkphi_kernel(
    const bf16* __restrict__ h_bf, const bf16* __restrict__ e_bf,
    const bf16* __restrict__ WT, const bf16* __restrict__ WPT,
    unsigned char* __restrict__ hk_f8, float* __restrict__ phi)
{
    __shared__ __align__(16) char smem[128 * 72 * 2 + 128 * 72 * 2];  // 36.9 kB
    int hop = blockIdx.z;
    if (blockIdx.x < 2) {
        gemm_dev<128, 2, 2, 2, true>(
            smem, h_bf, WT + (size_t)hop * 256 * 256,
            hk_f8 + (size_t)hop * N_NODES * 256, 256, 256, blockIdx.x * 128);
    } else {
        gemm_dev<16, 4, 1, 0, false>(
            smem, e_bf + (size_t)hop * N_NODES * 128, WPT + (size_t)hop * 16 * 128,
            phi + (size_t)hop * N_NODES * 16, 128, 16, 0);
    }
}

// ---------------------------------------------------------------------------
// hid_delta: fused  hid = relu(e@w1+b1)  ->  delta = hid@w2+b2 (+tn, l_focus).
// 64-row tiles: LDS = As(9.2k) + Bs(36.9k) + Hs(33.8k) = 79.9 kB -> 2 blk/CU.
// Phase 1: 4 waves col-split (wave w -> cols w*64..+63), MT=4, NT=4.
// B2 staged into Bs region (dead after phase 1); phase 2 pure LDS + MFMA.
// grid (N_NODES/64, HOPS).
// ---------------------------------------------------------------------------
__global__ __launch_bounds__(256) void hid_delta_kernel(
    const bf16* __restrict__ e_bf, const bf16* __restrict__ W1T,
    const bf16* __restrict__ W2T, const float* __restrict__ b1All,
    const float* __restrict__ b2All, const float* __restrict__ tnAll,
    float* __restrict__ DELTA, float* __restrict__ lfocus)
{
    __shared__ __align__(16) char smem[64 * 72 * 2 + 256 * 72 * 2 + 64 * 264 * 2]; // 79.9 kB
    __shared__ float s_w[4];
    short* As  = (short*)smem;           // [64][72]
    short* Bs  = As + 64 * 72;           // [256][72] phase 1 / B2s [64][264] phase 2
    short* Hs  = Bs + 256 * 72;          // [64][264] hid tile (bf16 bits)
    short* B2s = Bs;
    float* Ds  = (float*)smem;           // [64][64] f32, aliases As + Bs-front

    int hop = blockIdx.y;
    int rowBase = blockIdx.x * 64;
    const bf16* A  = e_bf + (size_t)hop * N_NODES * 128;
    const bf16* B1 = W1T + (size_t)hop * 256 * 128;
    const bf16* B2 = W2T + (size_t)hop * 64 * 256;
    const float* b1 = b1All + hop * 256;
    const float* b2 = b2All + hop * 64;
    const float* tn = tnAll + hop * 64;

    int tid = threadIdx.x;
    int w = tid >> 6, lane = tid & 63;
    int l16 = lane & 15, quad = lane >> 4;

    // ---- phase 1: hid = relu(e @ w1 + b1) -> Hs ----
    {
        f32x4 acc[4][4] = {};
        for (int k0 = 0; k0 < 128; k0 += 64) {
            for (int c = tid; c < 64 * 8; c += 256) {
                int row = c >> 3, c8 = c & 7;
                *(short8*)&As[row * 72 + c8 * 8] =
                    *(const short8*)(A + (size_t)(rowBase + row) * 128 + k0 + c8 * 8);
            }
            for (int c = tid; c < 256 * 8; c += 256) {
                int row = c >> 3, c8 = c & 7;
                *(short8*)&Bs[row * 72 + c8 * 8] =
                    *(const short8*)(B1 + (size_t)row * 128 + k0 + c8 * 8);
            }
            __syncthreads();
#pragma unroll
            for (int kc = 0; kc < 64; kc += 32) {
                short8 aF[4], bF[4];
#pragma unroll
                for (int mi = 0; mi < 4; mi++)
                    aF[mi] = *(const short8*)&As[(mi * 16 + l16) * 72 + kc + quad * 8];
#pragma unroll
                for (int ni = 0; ni < 4; ni++)
                    bF[ni] = *(const short8*)&Bs[(w * 64 + ni * 16 + l16) * 72 + kc + quad * 8];
#pragma unroll
                for (int mi = 0; mi < 4; mi++)
#pragma unroll
                    for (int ni = 0; ni < 4; ni++)
                        acc[mi][ni] = __builtin_amdgcn_mfma_f32_16x16x32_bf16(
                            aF[mi], bF[ni], acc[mi][ni], 0, 0, 0);
            }
            __syncthreads();
        }
        // epilogue -> Hs; also stage B2 into B2s (Bs region is dead now)
#pragma unroll
        for (int mi = 0; mi < 4; mi++) {
#pragma unroll
            for (int ni = 0; ni < 4; ni++) {
                int col = w * 64 + ni * 16 + l16;
                float bv = b1[col];
#pragma unroll
                for (int r = 0; r < 4; r++) {
                    int row = mi * 16 + quad * 4 + r;
                    float v = fmaxf(acc[mi][ni][r] + bv, 0.f);
                    Hs[row * 264 + col] = f2bfbits(v);
                }
            }
        }
        for (int c = tid; c < 64 * 32; c += 256) {       // 64 rows x 32 16B chunks
            int row = c >> 5, ch = c & 31;
            *(short8*)&B2s[row * 264 + ch * 8] =
                *(const short8*)(B2 + (size_t)row * 256 + ch * 8);
        }
        __syncthreads();
    }

    // ---- phase 2: delta = Hs @ w2 + b2; DELTA = delta + tn; l_focus ----
    {
        // 4 waves row-split: wave w -> rows w*16..+15. MT=1, NT=4 (N=64).
        f32x4 acc2[4] = {};
        for (int kc = 0; kc < 256; kc += 32) {
            short8 aF = *(const short8*)&Hs[(w * 16 + l16) * 264 + kc + quad * 8];
            short8 bF[4];
#pragma unroll
            for (int ni = 0; ni < 4; ni++)
                bF[ni] = *(const short8*)&B2s[(ni * 16 + l16) * 264 + kc + quad * 8];
#pragma unroll
            for (int ni = 0; ni < 4; ni++)
                acc2[ni] = __builtin_amdgcn_mfma_f32_16x16x32_bf16(aF, bF[ni], acc2[ni], 0, 0, 0);
        }
        __syncthreads();   // all waves done reading B2s before Ds overwrites it
        float sq = 0.f;
#pragma unroll
        for (int ni = 0; ni < 4; ni++) {
            int col = ni * 16 + l16;
            float bv = b2[col], tv = tn[col];
#pragma unroll
            for (int r = 0; r < 4; r++) {
                int row = w * 16 + quad * 4 + r;
                float v = acc2[ni][r] + bv;
                sq += v * v;
                Ds[row * 64 + col] = v + tv;
            }
        }
#pragma unroll
        for (int off = 32; off > 0; off >>= 1) sq += __shfl_xor(sq, off);
        if (lane == 0) s_w[w] = sq;
        __syncthreads();
        float* Dg = DELTA + (size_t)hop * N_NODES * 64;
        for (int c = tid; c < 64 * 16; c += 256) {       // 16 x 16B chunks/row
            int r = c >> 4, off = (c & 15) * 4;
            *(uint4v*)(Dg + (size_t)(rowBase + r) * 64 + off) =
                *(const uint4v*)(Ds + (size_t)r * 64 + off);
        }
        if (tid == 0) atomicAdd(lfocus, s_w[0] + s_w[1] + s_w[2] + s_w[3]);
    }
}

// ---------------------------------------------------------------------------
// edge_agg2: wave-synchronous, 4 nodes (one hop) per 256-thread block.
// 1-D grid, hop = blockIdx.x & 3 (XCD affinity: per-XCD hk working set 4.2 MB
// fits L2). src scalarized via readfirstlane; att stored [k][24-padded e]
// (rows 96 B = 16B-aligned -> ds_read_b128); __expf fast exp.
// ---------------------------------------------------------------------------
__global__ __launch_bounds__(256) void edge_agg2(
    const unsigned char* __restrict__ hk, const float* __restrict__ phi,
    const float* __restrict__ dik, const int* __restrict__ src,
    const float* __restrict__ biasAll, float* __restrict__ outs)
{
    int b = blockIdx.x;
    int hop = b & 3;                 // XCD affinity: hop h -> XCDs {h, h+4}
    int wave = threadIdx.x >> 6, lane = threadIdx.x & 63;
    int node = (b >> 2) * 4 + wave;
    const unsigned char* hk_l = hk + (size_t)hop * N_NODES * 256;
    const float* phi_l  = phi + (size_t)hop * N_NODES * 16;
    const float* dik_l  = dik + (size_t)hop * N_NODES * 64;
    const int*   src_n  = src + (size_t)hop * E_EDGES + (size_t)node * 16;
    const float* bias_l = biasAll + hop * 64;
    float*       outs_n = outs + ((size_t)hop * N_NODES + node) * 64;

    __shared__ float s_dik[4][64];
    __shared__ __align__(16) float s_attT[4][4][24];  // [wave][k][edge], 16B-aligned rows
    __shared__ int   s_src[4][16];

    s_dik[wave][lane] = dik_l[(size_t)node * 64 + lane];
    if (lane < 16) s_src[wave][lane] = src_n[lane];

    // ---- stage 1: dist + logits (4 lanes per edge; lane = 4e + q) ----
    int e = lane >> 2, q = lane & 3;
    int sN = s_src[wave][e];
    f32x4 ps = *(const f32x4*)(phi_l + (size_t)sN * 16 + q * 4);
    f32x4 pd = *(const f32x4*)(phi_l + (size_t)node * 16 + q * 4);
    float d0 = ps[0] - pd[0], d1 = ps[1] - pd[1];
    float d2 = ps[2] - pd[2], d3 = ps[3] - pd[3];
    bool q3 = (q == 3);            // p15 = flag col (phi col15 == 0)
    float nzf = ((d0 != 0.f) | (d1 != 0.f) | (d2 != 0.f) | (!q3 && d3 != 0.f)) ? 1.f : 0.f;
    float ssp = d0 * d0 + d1 * d1 + d2 * d2 + (q3 ? 0.f : d3 * d3);
    nzf += __shfl_xor(nzf, 1); nzf += __shfl_xor(nzf, 2);
    ssp += __shfl_xor(ssp, 1); ssp += __shfl_xor(ssp, 2);
    float last = (nzf == 0.f) ? 1.f : 0.f;
    if (q3) d3 = last;
    float inv = 1.f / fmaxf(sqrtf(ssp + last * last), 1e-8f);
#pragma unroll
    for (int k = 0; k < 4; k++) {
        const float* dk = &s_dik[wave][k * 16 + q * 4];
        float pk = d0 * dk[0] + d1 * dk[1] + d2 * dk[2] + d3 * dk[3];
        pk += __shfl_xor(pk, 1); pk += __shfl_xor(pk, 2);
        if (q == k) s_attT[wave][k][e] = pk * inv;
    }

    // ---- stage 2: softmax over 16 edges per k (lane = 4e + k) ----
    int k2 = lane & 3;
    float lgv = s_attT[wave][k2][e];
    float mx = lgv;
    mx = fmaxf(mx, __shfl_xor(mx, 4));
    mx = fmaxf(mx, __shfl_xor(mx, 8));
    mx = fmaxf(mx, __shfl_xor(mx, 16));
    mx = fmaxf(mx, __shfl_xor(mx, 32));
    float ex = __expf(lgv - mx);
    float den = ex;
    den += __shfl_xor(den, 4);
    den += __shfl_xor(den, 8);
    den += __shfl_xor(den, 16);
    den += __shfl_xor(den, 32);
    s_attT[wave][k2][e] = ex / den;

    // ---- stage 3: aggregation (lane = kk*16 + dim-group; 4 dims/lane) ----
    int kk = lane >> 4, dsub = (lane & 15) * 4;
    f32x4 attv[4];
#pragma unroll
    for (int g = 0; g < 4; g++) attv[g] = *(const f32x4*)&s_attT[wave][kk][g * 4];
    float a0 = 0.f, a1 = 0.f, a2 = 0.f, a3 = 0.f;
#pragma unroll
    for (int ee = 0; ee < 16; ee++) {
        int sm = __builtin_amdgcn_readfirstlane(s_src[wave][ee]);  // wave-uniform
        unsigned int u = *(const unsigned int*)(hk_l + (size_t)sm * 256 + lane * 4);
        float wgt = attv[ee >> 2][ee & 3];
        auto lo = __builtin_amdgcn_cvt_pk_f32_fp8((int)u, false);
        auto hi = __builtin_amdgcn_cvt_pk_f32_fp8((int)u, true);
        a0 += wgt * lo[0];
        a1 += wgt * lo[1];
        a2 += wgt * hi[0];
        a3 += wgt * hi[1];
    }
    a0 += __shfl_xor(a0, 16); a0 += __shfl_xor(a0, 32);
    a1 += __shfl_xor(a1, 16); a1 += __shfl_xor(a1, 32);
    a2 += __shfl_xor(a2, 16); a2 += __shfl_xor(a2, 32);
    a3 += __shfl_xor(a3, 16); a3 += __shfl_xor(a3, 32);
    float o0 = a0 + bias_l[dsub + 0];
    float o1 = a1 + bias_l[dsub + 1];
    float o2 = a2 + bias_l[dsub + 2];
    float o3 = a3 + bias_l[dsub + 3];
    float ssq = o0 * o0 + o1 * o1 + o2 * o2 + o3 * o3;
    ssq += __shfl_xor(ssq, 1);
    ssq += __shfl_xor(ssq, 2);
    ssq += __shfl_xor(ssq, 4);
    ssq += __shfl_xor(ssq, 8);
    float inv2 = 1.f / fmaxf(sqrtf(ssq), 1e-8f);
    if (kk == 0) {
        f32x4 st;
        st[0] = o0 * inv2; st[1] = o1 * inv2; st[2] = o2 * inv2; st[3] = o3 * inv2;
        *(f32x4*)(outs_n + dsub) = st;
    }
}

// Hop fusion + output store (dtype by flag) + scalar outputs (block 0).
__global__ __launch_bounds__(256) void fuse_kernel(
    const float* __restrict__ outs, const float* __restrict__ z,
    void* __restrict__ out, const int* __restrict__ flag,
    const float* __restrict__ acc)
{
    int tid = threadIdx.x;
    int node = blockIdx.x * 4 + (tid >> 6);
    int dd = tid & 63;
    float zv = z[dd];
    float o[4], sc[4];
#pragma unroll
    for (int h = 0; h < 4; h++) {
        o[h] = outs[((size_t)h * N_NODES + node) * 64 + dd];
        float v = o[h] * zv;
#pragma unroll
        for (int off = 32; off > 0; off >>= 1) v += __shfl_xor(v, off);
        sc[h] = v;
    }
    float mx = fmaxf(fmaxf(sc[0], sc[1]), fmaxf(sc[2], sc[3]));
    float e0 = __expf(sc[0] - mx), e1 = __expf(sc[1] - mx);
    float e2 = __expf(sc[2] - mx), e3 = __expf(sc[3] - mx);
    float den = e0 + e1 + e2 + e3;
    float t = (e0 * o[0] + e1 * o[1] + e2 * o[2] + e3 * o[3]) / den;
    size_t oi = (size_t)node * 64 + dd;
    bool isbf = (*flag != 0);
    if (isbf) ((bf16*)out)[oi] = __float2bfloat16(t);
    else      ((float*)out)[oi] = t;
    if (blockIdx.x == 0 && tid == 0) {
        float a = acc[0];                                 // l_sep (already scaled)
        float b = acc[1] / ((float)N_NODES * 4.f * 4.f);  // l_focus mean
        size_t base = (size_t)N_NODES * 64;
        if (isbf) {
            ((bf16*)out)[base]     = __float2bfloat16(a);
            ((bf16*)out)[base + 1] = __float2bfloat16(b);
        } else {
            ((float*)out)[base]     = a;
            ((float*)out)[base + 1] = b;
        }
    }
}

extern "C" void kernel_launch(void* const* d_in, const int* in_sizes, int n_in,
                              void* d_out, int out_size, void* d_ws, size_t ws_size,
                              hipStream_t stream)
{
    const void* h    = d_in[0];
    const void* e    = d_in[1];
    const int*  src  = (const int*)d_in[2];
    const void* Wphi = d_in[4];
    const void* w1   = d_in[5];
    const void* b1   = d_in[6];
    const void* w2   = d_in[7];
    const void* b2   = d_in[8];
    const void* tphi = d_in[9];
    const void* W    = d_in[10];
    const void* bias = d_in[11];
    const void* z    = d_in[12];

    float* ws    = (float*)d_ws;
    float* CV    = ws;                                  // CV_END
    float* OUTS  = CV + CV_END;                         // 4*16384*64
    float* PHI   = OUTS + (size_t)4 * N_NODES * 64;     // 4*16384*16
    float* DELTA = PHI + (size_t)4 * N_NODES * 16;      // 4*16384*64
    float* TN    = DELTA + (size_t)4 * N_NODES * 64;    // 4*64
    float* ACC   = TN + 256;                            // 2 (+pad)
    int*   FLAG  = (int*)(ACC + 2);
    bf16*  H_BF  = (bf16*)(ACC + 4);                    // 16384*256
    bf16*  E_BF  = H_BF + (size_t)N_NODES * 256;        // 4*16384*128
    bf16*  WT    = E_BF + (size_t)HOPS * N_NODES * 128;
    bf16*  W1T   = WT + WT_N;
    bf16*  W2T   = W1T + W1T_N;
    bf16*  WPT   = W2T + W2T_N;
    unsigned char* HK_F8 = (unsigned char*)(WPT + WPT_N);  // 4*16384*256 bytes

    // conversions + tn/l_sep + dtype flag + ACC init (self-detecting blocks)
    cvt_all<<<NB_ALL, 256, 0, stream>>>(
        h, e, Wphi, w1, b1, w2, b2, tphi, W, bias, z, CV,
        WT, W1T, W2T, WPT, H_BF, E_BF, TN, ACC, FLAG);

    // hk (fp8) + phi (f32) in one dispatch
    hkphi_kernel<<<dim3(3, 128, HOPS), 256, 0, stream>>>(
        H_BF, E_BF, WT, WPT, HK_F8, PHI);
    // hid (LDS-only) -> delta (+tn, l_focus) fused; 64-row tiles, 2 blk/CU
    hid_delta_kernel<<<dim3(N_NODES / 64, HOPS), 256, 0, stream>>>(
        E_BF, W1T, W2T, CV + CV_B1, CV + CV_B2, TN, DELTA, ACC + 1);
    // per-node edge softmax + aggregation + normalize (hop-XCD-affine)
    edge_agg2<<<dim3(N_NODES), 256, 0, stream>>>(
        HK_F8, PHI, DELTA, src, CV + CV_BIAS, OUTS);

    fuse_kernel<<<dim3(N_NODES / 4), 256, 0, stream>>>(
        OUTS, CV + CV_Z, d_out, FLAG, ACC);
}

// Round 12
// 215.159 us; speedup vs baseline: 7.6766x; 1.0810x over previous
//
#include <hip/hip_runtime.h>
#include <hip/hip_bf16.h>

#define N_NODES 16384
#define K_NBR 16
#define HOPS 4
#define IN_DIM 256
#define RAW_DIM 128
#define OUT_DIM 64
#define PHI_DIM 16
#define N_KERN 4
#define E_EDGES (N_NODES * K_NBR)

typedef __hip_bfloat16 bf16;
typedef __attribute__((ext_vector_type(8))) short short8;
typedef __attribute__((ext_vector_type(4))) float f32x4;
typedef __attribute__((ext_vector_type(4))) unsigned int uint4v;

__device__ __forceinline__ float toF(float x) { return x; }
__device__ __forceinline__ float toF(bf16 x) { return __bfloat162float(x); }
__device__ __forceinline__ short f2bfbits(float f)
{
    bf16 b = __float2bfloat16(f);
    short s; __builtin_memcpy(&s, &b, 2); return s;
}

// --------------------------- f32 workspace layout --------------------------
#define CV_WPHI 0
#define CV_W1   (CV_WPHI + HOPS * RAW_DIM * (PHI_DIM - 1))
#define CV_B1   (CV_W1 + HOPS * RAW_DIM * IN_DIM)
#define CV_W2   (CV_B1 + HOPS * IN_DIM)
#define CV_B2   (CV_W2 + HOPS * IN_DIM * PHI_DIM * N_KERN)
#define CV_TPHI (CV_B2 + HOPS * PHI_DIM * N_KERN)
#define CV_W    (CV_TPHI + HOPS * N_KERN * PHI_DIM)
#define CV_BIAS (CV_W + HOPS * IN_DIM * OUT_DIM * N_KERN)
#define CV_Z    (CV_BIAS + HOPS * OUT_DIM)
#define CV_END  (CV_Z + OUT_DIM)

// transposed bf16 weight region sizes
#define WT_N  (HOPS * 256 * 256)
#define W1T_N (HOPS * 256 * 128)
#define W2T_N (HOPS * 64 * 256)
#define WPT_N (HOPS * 16 * 128)
#define CVT_TOTAL (WT_N + W1T_N + W2T_N + WPT_N)

// cvt_all block ranges
#define NB_CV ((CV_END + 255) / 256)
#define NB_WT (CVT_TOTAL / 256)                      // exact
#define NB_H  (N_NODES * 256 / 8 / 256)              // h vec8 units
#define NB_E  (HOPS * N_NODES * 128 / 8 / 256)       // e vec8 units
#define NB_ALL (NB_CV + NB_WT + NB_H + NB_E + 1)

// gemm_all block mapping: A = hkphi work (1536), B = hid_delta work (1024)
#define GA_NA 1536
#define GA_NB 1024
#define GA_TOTAL (GA_NA + GA_NB)

__device__ __forceinline__ float loadDyn(const void* p, int i, bool isbf)
{
    return isbf ? toF(((const bf16*)p)[i]) : ((const float*)p)[i];
}

// 8-wide dyn -> bf16 conversion helper
__device__ __forceinline__ void cvt8(bf16* dst, const void* src, size_t base, bool isbf)
{
    short8 v;
    if (isbf) {
        v = *(const short8*)((const bf16*)src + base);
    } else {
        const float* sp = (const float*)src + base;
        f32x4 f0 = *(const f32x4*)sp;
        f32x4 f1 = *(const f32x4*)(sp + 4);
#pragma unroll
        for (int j = 0; j < 4; j++) { v[j] = f2bfbits(f0[j]); v[4 + j] = f2bfbits(f1[j]); }
    }
    *(short8*)(dst + base) = v;
}

// ---------------------------------------------------------------------------
// cvt_all: (a) small weights -> f32 CV, (b) transposed bf16 weights,
// (c) h -> bf16, (d) e -> bf16 (vec8), (e) tn + l_sep + FLAG/ACC (last block).
// Each block SELF-DETECTS dtype from h's first 256 shorts.
// ---------------------------------------------------------------------------
__global__ __launch_bounds__(256) void cvt_all(
    const void* h, const void* e,
    const void* wphi, const void* w1, const void* b1, const void* w2,
    const void* b2, const void* tphi, const void* W, const void* bias,
    const void* z, float* __restrict__ CV,
    bf16* __restrict__ wt, bf16* __restrict__ w1t, bf16* __restrict__ w2t,
    bf16* __restrict__ wpt, bf16* __restrict__ h_bf, bf16* __restrict__ e_bf,
    float* __restrict__ tn_out, float* __restrict__ acc, int* __restrict__ flagOut)
{
    __shared__ float s_det[4];
    int tid = threadIdx.x;
    // ---- self-detect ----
    {
        unsigned short pv = ((const unsigned short*)h)[tid];
        unsigned int bits = ((unsigned int)pv) << 16;
        float v; __builtin_memcpy(&v, &bits, 4);
        v = fabsf(v);
        if (!(v == v) || v > 1e30f) v = 1e30f;
#pragma unroll
        for (int off = 32; off > 0; off >>= 1) v = fmaxf(v, __shfl_xor(v, off));
        if ((tid & 63) == 0) s_det[tid >> 6] = v;
    }
    __syncthreads();
    bool isbf = fmaxf(fmaxf(s_det[0], s_det[1]), fmaxf(s_det[2], s_det[3])) < 1e4f;

    int b = blockIdx.x;
    if (b == NB_ALL - 1) {
        // ---- tn = row-normalized tilde_phi (no eps) + l_sep; writes ACC/FLAG ----
        __shared__ float s_v[256], s_tn[256], s_red[256], s_hop[4];
        int hop = tid >> 6, t64 = tid & 63;
        int row = t64 >> 4, p = t64 & 15;
        float v = loadDyn(tphi, hop * 64 + t64, isbf);
        s_v[tid] = v;
        __syncthreads();
        float ss = 0.f;
        for (int q = 0; q < 16; q++) { float x = s_v[hop * 64 + row * 16 + q]; ss += x * x; }
        float tnv = v / sqrtf(ss);
        tn_out[hop * 64 + t64] = tnv;
        s_tn[tid] = tnv;
        __syncthreads();
        float s = 0.f;
        for (int j = 0; j < 4; j++) {
            float d = tnv - s_tn[hop * 64 + j * 16 + p];
            s += d * d;
        }
        s_red[tid] = s;
        __syncthreads();
        if (t64 == 0) {
            float tot = 0.f;
            for (int i = 0; i < 64; i++) tot += s_red[hop * 64 + i];
            s_hop[hop] = tot;
        }
        __syncthreads();
        if (tid == 0) {
            // l_sep = mean over hops of (tot_hop / nk) = sum * (1/4) * (1/4)
            acc[0] = (s_hop[0] + s_hop[1] + s_hop[2] + s_hop[3]) * 0.0625f;
            acc[1] = 0.f;                        // l_focus accumulator
            *flagOut = isbf ? 1 : 0;
        }
        return;
    }
    if (b < NB_CV) {
        int idx = b * 256 + tid;
        if (idx >= CV_END) return;
        float v;
        if      (idx < CV_W1)   v = loadDyn(wphi, idx - CV_WPHI, isbf);
        else if (idx < CV_B1)   v = loadDyn(w1,   idx - CV_W1,   isbf);
        else if (idx < CV_W2)   v = loadDyn(b1,   idx - CV_B1,   isbf);
        else if (idx < CV_B2)   v = loadDyn(w2,   idx - CV_W2,   isbf);
        else if (idx < CV_TPHI) v = loadDyn(b2,   idx - CV_B2,   isbf);
        else if (idx < CV_W)    v = loadDyn(tphi, idx - CV_TPHI, isbf);
        else if (idx < CV_BIAS) v = loadDyn(W,    idx - CV_W,    isbf);
        else if (idx < CV_Z)    v = loadDyn(bias, idx - CV_BIAS, isbf);
        else                    v = loadDyn(z,    idx - CV_Z,    isbf);
        CV[idx] = v;
        return;
    }
    b -= NB_CV;
    if (b < NB_WT) {
        int idx = b * 256 + tid;
        if (idx < WT_N) {                      // 256N x 256K per hop
            int o = idx, hop = o >> 16, rem = o & 65535, n = rem >> 8, k = rem & 255;
            wt[o] = __float2bfloat16(loadDyn(W, hop * 65536 + k * 256 + n, isbf));
        } else if (idx < WT_N + W1T_N) {       // 256N x 128K per hop
            int o = idx - WT_N, hop = o >> 15, rem = o & 32767, n = rem >> 7, k = rem & 127;
            w1t[o] = __float2bfloat16(loadDyn(w1, hop * 32768 + k * 256 + n, isbf));
        } else if (idx < WT_N + W1T_N + W2T_N) { // 64N x 256K per hop
            int o = idx - WT_N - W1T_N, hop = o >> 14, rem = o & 16383, n = rem >> 8, k = rem & 255;
            w2t[o] = __float2bfloat16(loadDyn(w2, hop * 16384 + k * 64 + n, isbf));
        } else {                               // 16N x 128K per hop (row 15 zero)
            int o = idx - WT_N - W1T_N - W2T_N, hop = o >> 11, rem = o & 2047, n = rem >> 7, k = rem & 127;
            float v = (n < 15) ? loadDyn(wphi, hop * 1920 + k * 15 + n, isbf) : 0.f;
            wpt[o] = __float2bfloat16(v);
        }
        return;
    }
    b -= NB_WT;
    if (b < NB_H) {
        size_t base = ((size_t)b * 256 + tid) * 8;
        cvt8(h_bf, h, base, isbf);
        return;
    }
    b -= NB_H;
    {
        size_t base = ((size_t)b * 256 + tid) * 8;
        cvt8(e_bf, e, base, isbf);
    }
}

// ---------------------------------------------------------------------------
// MFMA GEMM device body: C = A @ B, A (M x K) bf16, Bt (N x K) bf16.
// BM=128, BK=64. OUTMODE: 0 = f32 direct store, 2 = fp8-e4m3 staged.
// Fragment layouts (HW-verified): A[m=lane&15][k=quad*8+j],
// B[k=quad*8+j][n=lane&15] (rows of Bt), C/D col=lane&15,row=quad*4+reg.
// ---------------------------------------------------------------------------
template <int BN, int WR, int WC, int OUTMODE, bool STAGED>
__device__ __forceinline__ void gemm_dev(
    char* smem, const bf16* __restrict__ A, const bf16* __restrict__ Bt,
    void* __restrict__ Cg, int K, int N, int colBase, int rowBase)
{
    constexpr int WM = 128 / WR;
    constexpr int WN = BN / WC;
    constexpr int MT = WM / 16;
    constexpr int NT = WN / 16;
    constexpr int ESZ = (OUTMODE == 0) ? 4 : 1;
    short* As = (short*)smem;            // [128][72]
    short* Bs = As + 128 * 72;           // [BN][72]

    int tid = threadIdx.x;
    int w = tid >> 6, lane = tid & 63;
    int wr = w / WC, wc = w % WC;
    int l16 = lane & 15, quad = lane >> 4;

    f32x4 acc[MT][NT] = {};

    for (int k0 = 0; k0 < K; k0 += 64) {
        for (int c = tid; c < 128 * 8; c += 256) {
            int row = c >> 3, c8 = c & 7;
            *(short8*)&As[row * 72 + c8 * 8] =
                *(const short8*)(A + (size_t)(rowBase + row) * K + k0 + c8 * 8);
        }
        for (int c = tid; c < BN * 8; c += 256) {
            int row = c >> 3, c8 = c & 7;
            *(short8*)&Bs[row * 72 + c8 * 8] =
                *(const short8*)(Bt + (size_t)(colBase + row) * K + k0 + c8 * 8);
        }
        __syncthreads();
#pragma unroll
        for (int kc = 0; kc < 64; kc += 32) {
            short8 aF[MT], bF[NT];
#pragma unroll
            for (int mi = 0; mi < MT; mi++)
                aF[mi] = *(const short8*)&As[(wr * WM + mi * 16 + l16) * 72 + kc + quad * 8];
#pragma unroll
            for (int ni = 0; ni < NT; ni++)
                bF[ni] = *(const short8*)&Bs[(wc * WN + ni * 16 + l16) * 72 + kc + quad * 8];
#pragma unroll
            for (int mi = 0; mi < MT; mi++)
#pragma unroll
                for (int ni = 0; ni < NT; ni++)
                    acc[mi][ni] = __builtin_amdgcn_mfma_f32_16x16x32_bf16(
                        aF[mi], bF[ni], acc[mi][ni], 0, 0, 0);
        }
        __syncthreads();
    }

#pragma unroll
    for (int mi = 0; mi < MT; mi++) {
#pragma unroll
        for (int ni = 0; ni < NT; ni++) {
            int cl = wc * WN + ni * 16 + l16;
            int col = colBase + cl;
#pragma unroll
            for (int r = 0; r < 4; r++) {
                int rl = wr * WM + mi * 16 + quad * 4 + r;
                float v = acc[mi][ni][r];
                if (STAGED) {
                    size_t idx = (size_t)rl * BN + cl;
                    if (OUTMODE == 0) ((float*)smem)[idx] = v;
                    else {
                        int pk = __builtin_amdgcn_cvt_pk_fp8_f32(v, v, 0, false);
                        ((unsigned char*)smem)[idx] = (unsigned char)(pk & 0xFF);
                    }
                } else {
                    ((float*)Cg)[(size_t)(rowBase + rl) * N + col] = v;
                }
            }
        }
    }
    if (STAGED) {
        __syncthreads();
        constexpr int CPR = BN * ESZ / 16;           // 16B chunks per row
        for (int c = tid; c < 128 * CPR; c += 256) {
            int r = c / CPR, off = (c % CPR) * 16;
            *(uint4v*)((char*)Cg + ((size_t)(rowBase + r) * N + colBase) * ESZ + off) =
                *(const uint4v*)(smem + (size_t)r * BN * ESZ + off);
        }
    }
}

// ---------------------------------------------------------------------------
// hid_delta device body: hid = relu(e@w1+b1) (LDS-only) -> delta = hid@w2+b2
// (+tn, l_focus). 64-row tile. LDS: As(9.2k)+Bs(36.9k)+Hs(33.8k) = 79.9 kB.
// ---------------------------------------------------------------------------
__device__ __forceinline__ void hid_delta_dev(
    char* smem, float* s_w,
    const bf16* __restrict__ A, const bf16* __restrict__ B1,
    const bf16* __restrict__ B2, const float* __restrict__ b1,
    const float* __restrict__ b2, const float* __restrict__ tn,
    float* __restrict__ Dg, float* __restrict__ lfocus, int rowBase)
{
    short* As  = (short*)smem;           // [64][72]
    short* Bs  = As + 64 * 72;           // [256][72] phase 1 / B2s [64][264] phase 2
    short* Hs  = Bs + 256 * 72;          // [64][264] hid tile (bf16 bits)
    short* B2s = Bs;
    float* Ds  = (float*)smem;           // [64][64] f32, aliases As + Bs-front

    int tid = threadIdx.x;
    int w = tid >> 6, lane = tid & 63;
    int l16 = lane & 15, quad = lane >> 4;

    // ---- phase 1: hid = relu(e @ w1 + b1) -> Hs ----
    {
        f32x4 acc[4][4] = {};
        for (int k0 = 0; k0 < 128; k0 += 64) {
            for (int c = tid; c < 64 * 8; c += 256) {
                int row = c >> 3, c8 = c & 7;
                *(short8*)&As[row * 72 + c8 * 8] =
                    *(const short8*)(A + (size_t)(rowBase + row) * 128 + k0 + c8 * 8);
            }
            for (int c = tid; c < 256 * 8; c += 256) {
                int row = c >> 3, c8 = c & 7;
                *(short8*)&Bs[row * 72 + c8 * 8] =
                    *(const short8*)(B1 + (size_t)row * 128 + k0 + c8 * 8);
            }
            __syncthreads();
#pragma unroll
            for (int kc = 0; kc < 64; kc += 32) {
                short8 aF[4], bF[4];
#pragma unroll
                for (int mi = 0; mi < 4; mi++)
                    aF[mi] = *(const short8*)&As[(mi * 16 + l16) * 72 + kc + quad * 8];
#pragma unroll
                for (int ni = 0; ni < 4; ni++)
                    bF[ni] = *(const short8*)&Bs[(w * 64 + ni * 16 + l16) * 72 + kc + quad * 8];
#pragma unroll
                for (int mi = 0; mi < 4; mi++)
#pragma unroll
                    for (int ni = 0; ni < 4; ni++)
                        acc[mi][ni] = __builtin_amdgcn_mfma_f32_16x16x32_bf16(
                            aF[mi], bF[ni], acc[mi][ni], 0, 0, 0);
            }
            __syncthreads();
        }
        // epilogue -> Hs; also stage B2 into B2s (Bs region is dead now)
#pragma unroll
        for (int mi = 0; mi < 4; mi++) {
#pragma unroll
            for (int ni = 0; ni < 4; ni++) {
                int col = w * 64 + ni * 16 + l16;
                float bv = b1[col];
#pragma unroll
                for (int r = 0; r < 4; r++) {
                    int row = mi * 16 + quad * 4 + r;
                    float v = fmaxf(acc[mi][ni][r] + bv, 0.f);
                    Hs[row * 264 + col] = f2bfbits(v);
                }
            }
        }
        for (int c = tid; c < 64 * 32; c += 256) {       // 64 rows x 32 16B chunks
            int row = c >> 5, ch = c & 31;
            *(short8*)&B2s[row * 264 + ch * 8] =
                *(const short8*)(B2 + (size_t)row * 256 + ch * 8);
        }
        __syncthreads();
    }

    // ---- phase 2: delta = Hs @ w2 + b2; DELTA = delta + tn; l_focus ----
    {
        f32x4 acc2[4] = {};
        for (int kc = 0; kc < 256; kc += 32) {
            short8 aF = *(const short8*)&Hs[(w * 16 + l16) * 264 + kc + quad * 8];
            short8 bF[4];
#pragma unroll
            for (int ni = 0; ni < 4; ni++)
                bF[ni] = *(const short8*)&B2s[(ni * 16 + l16) * 264 + kc + quad * 8];
#pragma unroll
            for (int ni = 0; ni < 4; ni++)
                acc2[ni] = __builtin_amdgcn_mfma_f32_16x16x32_bf16(aF, bF[ni], acc2[ni], 0, 0, 0);
        }
        __syncthreads();   // all waves done reading B2s before Ds overwrites it
        float sq = 0.f;
#pragma unroll
        for (int ni = 0; ni < 4; ni++) {
            int col = ni * 16 + l16;
            float bv = b2[col], tv = tn[col];
#pragma unroll
            for (int r = 0; r < 4; r++) {
                int row = w * 16 + quad * 4 + r;
                float v = acc2[ni][r] + bv;
                sq += v * v;
                Ds[row * 64 + col] = v + tv;
            }
        }
#pragma unroll
        for (int off = 32; off > 0; off >>= 1) sq += __shfl_xor(sq, off);
        if (lane == 0) s_w[w] = sq;
        __syncthreads();
        for (int c = tid; c < 64 * 16; c += 256) {       // 16 x 16B chunks/row
            int r = c >> 4, off = (c & 15) * 4;
            *(uint4v*)(Dg + (size_t)(rowBase + r) * 64 + off) =
                *(const uint4v*)(Ds + (size_t)r * 64 + off);
        }
        if (tid == 0) atomicAdd(lfocus, s_w[0] + s_w[1] + s_w[2] + s_w[3]);
    }
}

// ---------------------------------------------------------------------------
// gemm_all: hkphi work (A, 1536 blocks) + hid_delta work (B, 1024 blocks)
// in ONE dispatch, interleaved for co-scheduling (A and B are independent).
// b < 2048: even -> A[b/2], odd -> B[b/2]; else A[1024 + b - 2048].
// ---------------------------------------------------------------------------
__global__ __launch_bounds__(256) void gemm_all(
    const bf16* __restrict__ h_bf, const bf16* __restrict__ e_bf,
    const bf16* __restrict__ WT, const bf16* __restrict__ WPT,
    const bf16* __restrict__ W1T, const bf16* __restrict__ W2T,
    const float* __restrict__ b1All, const float* __restrict__ b2All,
    const float* __restrict__ tnAll, unsigned char* __restrict__ hk_f8,
    float* __restrict__ phi, float* __restrict__ DELTA, float* __restrict__ lfocus)
{
    __shared__ __align__(16) char smem[64 * 72 * 2 + 256 * 72 * 2 + 64 * 264 * 2]; // 79.9 kB
    __shared__ float s_w[4];
    int b = blockIdx.x;
    bool isA;
    int a;
    if (b < 2 * GA_NB) { isA = !(b & 1); a = b >> 1; }
    else               { isA = true;     a = GA_NB + (b - 2 * GA_NB); }
    if (isA) {
        int hop = a / 384, r = a % 384, part = r >> 7, row = r & 127;
        if (part < 2) {
            gemm_dev<128, 2, 2, 2, true>(
                smem, h_bf, WT + (size_t)hop * 256 * 256,
                hk_f8 + (size_t)hop * N_NODES * 256, 256, 256, part * 128, row * 128);
        } else {
            gemm_dev<16, 4, 1, 0, false>(
                smem, e_bf + (size_t)hop * N_NODES * 128, WPT + (size_t)hop * 16 * 128,
                phi + (size_t)hop * N_NODES * 16, 128, 16, 0, row * 128);
        }
    } else {
        int hop = a >> 8, tile = a & 255;
        hid_delta_dev(smem, s_w,
            e_bf + (size_t)hop * N_NODES * 128,
            W1T + (size_t)hop * 256 * 128, W2T + (size_t)hop * 64 * 256,
            b1All + hop * 256, b2All + hop * 64, tnAll + hop * 64,
            DELTA + (size_t)hop * N_NODES * 64, lfocus, tile * 64);
    }
}

// ---------------------------------------------------------------------------
// edge_agg2: wave-synchronous, 4 nodes (one hop) per 256-thread block.
// hop = blockIdx.x & 3 (XCD affinity). src scalarized via readfirstlane;
// att [k][24-pad e] (16B-aligned rows); __expf; last-flag via ssp==0
// (exact: nonzero f32 diffs give d^2 >= ~1e-17, sums of nonnegs can't cancel).
// ---------------------------------------------------------------------------
__global__ __launch_bounds__(256) void edge_agg2(
    const unsigned char* __restrict__ hk, const float* __restrict__ phi,
    const float* __restrict__ dik, const int* __restrict__ src,
    const float* __restrict__ biasAll, float* __restrict__ outs)
{
    int b = blockIdx.x;
    int hop = b & 3;                 // XCD affinity: hop h -> XCDs {h, h+4}
    int wave = threadIdx.x >> 6, lane = threadIdx.x & 63;
    int node = (b >> 2) * 4 + wave;
    const unsigned char* hk_l = hk + (size_t)hop * N_NODES * 256;
    const float* phi_l  = phi + (size_t)hop * N_NODES * 16;
    const float* dik_l  = dik + (size_t)hop * N_NODES * 64;
    const int*   src_n  = src + (size_t)hop * E_EDGES + (size_t)node * 16;
    const float* bias_l = biasAll + hop * 64;
    float*       outs_n = outs + ((size_t)hop * N_NODES + node) * 64;

    __shared__ float s_dik[4][64];
    __shared__ __align__(16) float s_attT[4][4][24];  // [wave][k][edge]
    __shared__ int   s_src[4][16];

    s_dik[wave][lane] = dik_l[(size_t)node * 64 + lane];
    if (lane < 16) s_src[wave][lane] = src_n[lane];

    // ---- stage 1: dist + logits (4 lanes per edge; lane = 4e + q) ----
    int e = lane >> 2, q = lane & 3;
    int sN = s_src[wave][e];
    f32x4 ps = *(const f32x4*)(phi_l + (size_t)sN * 16 + q * 4);
    f32x4 pd = *(const f32x4*)(phi_l + (size_t)node * 16 + q * 4);
    float d0 = ps[0] - pd[0], d1 = ps[1] - pd[1];
    float d2 = ps[2] - pd[2], d3 = ps[3] - pd[3];
    bool q3 = (q == 3);            // p15 = flag col (phi col15 == 0)
    float ssp = d0 * d0 + d1 * d1 + d2 * d2 + (q3 ? 0.f : d3 * d3);
    ssp += __shfl_xor(ssp, 1); ssp += __shfl_xor(ssp, 2);
    float last = (ssp == 0.f) ? 1.f : 0.f;   // all dist==0 <=> ssp==0 (see header)
    if (q3) d3 = last;
    float inv = 1.f / fmaxf(sqrtf(ssp + last * last), 1e-8f);
#pragma unroll
    for (int k = 0; k < 4; k++) {
        const float* dk = &s_dik[wave][k * 16 + q * 4];
        float pk = d0 * dk[0] + d1 * dk[1] + d2 * dk[2] + d3 * dk[3];
        pk += __shfl_xor(pk, 1); pk += __shfl_xor(pk, 2);
        if (q == k) s_attT[wave][k][e] = pk * inv;
    }

    // ---- stage 2: softmax over 16 edges per k (lane = 4e + k) ----
    int k2 = lane & 3;
    float lgv = s_attT[wave][k2][e];
    float mx = lgv;
    mx = fmaxf(mx, __shfl_xor(mx, 4));
    mx = fmaxf(mx, __shfl_xor(mx, 8));
    mx = fmaxf(mx, __shfl_xor(mx, 16));
    mx = fmaxf(mx, __shfl_xor(mx, 32));
    float ex = __expf(lgv - mx);
    float den = ex;
    den += __shfl_xor(den, 4);
    den += __shfl_xor(den, 8);
    den += __shfl_xor(den, 16);
    den += __shfl_xor(den, 32);
    s_attT[wave][k2][e] = ex / den;

    // ---- stage 3: aggregation (lane = kk*16 + dim-group; 4 dims/lane) ----
    int kk = lane >> 4, dsub = (lane & 15) * 4;
    f32x4 attv[4];
#pragma unroll
    for (int g = 0; g < 4; g++) attv[g] = *(const f32x4*)&s_attT[wave][kk][g * 4];
    float a0 = 0.f, a1 = 0.f, a2 = 0.f, a3 = 0.f;
#pragma unroll
    for (int ee = 0; ee < 16; ee++) {
        int sm = __builtin_amdgcn_readfirstlane(s_src[wave][ee]);  // wave-uniform
        unsigned int u = *(const unsigned int*)(hk_l + (size_t)sm * 256 + lane * 4);
        float wgt = attv[ee >> 2][ee & 3];
        auto lo = __builtin_amdgcn_cvt_pk_f32_fp8((int)u, false);
        auto hi = __builtin_amdgcn_cvt_pk_f32_fp8((int)u, true);
        a0 += wgt * lo[0];
        a1 += wgt * lo[1];
        a2 += wgt * hi[0];
        a3 += wgt * hi[1];
    }
    a0 += __shfl_xor(a0, 16); a0 += __shfl_xor(a0, 32);
    a1 += __shfl_xor(a1, 16); a1 += __shfl_xor(a1, 32);
    a2 += __shfl_xor(a2, 16); a2 += __shfl_xor(a2, 32);
    a3 += __shfl_xor(a3, 16); a3 += __shfl_xor(a3, 32);
    f32x4 bv = *(const f32x4*)(bias_l + dsub);
    float o0 = a0 + bv[0];
    float o1 = a1 + bv[1];
    float o2 = a2 + bv[2];
    float o3 = a3 + bv[3];
    float ssq = o0 * o0 + o1 * o1 + o2 * o2 + o3 * o3;
    ssq += __shfl_xor(ssq, 1);
    ssq += __shfl_xor(ssq, 2);
    ssq += __shfl_xor(ssq, 4);
    ssq += __shfl_xor(ssq, 8);
    float inv2 = 1.f / fmaxf(sqrtf(ssq), 1e-8f);
    if (kk == 0) {
        f32x4 st;
        st[0] = o0 * inv2; st[1] = o1 * inv2; st[2] = o2 * inv2; st[3] = o3 * inv2;
        *(f32x4*)(outs_n + dsub) = st;
    }
}

// Hop fusion + output store (dtype by flag) + scalar outputs (block 0).
__global__ __launch_bounds__(256) void fuse_kernel(
    const float* __restrict__ outs, const float* __restrict__ z,
    void* __restrict__ out, const int* __restrict__ flag,
    const float* __restrict__ acc)
{
    int tid = threadIdx.x;
    int node = blockIdx.x * 4 + (tid >> 6);
    int dd = tid & 63;
    float zv = z[dd];
    float o[4], sc[4];
#pragma unroll
    for (int h = 0; h < 4; h++) {
        o[h] = outs[((size_t)h * N_NODES + node) * 64 + dd];
        float v = o[h] * zv;
#pragma unroll
        for (int off = 32; off > 0; off >>= 1) v += __shfl_xor(v, off);
        sc[h] = v;
    }
    float mx = fmaxf(fmaxf(sc[0], sc[1]), fmaxf(sc[2], sc[3]));
    float e0 = __expf(sc[0] - mx), e1 = __expf(sc[1] - mx);
    float e2 = __expf(sc[2] - mx), e3 = __expf(sc[3] - mx);
    float den = e0 + e1 + e2 + e3;
    float t = (e0 * o[0] + e1 * o[1] + e2 * o[2] + e3 * o[3]) / den;
    size_t oi = (size_t)node * 64 + dd;
    bool isbf = (*flag != 0);
    if (isbf) ((bf16*)out)[oi] = __float2bfloat16(t);
    else      ((float*)out)[oi] = t;
    if (blockIdx.x == 0 && tid == 0) {
        float a = acc[0];                                 // l_sep (already scaled)
        float b = acc[1] / ((float)N_NODES * 4.f * 4.f);  // l_focus mean
        size_t base = (size_t)N_NODES * 64;
        if (isbf) {
            ((bf16*)out)[base]     = __float2bfloat16(a);
            ((bf16*)out)[base + 1] = __float2bfloat16(b);
        } else {
            ((float*)out)[base]     = a;
            ((float*)out)[base + 1] = b;
        }
    }
}

extern "C" void kernel_launch(void* const* d_in, const int* in_sizes, int n_in,
                              void* d_out, int out_size, void* d_ws, size_t ws_size,
                              hipStream_t stream)
{
    const void* h    = d_in[0];
    const void* e    = d_in[1];
    const int*  src  = (const int*)d_in[2];
    const void* Wphi = d_in[4];
    const void* w1   = d_in[5];
    const void* b1   = d_in[6];
    const void* w2   = d_in[7];
    const void* b2   = d_in[8];
    const void* tphi = d_in[9];
    const void* W    = d_in[10];
    const void* bias = d_in[11];
    const void* z    = d_in[12];

    float* ws    = (float*)d_ws;
    float* CV    = ws;                                  // CV_END
    float* OUTS  = CV + CV_END;                         // 4*16384*64
    float* PHI   = OUTS + (size_t)4 * N_NODES * 64;     // 4*16384*16
    float* DELTA = PHI + (size_t)4 * N_NODES * 16;      // 4*16384*64
    float* TN    = DELTA + (size_t)4 * N_NODES * 64;    // 4*64
    float* ACC   = TN + 256;                            // 2 (+pad)
    int*   FLAG  = (int*)(ACC + 2);
    bf16*  H_BF  = (bf16*)(ACC + 4);                    // 16384*256
    bf16*  E_BF  = H_BF + (size_t)N_NODES * 256;        // 4*16384*128
    bf16*  WT    = E_BF + (size_t)HOPS * N_NODES * 128;
    bf16*  W1T   = WT + WT_N;
    bf16*  W2T   = W1T + W1T_N;
    bf16*  WPT   = W2T + W2T_N;
    unsigned char* HK_F8 = (unsigned char*)(WPT + WPT_N);  // 4*16384*256 bytes

    // conversions + tn/l_sep + dtype flag + ACC init (self-detecting blocks)
    cvt_all<<<NB_ALL, 256, 0, stream>>>(
        h, e, Wphi, w1, b1, w2, b2, tphi, W, bias, z, CV,
        WT, W1T, W2T, WPT, H_BF, E_BF, TN, ACC, FLAG);

    // hk (fp8) + phi (f32) + hid->delta (+tn, l_focus): one dispatch
    gemm_all<<<dim3(GA_TOTAL), 256, 0, stream>>>(
        H_BF, E_BF, WT, WPT, W1T, W2T,
        CV + CV_B1, CV + CV_B2, TN, HK_F8, PHI, DELTA, ACC + 1);

    // per-node edge softmax + aggregation + normalize (hop-XCD-affine)
    edge_agg2<<<dim3(N_NODES), 256, 0, stream>>>(
        HK_F8, PHI, DELTA, src, CV + CV_BIAS, OUTS);

    fuse_kernel<<<dim3(N_NODES / 4), 256, 0, stream>>>(
        OUTS, CV + CV_Z, d_out, FLAG, ACC);
}